// Round 13
// baseline (2000.772 us; speedup 1.0000x reference)
//
#include <hip/hip_runtime.h>
#include <math.h>

// ---------------------------------------------------------------------------
// Dictionary_56212531970303 : FISTA dictionary forward on MI355X, fp32.
// Setup: prep1, k_PP, k_impulse, k_dft, atoms1 (+af_rnT), k_M, k_fin.
// Loop (20 iters):
//   kA  — coefficient state stored [b][pix][ch] (TRANSPOSED — round-12
//         diagnosis: with [ch][pix], the channel walk is 256B bursts at 64KB
//         stride -> HBM transaction-bound at 1.3TB/s; 47us invariant across
//         3 block-shape variants). Phase1/3 now contiguous float4 loads.
//         Writes nc additionally in [ch][pix] (ncT) for kB1 (+16.8MB/iter,
//         non-blocking stores). Weights via wave-uniform s_load.
//   kB1 — unchanged (reads ncT [ch][pix]): 16 cgroups x 4ch, 8 px/thread.
//   kB2 — image update + residual partials (sums 16 partial groups).
// Iter 1 templated FIRST; iter 20 writes ncT directly into d_out.
// NOTE: every "if (tid<N)" with N>blockDim must be a grid-stride loop —
// round-2/3 regression: `if(tid<289)` under 256 threads left pi[256..288]
// unwritten (deterministic absmax 0.134).
// ---------------------------------------------------------------------------

#define NB 4
#define NCH 64
#define NPIX 16384              // 128*128
#define NPB (NCH*NPIX)          // per-batch coeff elements
#define NCOEF (NB*NCH*NPIX)     // 4194304
#define NIMG  (NB*NPIX)         // 65536
#define NPG 16                  // partial channel-groups (4 ch each)
#define TOLV 1e-4f

#define SC_BETA 0
#define SC_L    1
#define SC_G    4
#define SC_G2   5
#define SC_LPK2 6

// ---------------------------------------------------------------------------
// prep1: one block. bjorck via 8x8 gram-iteration; writes gram + pf + scalars.
__global__ __launch_bounds__(256) void k_prep1(const float* __restrict__ fatoms,
    const float* __restrict__ beta_p,
    float* __restrict__ gram_g, float* __restrict__ pf_g,
    float* __restrict__ scalars)
{
    __shared__ float sW[648], sWf[648];
    __shared__ float sG[64], sP[64], sF[64], sT[64], sTmp[64];
    __shared__ float sGr[6561];
    __shared__ float rs[81];
    __shared__ float sSig;
    int tid = threadIdx.x;
    if (tid==0){ float b=beta_p[0]; scalars[SC_BETA]=(b>0.f)?b:0.f;
                 ((unsigned*)scalars)[SC_LPK2]=0u; }
    for (int e=tid; e<648; e+=256) sW[e]=fatoms[e];
    __syncthreads();
    if (tid<64){ int r=tid>>3, s=tid&7; float a=0.f;
        for (int k=0;k<81;++k) a=fmaf(sW[r*81+k],sW[s*81+k],a); sG[tid]=a; }
    __syncthreads();
    if (tid<64){
        int r8 = tid&7;
        float v = 1.f;
        for (int it=0; it<128; ++it){
            float nv=0.f;
            #pragma unroll
            for (int j=0;j<8;++j) nv = fmaf(sG[r8*8+j], __shfl(v,j,8), nv);
            float m = fabsf(nv);
            m = fmaxf(m, __shfl_xor(m,1,8));
            m = fmaxf(m, __shfl_xor(m,2,8));
            m = fmaxf(m, __shfl_xor(m,4,8));
            v = nv/m;
        }
        float wv=0.f;
        #pragma unroll
        for (int j=0;j<8;++j) wv = fmaf(sG[r8*8+j], __shfl(v,j,8), wv);
        float num=v*wv, den=v*v;
        num += __shfl_xor(num,1,8); num += __shfl_xor(num,2,8); num += __shfl_xor(num,4,8);
        den += __shfl_xor(den,1,8); den += __shfl_xor(den,2,8); den += __shfl_xor(den,4,8);
        if (tid==0) sSig = sqrtf(num/den);
    }
    __syncthreads();
    float inv_s = 1.f/sSig;
    for (int e=tid; e<648; e+=256) sW[e]*=inv_s;
    if (tid<64){ sG[tid]*=inv_s*inv_s; sP[tid]=((tid>>3)==(tid&7))?1.f:0.f; }
    __syncthreads();
    for (int it=0; it<15; ++it){
        if (tid<64) sF[tid] = (((tid>>3)==(tid&7))?1.5f:0.f) - 0.5f*sG[tid];
        __syncthreads();
        if (tid<64){ int r=tid>>3, c=tid&7; float ap=0.f, ag=0.f;
            #pragma unroll
            for (int k=0;k<8;++k){ float f=sF[r*8+k]; ap=fmaf(f,sP[k*8+c],ap); ag=fmaf(f,sG[k*8+c],ag); }
            sTmp[tid]=ap; sT[tid]=ag; }
        __syncthreads();
        if (tid<64){ int r=tid>>3, c=tid&7; float g2=0.f;
            #pragma unroll
            for (int k=0;k<8;++k) g2=fmaf(sT[r*8+k],sF[k*8+c],g2);
            sG[tid]=g2; sP[tid]=sTmp[tid]; }
        __syncthreads();
    }
    for (int e=tid; e<648; e+=256){ int r=e/81, j=e%81; float a=0.f;
        #pragma unroll
        for (int k=0;k<8;++k) a=fmaf(sP[r*8+k], sW[k*81+j], a);
        sWf[e]=a; }
    __syncthreads();
    for (int e=tid; e<6561; e+=256){ int i=e/81, j=e%81; float a=0.f;
        #pragma unroll
        for (int r=0;r<8;++r) a=fmaf(sWf[r*81+i],sWf[r*81+j],a);
        sGr[e]=a; gram_g[e]=a; }
    __syncthreads();
    if (tid<81){ float s=0.f; for (int k=0;k<81;++k) s+=sGr[tid*81+k]; rs[tid]=(1.f-s)/81.f; }
    __syncthreads();
    for (int e=tid; e<6561; e+=256){ int i=e/81, j=e%81;
        pf_g[e] = ((i==j)?1.f:0.f) - sGr[e] - rs[j]; }
}

// PP = pf^T pf (81x81), pf staged in LDS. 26 blocks x 256 thr.
__global__ __launch_bounds__(256) void k_PP(const float* __restrict__ pf, float* __restrict__ PP)
{
    __shared__ float spf[6561];
    for (int e=threadIdx.x; e<6561; e+=256) spf[e]=pf[e];
    __syncthreads();
    int e = blockIdx.x*256 + threadIdx.x;
    if (e>=6561) return;
    int al=e/81, be=e%81; float a=0.f;
    for (int c=0;c<81;++c) a=fmaf(spf[c*81+al], spf[c*81+be], a);
    PP[e]=a;
}

// proj_impulse (17x17) via PP lookups. One block, 320 thr (guard: t<289).
__global__ void k_impulse(const float* __restrict__ PP, float* __restrict__ pi)
{
    int t = threadIdx.x;
    if (t>=289) return;
    int h=t/17, w=t%17;
    float acc=0.f;
    for (int p=0;p<9;++p){
        int i2=(h+p-4+17)%17;
        if (i2<4||i2>12) continue;
        for (int q=0;q<9;++q){
            int j2=(w+q-4+17)%17;
            if (j2<4||j2>12) continue;
            int al=(12-i2)*9+(12-j2);
            int be=(8-p)*9+(8-q);
            acc += PP[al*81+be];
        }
    }
    pi[t]=acc;
}

// |FFT2(pi zero-padded to 128x128)|^2 max. 256 blocks x 64 thr (1 wave).
__global__ __launch_bounds__(64) void k_dft(const float* __restrict__ pi, float* __restrict__ scalars)
{
    __shared__ float spi[289], ct[128], st[128];
    int tid=threadIdx.x; int gid=blockIdx.x*64+tid;
    for (int e=tid; e<289; e+=64) spi[e]=pi[e];
    for (int e=tid; e<128; e+=64){ float ang=(float)e*(6.28318530717958647692f/128.f);
                  ct[e]=cosf(ang); st[e]=sinf(ang); }
    __syncthreads();
    int u=gid>>7, v=gid&127;
    float re=0.f, im=0.f;
    for (int i=0;i<17;++i){
        int ku=(u*i)&127;
        const float* prow=spi+i*17;
        for (int j=0;j<17;++j){
            int k=(ku+v*j)&127;
            float x=prow[j];
            re=fmaf(x,ct[k],re); im=fmaf(x,st[k],im);
        }
    }
    float m2=re*re+im*im;
    #pragma unroll
    for (int d=32; d; d>>=1) m2=fmaxf(m2, __shfl_down(m2,d));
    if (tid==0) atomicMax(((unsigned*)scalars)+SC_LPK2, __float_as_uint(m2));
}

// per-atom: center, subtract af@gram, row-normalize. Writes af_rn AND af_rnT.
__global__ __launch_bounds__(128) void k_atoms1(const float* __restrict__ atoms_in,
    const float* __restrict__ gram, float* __restrict__ af_rn, float* __restrict__ af_rnT)
{
    int a=blockIdx.x, tid=threadIdx.x;
    __shared__ float a0[81], a1[81], rbuf[128];
    float v = (tid<81)? atoms_in[a*81+tid] : 0.f;
    rbuf[tid]=v; __syncthreads();
    for (int off=64; off; off>>=1){ if (tid<off) rbuf[tid]+=rbuf[tid+off]; __syncthreads(); }
    float mean = rbuf[0]/81.f;
    __syncthreads();
    if (tid<81) a0[tid]=v-mean;
    __syncthreads();
    float w=0.f;
    if (tid<81){ float dot=0.f;
        for (int k=0;k<81;++k) dot=fmaf(a0[k], gram[k*81+tid], dot);
        w=a0[tid]-dot; a1[tid]=w; }
    rbuf[tid]=(tid<81)? w*w : 0.f;
    __syncthreads();
    for (int off=64; off; off>>=1){ if (tid<off) rbuf[tid]+=rbuf[tid+off]; __syncthreads(); }
    float inv = 1.f/sqrtf(rbuf[0]);
    if (tid<81){ float r=a1[tid]*inv; af_rn[a*81+tid]=r; af_rnT[tid*64+a]=r; }
}

// M = af_rn af_rn^T. 16 blocks x 256.
__global__ __launch_bounds__(256) void k_M(const float* __restrict__ af_rn,
    const float* __restrict__ af_rnT, float* __restrict__ M)
{
    int e=blockIdx.x*256+threadIdx.x;
    int i=e>>6, j=e&63;
    float a=0.f;
    for (int k=0;k<81;++k) a=fmaf(af_rn[i*81+k], af_rnT[(k<<6)+j], a);
    M[e]=a;
}

// k_fin: one block. A=M^2, power 48 on A, Rayleigh with M, finalize.
__global__ __launch_bounds__(256) void k_fin(const float* __restrict__ Mg,
    const float* __restrict__ af_rn, float* __restrict__ scalars,
    float* __restrict__ atoms_f, float* __restrict__ atomsT, float* __restrict__ Xmat)
{
    __shared__ __align__(16) float sM [64*68];
    __shared__ __align__(16) float sA [64*68];
    __shared__ float sGc[2];
    int tid=threadIdx.x;
    for (int e=tid; e<4096; e+=256) sM[(e>>6)*68+(e&63)]=Mg[e];
    for (int e=tid; e<64*68; e+=256){ if ((e%68)>=64) sM[e]=0.f; }
    __syncthreads();
    for (int e=tid; e<4096; e+=256){
        int i=e>>6, j=e&63;
        const float4* ri = reinterpret_cast<const float4*>(sM + i*68);
        const float4* rj = reinterpret_cast<const float4*>(sM + j*68);
        float a0=0.f,a1=0.f,a2=0.f,a3=0.f;
        #pragma unroll
        for (int k=0;k<16;++k){
            float4 x=ri[k], y=rj[k];
            a0=fmaf(x.x,y.x,a0); a1=fmaf(x.y,y.y,a1);
            a2=fmaf(x.z,y.z,a2); a3=fmaf(x.w,y.w,a3);
        }
        sA[i*68+j]=(a0+a1)+(a2+a3);
    }
    __syncthreads();
    if (tid<64){
        float m[64];
        #pragma unroll
        for (int j=0;j<64;++j) m[j]=sA[tid*68+j];
        float v = 1.0f + 0.01f*(float)tid;
        for (int it=0; it<48; ++it){
            float a0=0.f,a1=0.f,a2=0.f,a3=0.f;
            #pragma unroll
            for (int j=0;j<64;j+=4){
                a0=fmaf(m[j+0], __shfl(v,j+0), a0);
                a1=fmaf(m[j+1], __shfl(v,j+1), a1);
                a2=fmaf(m[j+2], __shfl(v,j+2), a2);
                a3=fmaf(m[j+3], __shfl(v,j+3), a3);
            }
            float nv=(a0+a1)+(a2+a3);
            float mx=fabsf(nv);
            #pragma unroll
            for (int d=1; d<64; d<<=1) mx=fmaxf(mx, __shfl_xor(mx,d));
            v=nv/mx;
        }
        float w0=0.f,w1=0.f,w2=0.f,w3=0.f;
        #pragma unroll
        for (int j=0;j<64;j+=4){
            w0=fmaf(sM[tid*68+j+0], __shfl(v,j+0), w0);
            w1=fmaf(sM[tid*68+j+1], __shfl(v,j+1), w1);
            w2=fmaf(sM[tid*68+j+2], __shfl(v,j+2), w2);
            w3=fmaf(sM[tid*68+j+3], __shfl(v,j+3), w3);
        }
        float wv=(w0+w1)+(w2+w3);
        float num=v*wv, den=v*v;
        #pragma unroll
        for (int d=1; d<64; d<<=1){ num+=__shfl_xor(num,d); den+=__shfl_xor(den,d); }
        if (tid==0){
            float sig = sqrtf(num/den);
            float b = scalars[SC_BETA];
            float s = sqrtf(0.99f/fmaxf(b,0.1f));
            float g = s/sig;
            scalars[SC_G]=g; scalars[SC_G2]=g*g;
            float lpk = sqrtf(__uint_as_float(((unsigned*)scalars)[SC_LPK2]));
            scalars[SC_L] = 1.01f*b*lpk;
            sGc[0]=g; sGc[1]=g*g;
        }
    }
    __syncthreads();
    float g=sGc[0], g2=sGc[1];
    for (int idx=tid; idx<5184; idx+=256){
        int a=idx/81, pq=idx-a*81;
        float v=g*af_rn[idx];
        atoms_f[idx]=v;
        atomsT[pq*64+a]=v;
    }
    for (int e=tid; e<4096; e+=256) Xmat[e]=g2*sM[(e>>6)*68+(e&63)];
}

// ---------------------------------------------------------------------------
// kA: coefficient update over [b][pix][ch] state. grid (row, batch) =
// (128,4), 256 thr (2 og halves x 128 px). Phase1: 32 contiguous float4
// loads/thread; phase3: float4 read/write + scalar [ch][pix] nc copy for kB1.
template<bool FIRST>
__global__ __launch_bounds__(256) void kA(const float* __restrict__ c_in,
    const float* __restrict__ nc_in, const float* __restrict__ nimg,
    const float* __restrict__ Xmat, const float* __restrict__ atomsT,
    const float* __restrict__ scalars, const float* __restrict__ lmbda_p,
    const float* __restrict__ red_in,
    float* __restrict__ c_out, float* __restrict__ nc_out,
    float* __restrict__ nc_outT, float mom)
{
    int b=blockIdx.y, h0=blockIdx.x;
    int tid=threadIdx.x;
    int og = __builtin_amdgcn_readfirstlane(tid>>7);  // wave-uniform half
    int w = tid&127;
    __shared__ float simg[9*128];
    __shared__ float sAct;
    if (FIRST){ if (tid==0) sAct=1.f; }
    else if (tid<64){
        float sd=red_in[(b<<7)+(tid<<1)], si=red_in[(b<<7)+(tid<<1)+1];
        #pragma unroll
        for (int off=32; off; off>>=1){ sd+=__shfl_down(sd,off); si+=__shfl_down(si,off); }
        if (tid==0) sAct = (sd > TOLV*TOLV*si) ? 1.f : 0.f;
    }
    for (int e=tid; e<1152; e+=256)
        simg[e]=nimg[b*NPIX + (((h0-4+(e>>7))&127)<<7) + (e&127)];
    __syncthreads();
    int pix=(h0<<7)+w;
    size_t base = (size_t)b*NPB + (size_t)pix*NCH;
    const float4* cp4  = reinterpret_cast<const float4*>(c_in  + base);
    const float4* ncp4 = reinterpret_cast<const float4*>(nc_in + base);
    const float* Xo  = Xmat   + og*32;   // wave-uniform row bases
    const float* Ao  = atomsT + og*32;
    float acc[32];
    #pragma unroll
    for (int o=0;o<32;++o) acc[o]=0.f;
    if (!FIRST){
        #pragma unroll 2
        for (int c4=0;c4<16;++c4){
            float4 nv=ncp4[c4], cv=cp4[c4];
            float t0=fmaf(mom,nv.x-cv.x,nv.x);
            float t1=fmaf(mom,nv.y-cv.y,nv.y);
            float t2=fmaf(mom,nv.z-cv.z,nv.z);
            float t3=fmaf(mom,nv.w-cv.w,nv.w);
            const float* X0 = Xo + ((c4*4+0)<<6);   // uniform -> s_load
            const float* X1 = Xo + ((c4*4+1)<<6);
            const float* X2 = Xo + ((c4*4+2)<<6);
            const float* X3 = Xo + ((c4*4+3)<<6);
            #pragma unroll
            for (int i=0;i<32;++i){
                float a=acc[i];
                a=fmaf(X0[i],t0,a); a=fmaf(X1[i],t1,a);
                a=fmaf(X2[i],t2,a); a=fmaf(X3[i],t3,a);
                acc[i]=a;
            }
        }
    }
    for (int p=0;p<9;++p){
        const float* srow = simg + p*128;
        #pragma unroll 3
        for (int q=0;q<9;++q){
            float wv = -srow[(w+q-4)&127];
            const float* Ar = Ao + ((p*9+q)<<6);  // uniform -> s_load
            #pragma unroll
            for (int i=0;i<32;++i) acc[i]=fmaf(Ar[i], wv, acc[i]);
        }
    }
    float beta=scalars[SC_BETA], lmb=lmbda_p[0];
    bool act = (sAct!=0.f);
    int co = og*32;
    const float* cpoB  = c_in  + base + co;
    const float* ncpoB = nc_in + base + co;
    float* copB  = c_out  + base + co;
    float* ncopB = nc_out + base + co;
    float* ncT   = nc_outT + (size_t)b*NPB + (size_t)co*NPIX + pix;
    #pragma unroll
    for (int j4=0;j4<8;++j4){
        float4 nv, cv;
        if (FIRST){ nv=make_float4(0.f,0.f,0.f,0.f); cv=nv; }
        else {
            nv=*reinterpret_cast<const float4*>(ncpoB + 4*j4);
            cv=*reinterpret_cast<const float4*>(cpoB  + 4*j4);
        }
        float4 nw, cw;
        {
            float t=FIRST?0.f:fmaf(mom,nv.x-cv.x,nv.x);
            float u=fmaf(-beta,acc[4*j4+0],t); float au=fabsf(u)-lmb;
            u=(au>0.f)?copysignf(au,u):0.f; nw.x=act?u:nv.x; cw.x=act?nv.x:cv.x;
        }{
            float t=FIRST?0.f:fmaf(mom,nv.y-cv.y,nv.y);
            float u=fmaf(-beta,acc[4*j4+1],t); float au=fabsf(u)-lmb;
            u=(au>0.f)?copysignf(au,u):0.f; nw.y=act?u:nv.y; cw.y=act?nv.y:cv.y;
        }{
            float t=FIRST?0.f:fmaf(mom,nv.z-cv.z,nv.z);
            float u=fmaf(-beta,acc[4*j4+2],t); float au=fabsf(u)-lmb;
            u=(au>0.f)?copysignf(au,u):0.f; nw.z=act?u:nv.z; cw.z=act?nv.z:cv.z;
        }{
            float t=FIRST?0.f:fmaf(mom,nv.w-cv.w,nv.w);
            float u=fmaf(-beta,acc[4*j4+3],t); float au=fabsf(u)-lmb;
            u=(au>0.f)?copysignf(au,u):0.f; nw.w=act?u:nv.w; cw.w=act?nv.w:cv.w;
        }
        *reinterpret_cast<float4*>(copB  + 4*j4) = cw;
        *reinterpret_cast<float4*>(ncopB + 4*j4) = nw;
        ncT[(4*j4+0)*NPIX]=nw.x; ncT[(4*j4+1)*NPIX]=nw.y;
        ncT[(4*j4+2)*NPIX]=nw.z; ncT[(4*j4+3)*NPIX]=nw.w;
    }
}

// kB1: dict_pred partials from ncT [ch][pix]. grid (8 rowblk, 16 cgroup, 4 b)
// = 512 blocks of 256 thr. 16 rows/block, 8 px/thread, 4 ch per cgroup.
__global__ __launch_bounds__(256,4) void kB1(const float* __restrict__ nc2,
    const float* __restrict__ atoms_f, float* __restrict__ part)
{
    int b=blockIdx.z, cg=blockIdx.y, pb=blockIdx.x;
    int t=threadIdx.x;
    int row = pb*16 + (t>>4);
    int cb  = (t&15)*8;
    const float* src = nc2 + (b*NCH + cg*4)*NPIX;
    float acc[8];
    #pragma unroll
    for (int k=0;k<8;++k) acc[k]=0.f;
    for (int c=0;c<4;++c){
        const float* chan = src + c*NPIX;
        const float* arow = atoms_f + (cg*4+c)*81;
        #pragma unroll 3
        for (int p=0;p<9;++p){
            int r=(row+4-p)&127;
            const float* rp_ = chan + (r<<7);
            float in16[16];
            #pragma unroll
            for (int k4=0;k4<4;++k4){
                int col=(cb-4+(k4<<2))&127;
                const float4 vv = *reinterpret_cast<const float4*>(rp_+col);
                in16[(k4<<2)+0]=vv.x; in16[(k4<<2)+1]=vv.y;
                in16[(k4<<2)+2]=vv.z; in16[(k4<<2)+3]=vv.w;
            }
            #pragma unroll
            for (int q=0;q<9;++q){
                float a = arow[p*9+q];
                #pragma unroll
                for (int k=0;k<8;++k) acc[k]=fmaf(in16[k+8-q], a, acc[k]);
            }
        }
    }
    float* dst = part + (cg*NB+b)*NPIX + (row<<7) + cb;
    #pragma unroll
    for (int k=0;k<8;++k) dst[k]=acc[k];
}

// kB2: image update + residual block partials (+ in-block active flag)
template<bool FIRST>
__global__ __launch_bounds__(256) void kB2(const float* __restrict__ img,
    const float* __restrict__ nimg, const float* __restrict__ y,
    const float* __restrict__ part, const float* __restrict__ pi,
    const float* __restrict__ scalars, const float* __restrict__ red_in,
    float* __restrict__ img_out, float* __restrict__ nimg_out,
    float* __restrict__ red_out, float mom)
{
    int b=blockIdx.y, rp=blockIdx.x;
    int tid=threadIdx.x, ty=tid>>7, w=tid&127;
    int h0=rp*2;
    __shared__ float sti[18*128];
    __shared__ float spi[289];
    __shared__ float rsd[4], rsi[4];
    __shared__ float sAct;
    if (FIRST){ if (tid==0) sAct=1.f; }
    else if (tid<64){
        float sd=red_in[(b<<7)+(tid<<1)], si=red_in[(b<<7)+(tid<<1)+1];
        #pragma unroll
        for (int off=32; off; off>>=1){ sd+=__shfl_down(sd,off); si+=__shfl_down(si,off); }
        if (tid==0) sAct = (sd > TOLV*TOLV*si) ? 1.f : 0.f;
    }
    const float* ib  = img  + b*NPIX;
    const float* nib = nimg + b*NPIX;
    for (int e=tid; e<2304; e+=256){
        int r=e>>7, cc=e&127;
        int idx=(((h0-8+r)&127)<<7)+cc;
        float nv=nib[idx], v=ib[idx];
        sti[e]=fmaf(mom, nv-v, nv);
    }
    for (int e=tid; e<289; e+=256) spi[e]=pi[e];
    __syncthreads();
    float sp=0.f;
    for (int p=0;p<17;++p){
        const float* srow = sti + (ty+p)*128;
        const float* pr = spi + p*17;
        #pragma unroll
        for (int q=0;q<17;++q) sp=fmaf(srow[(w+q-8)&127], pr[q], sp);
    }
    int pix=((h0+ty)<<7)+w;
    float dp=0.f;
    #pragma unroll
    for (int g=0; g<NPG; ++g) dp += part[(g*NB+b)*NPIX + pix];
    float ti = sti[(ty+8)*128 + w];
    float beta=scalars[SC_BETA], L=scalars[SC_L];
    float yv=y[b*NPIX+pix];
    float upd = ti - (ti - yv + beta*(sp - dp))/L;
    bool act = (sAct!=0.f);
    float iv=ib[pix], niv=nib[pix];
    float i2 = act? niv : iv;
    float ni2 = act? upd : niv;
    img_out[b*NPIX+pix]=i2;
    nimg_out[b*NPIX+pix]=ni2;
    float d=i2-ni2;
    float sd=d*d, si=i2*i2;
    #pragma unroll
    for (int off=32; off; off>>=1){ sd+=__shfl_down(sd,off); si+=__shfl_down(si,off); }
    if ((tid&63)==0){ rsd[tid>>6]=sd; rsi[tid>>6]=si; }
    __syncthreads();
    if (tid==0){
        float a=rsd[0]+rsd[1]+rsd[2]+rsd[3];
        float c2=rsi[0]+rsi[1]+rsi[2]+rsi[3];
        red_out[(b<<7)+(rp<<1)+0]=a;
        red_out[(b<<7)+(rp<<1)+1]=c2;
    }
}

// ---------------------------------------------------------------------------
extern "C" void kernel_launch(void* const* d_in, const int* in_sizes, int n_in,
                              void* d_out, int out_size, void* d_ws, size_t ws_size,
                              hipStream_t stream)
{
    const float* y        = (const float*)d_in[0];
    const float* atoms_p  = (const float*)d_in[1];
    const float* fatoms_p = (const float*)d_in[2];
    const float* beta_p   = (const float*)d_in[3];
    const float* lmbda_p  = (const float*)d_in[4];
    float* out = (float*)d_out;
    float* w = (float*)d_ws;

    size_t off=0;
    float* cb[2];  cb[0]=w+off;  off+=NCOEF; cb[1]=w+off;  off+=NCOEF;   // [b][pix][ch]
    float* ncb[2]; ncb[0]=w+off; off+=NCOEF; ncb[1]=w+off; off+=NCOEF;   // [b][pix][ch]
    float* ncT=w+off;     off+=NCOEF;                                    // [b][ch][pix]
    float* ib[2];  ib[0]=w+off;  off+=NIMG;  ib[1]=w+off;  off+=NIMG;
    float* nib[2]; nib[0]=w+off; off+=NIMG;  nib[1]=w+off; off+=NIMG;
    float* part=w+off;    off+=NPG*NIMG;
    float* red[2]; red[0]=w+off; off+=512; red[1]=w+off; off+=512;
    float* gram=w+off;    off+=6561;
    float* pf=w+off;      off+=6561;
    float* PP=w+off;      off+=6561;
    float* pi=w+off;      off+=512;
    float* af_rn=w+off;   off+=5184;
    float* af_rnT=w+off;  off+=5184;
    float* Mmat=w+off;    off+=4096;
    float* atoms_f=w+off; off+=5184;
    float* atomsT=w+off;  off+=5184;
    float* Xmat=w+off;    off+=4096;
    float* scalars=w+off; off+=32;

    k_prep1<<<dim3(1),dim3(256),0,stream>>>(fatoms_p, beta_p, gram, pf, scalars);
    k_PP<<<dim3(26),dim3(256),0,stream>>>(pf, PP);
    k_impulse<<<dim3(1),dim3(320),0,stream>>>(PP, pi);
    k_dft<<<dim3(256),dim3(64),0,stream>>>(pi, scalars);
    k_atoms1<<<dim3(64),dim3(128),0,stream>>>(atoms_p, gram, af_rn, af_rnT);
    k_M<<<dim3(16),dim3(256),0,stream>>>(af_rn, af_rnT, Mmat);
    k_fin<<<dim3(1),dim3(256),0,stream>>>(Mmat, af_rn, scalars, atoms_f, atomsT, Xmat);

    int p=0;
    for (int k=1; k<=20; ++k){
        float mom = (float)(k-1)/(float)(k+2);
        const float* rin = red[(k-1)&1];
        float* rout = red[k&1];
        const float* img_i  = (k==1)? y : ib[p];
        const float* nimg_i = (k==1)? y : nib[p];
        float* ncT_t = (k==20)? (out+NIMG) : ncT;   // [ch][pix] copy (d_out layout)
        float* nimg_t= (k==20)? out : nib[p^1];
        if (k==1){
            kA<true><<<dim3(128,4),dim3(256),0,stream>>>(cb[p],ncb[p],nimg_i,Xmat,atomsT,
                scalars,lmbda_p,rin, cb[p^1],ncb[p^1],ncT_t,mom);
        } else {
            kA<false><<<dim3(128,4),dim3(256),0,stream>>>(cb[p],ncb[p],nimg_i,Xmat,atomsT,
                scalars,lmbda_p,rin, cb[p^1],ncb[p^1],ncT_t,mom);
        }
        kB1<<<dim3(8,16,4),dim3(256),0,stream>>>(ncT_t, atoms_f, part);
        if (k==1){
            kB2<true><<<dim3(64,4),dim3(256),0,stream>>>(img_i,nimg_i,y,part,pi,scalars,rin,
                ib[p^1],nimg_t,rout,mom);
        } else {
            kB2<false><<<dim3(64,4),dim3(256),0,stream>>>(img_i,nimg_i,y,part,pi,scalars,rin,
                ib[p^1],nimg_t,rout,mom);
        }
        p^=1;
    }
}

// Round 14
// 1413.479 us; speedup vs baseline: 1.4155x; 1.4155x over previous
//
#include <hip/hip_runtime.h>
#include <math.h>

// ---------------------------------------------------------------------------
// Dictionary_56212531970303 : FISTA dictionary forward on MI355X, fp32.
// Layout: coefficient state [b][ch][pix] (kB1-native; round-13 transpose
// experiment: coalescing raised BW 1.3->2.3 TB/s but 256B-stride per-lane
// float4 stores caused write-allocate RMW amplification (FETCH 29->55MB,
// WRITE 32->93MB) -> net loss. Lesson: per-INSTRUCTION contiguity is what
// counts, for stores even more than loads.)
// Loop (20 iters):
//   kA  — 512-thr blocks over 2-row strip; lane = 4 contiguous px (float4),
//         wave = 8-channel slice (weights via wave-uniform s_load). Every
//         c/nc load AND store instruction = 64 lanes x 16B = 1KB contiguous.
//   kB1 — 16 cgroups x 4ch, 8 px/thread (round-9: split channels, not px).
//   kB2 — image update + residual partials (sums 16 partial groups).
// Iter 1 templated FIRST; iter 20 writes nc/img directly into d_out.
// NOTE: every "if (tid<N)" with N>blockDim must be a grid-stride loop —
// round-2/3 regression (absmax 0.134).
// ---------------------------------------------------------------------------

#define NB 4
#define NCH 64
#define NPIX 16384              // 128*128
#define NPB (NCH*NPIX)
#define NCOEF (NB*NCH*NPIX)     // 4194304
#define NIMG  (NB*NPIX)         // 65536
#define NPG 16                  // partial channel-groups (4 ch each)
#define TOLV 1e-4f

#define SC_BETA 0
#define SC_L    1
#define SC_G    4
#define SC_G2   5
#define SC_LPK2 6

// ---------------------------------------------------------------------------
// prep1: one block. bjorck via 8x8 gram-iteration; writes gram + pf + scalars.
__global__ __launch_bounds__(256) void k_prep1(const float* __restrict__ fatoms,
    const float* __restrict__ beta_p,
    float* __restrict__ gram_g, float* __restrict__ pf_g,
    float* __restrict__ scalars)
{
    __shared__ float sW[648], sWf[648];
    __shared__ float sG[64], sP[64], sF[64], sT[64], sTmp[64];
    __shared__ float sGr[6561];
    __shared__ float rs[81];
    __shared__ float sSig;
    int tid = threadIdx.x;
    if (tid==0){ float b=beta_p[0]; scalars[SC_BETA]=(b>0.f)?b:0.f;
                 ((unsigned*)scalars)[SC_LPK2]=0u; }
    for (int e=tid; e<648; e+=256) sW[e]=fatoms[e];
    __syncthreads();
    if (tid<64){ int r=tid>>3, s=tid&7; float a=0.f;
        for (int k=0;k<81;++k) a=fmaf(sW[r*81+k],sW[s*81+k],a); sG[tid]=a; }
    __syncthreads();
    if (tid<64){
        int r8 = tid&7;
        float v = 1.f;
        for (int it=0; it<128; ++it){
            float nv=0.f;
            #pragma unroll
            for (int j=0;j<8;++j) nv = fmaf(sG[r8*8+j], __shfl(v,j,8), nv);
            float m = fabsf(nv);
            m = fmaxf(m, __shfl_xor(m,1,8));
            m = fmaxf(m, __shfl_xor(m,2,8));
            m = fmaxf(m, __shfl_xor(m,4,8));
            v = nv/m;
        }
        float wv=0.f;
        #pragma unroll
        for (int j=0;j<8;++j) wv = fmaf(sG[r8*8+j], __shfl(v,j,8), wv);
        float num=v*wv, den=v*v;
        num += __shfl_xor(num,1,8); num += __shfl_xor(num,2,8); num += __shfl_xor(num,4,8);
        den += __shfl_xor(den,1,8); den += __shfl_xor(den,2,8); den += __shfl_xor(den,4,8);
        if (tid==0) sSig = sqrtf(num/den);
    }
    __syncthreads();
    float inv_s = 1.f/sSig;
    for (int e=tid; e<648; e+=256) sW[e]*=inv_s;
    if (tid<64){ sG[tid]*=inv_s*inv_s; sP[tid]=((tid>>3)==(tid&7))?1.f:0.f; }
    __syncthreads();
    for (int it=0; it<15; ++it){
        if (tid<64) sF[tid] = (((tid>>3)==(tid&7))?1.5f:0.f) - 0.5f*sG[tid];
        __syncthreads();
        if (tid<64){ int r=tid>>3, c=tid&7; float ap=0.f, ag=0.f;
            #pragma unroll
            for (int k=0;k<8;++k){ float f=sF[r*8+k]; ap=fmaf(f,sP[k*8+c],ap); ag=fmaf(f,sG[k*8+c],ag); }
            sTmp[tid]=ap; sT[tid]=ag; }
        __syncthreads();
        if (tid<64){ int r=tid>>3, c=tid&7; float g2=0.f;
            #pragma unroll
            for (int k=0;k<8;++k) g2=fmaf(sT[r*8+k],sF[k*8+c],g2);
            sG[tid]=g2; sP[tid]=sTmp[tid]; }
        __syncthreads();
    }
    for (int e=tid; e<648; e+=256){ int r=e/81, j=e%81; float a=0.f;
        #pragma unroll
        for (int k=0;k<8;++k) a=fmaf(sP[r*8+k], sW[k*81+j], a);
        sWf[e]=a; }
    __syncthreads();
    for (int e=tid; e<6561; e+=256){ int i=e/81, j=e%81; float a=0.f;
        #pragma unroll
        for (int r=0;r<8;++r) a=fmaf(sWf[r*81+i],sWf[r*81+j],a);
        sGr[e]=a; gram_g[e]=a; }
    __syncthreads();
    if (tid<81){ float s=0.f; for (int k=0;k<81;++k) s+=sGr[tid*81+k]; rs[tid]=(1.f-s)/81.f; }
    __syncthreads();
    for (int e=tid; e<6561; e+=256){ int i=e/81, j=e%81;
        pf_g[e] = ((i==j)?1.f:0.f) - sGr[e] - rs[j]; }
}

// PP = pf^T pf (81x81), pf staged in LDS. 26 blocks x 256 thr.
__global__ __launch_bounds__(256) void k_PP(const float* __restrict__ pf, float* __restrict__ PP)
{
    __shared__ float spf[6561];
    for (int e=threadIdx.x; e<6561; e+=256) spf[e]=pf[e];
    __syncthreads();
    int e = blockIdx.x*256 + threadIdx.x;
    if (e>=6561) return;
    int al=e/81, be=e%81; float a=0.f;
    for (int c=0;c<81;++c) a=fmaf(spf[c*81+al], spf[c*81+be], a);
    PP[e]=a;
}

// proj_impulse (17x17) via PP lookups. One block, 320 thr (guard: t<289).
__global__ void k_impulse(const float* __restrict__ PP, float* __restrict__ pi)
{
    int t = threadIdx.x;
    if (t>=289) return;
    int h=t/17, w=t%17;
    float acc=0.f;
    for (int p=0;p<9;++p){
        int i2=(h+p-4+17)%17;
        if (i2<4||i2>12) continue;
        for (int q=0;q<9;++q){
            int j2=(w+q-4+17)%17;
            if (j2<4||j2>12) continue;
            int al=(12-i2)*9+(12-j2);
            int be=(8-p)*9+(8-q);
            acc += PP[al*81+be];
        }
    }
    pi[t]=acc;
}

// |FFT2(pi zero-padded to 128x128)|^2 max. 256 blocks x 64 thr (1 wave).
__global__ __launch_bounds__(64) void k_dft(const float* __restrict__ pi, float* __restrict__ scalars)
{
    __shared__ float spi[289], ct[128], st[128];
    int tid=threadIdx.x; int gid=blockIdx.x*64+tid;
    for (int e=tid; e<289; e+=64) spi[e]=pi[e];
    for (int e=tid; e<128; e+=64){ float ang=(float)e*(6.28318530717958647692f/128.f);
                  ct[e]=cosf(ang); st[e]=sinf(ang); }
    __syncthreads();
    int u=gid>>7, v=gid&127;
    float re=0.f, im=0.f;
    for (int i=0;i<17;++i){
        int ku=(u*i)&127;
        const float* prow=spi+i*17;
        for (int j=0;j<17;++j){
            int k=(ku+v*j)&127;
            float x=prow[j];
            re=fmaf(x,ct[k],re); im=fmaf(x,st[k],im);
        }
    }
    float m2=re*re+im*im;
    #pragma unroll
    for (int d=32; d; d>>=1) m2=fmaxf(m2, __shfl_down(m2,d));
    if (tid==0) atomicMax(((unsigned*)scalars)+SC_LPK2, __float_as_uint(m2));
}

// per-atom: center, subtract af@gram, row-normalize. Writes af_rn AND af_rnT.
__global__ __launch_bounds__(128) void k_atoms1(const float* __restrict__ atoms_in,
    const float* __restrict__ gram, float* __restrict__ af_rn, float* __restrict__ af_rnT)
{
    int a=blockIdx.x, tid=threadIdx.x;
    __shared__ float a0[81], a1[81], rbuf[128];
    float v = (tid<81)? atoms_in[a*81+tid] : 0.f;
    rbuf[tid]=v; __syncthreads();
    for (int off=64; off; off>>=1){ if (tid<off) rbuf[tid]+=rbuf[tid+off]; __syncthreads(); }
    float mean = rbuf[0]/81.f;
    __syncthreads();
    if (tid<81) a0[tid]=v-mean;
    __syncthreads();
    float w=0.f;
    if (tid<81){ float dot=0.f;
        for (int k=0;k<81;++k) dot=fmaf(a0[k], gram[k*81+tid], dot);
        w=a0[tid]-dot; a1[tid]=w; }
    rbuf[tid]=(tid<81)? w*w : 0.f;
    __syncthreads();
    for (int off=64; off; off>>=1){ if (tid<off) rbuf[tid]+=rbuf[tid+off]; __syncthreads(); }
    float inv = 1.f/sqrtf(rbuf[0]);
    if (tid<81){ float r=a1[tid]*inv; af_rn[a*81+tid]=r; af_rnT[tid*64+a]=r; }
}

// M = af_rn af_rn^T. 16 blocks x 256.
__global__ __launch_bounds__(256) void k_M(const float* __restrict__ af_rn,
    const float* __restrict__ af_rnT, float* __restrict__ M)
{
    int e=blockIdx.x*256+threadIdx.x;
    int i=e>>6, j=e&63;
    float a=0.f;
    for (int k=0;k<81;++k) a=fmaf(af_rn[i*81+k], af_rnT[(k<<6)+j], a);
    M[e]=a;
}

// k_fin: one block. A=M^2, power 48 on A, Rayleigh with M, finalize.
__global__ __launch_bounds__(256) void k_fin(const float* __restrict__ Mg,
    const float* __restrict__ af_rn, float* __restrict__ scalars,
    float* __restrict__ atoms_f, float* __restrict__ atomsT, float* __restrict__ Xmat)
{
    __shared__ __align__(16) float sM [64*68];
    __shared__ __align__(16) float sA [64*68];
    __shared__ float sGc[2];
    int tid=threadIdx.x;
    for (int e=tid; e<4096; e+=256) sM[(e>>6)*68+(e&63)]=Mg[e];
    for (int e=tid; e<64*68; e+=256){ if ((e%68)>=64) sM[e]=0.f; }
    __syncthreads();
    for (int e=tid; e<4096; e+=256){
        int i=e>>6, j=e&63;
        const float4* ri = reinterpret_cast<const float4*>(sM + i*68);
        const float4* rj = reinterpret_cast<const float4*>(sM + j*68);
        float a0=0.f,a1=0.f,a2=0.f,a3=0.f;
        #pragma unroll
        for (int k=0;k<16;++k){
            float4 x=ri[k], y=rj[k];
            a0=fmaf(x.x,y.x,a0); a1=fmaf(x.y,y.y,a1);
            a2=fmaf(x.z,y.z,a2); a3=fmaf(x.w,y.w,a3);
        }
        sA[i*68+j]=(a0+a1)+(a2+a3);
    }
    __syncthreads();
    if (tid<64){
        float m[64];
        #pragma unroll
        for (int j=0;j<64;++j) m[j]=sA[tid*68+j];
        float v = 1.0f + 0.01f*(float)tid;
        for (int it=0; it<48; ++it){
            float a0=0.f,a1=0.f,a2=0.f,a3=0.f;
            #pragma unroll
            for (int j=0;j<64;j+=4){
                a0=fmaf(m[j+0], __shfl(v,j+0), a0);
                a1=fmaf(m[j+1], __shfl(v,j+1), a1);
                a2=fmaf(m[j+2], __shfl(v,j+2), a2);
                a3=fmaf(m[j+3], __shfl(v,j+3), a3);
            }
            float nv=(a0+a1)+(a2+a3);
            float mx=fabsf(nv);
            #pragma unroll
            for (int d=1; d<64; d<<=1) mx=fmaxf(mx, __shfl_xor(mx,d));
            v=nv/mx;
        }
        float w0=0.f,w1=0.f,w2=0.f,w3=0.f;
        #pragma unroll
        for (int j=0;j<64;j+=4){
            w0=fmaf(sM[tid*68+j+0], __shfl(v,j+0), w0);
            w1=fmaf(sM[tid*68+j+1], __shfl(v,j+1), w1);
            w2=fmaf(sM[tid*68+j+2], __shfl(v,j+2), w2);
            w3=fmaf(sM[tid*68+j+3], __shfl(v,j+3), w3);
        }
        float wv=(w0+w1)+(w2+w3);
        float num=v*wv, den=v*v;
        #pragma unroll
        for (int d=1; d<64; d<<=1){ num+=__shfl_xor(num,d); den+=__shfl_xor(den,d); }
        if (tid==0){
            float sig = sqrtf(num/den);
            float b = scalars[SC_BETA];
            float s = sqrtf(0.99f/fmaxf(b,0.1f));
            float g = s/sig;
            scalars[SC_G]=g; scalars[SC_G2]=g*g;
            float lpk = sqrtf(__uint_as_float(((unsigned*)scalars)[SC_LPK2]));
            scalars[SC_L] = 1.01f*b*lpk;
            sGc[0]=g; sGc[1]=g*g;
        }
    }
    __syncthreads();
    float g=sGc[0], g2=sGc[1];
    for (int idx=tid; idx<5184; idx+=256){
        int a=idx/81, pq=idx-a*81;
        float v=g*af_rn[idx];
        atoms_f[idx]=v;
        atomsT[pq*64+a]=v;
    }
    for (int e=tid; e<4096; e+=256) Xmat[e]=g2*sM[(e>>6)*68+(e&63)];
}

// ---------------------------------------------------------------------------
// kA: coefficient update, [b][ch][pix] layout. grid (strip,b) = (64,4),
// 512 thr: wave wv (0..7) owns 8 output channels; lane owns 4 contiguous
// pixels of the 2-row strip. All c/nc loads+stores: 64 lanes x float4 =
// 1KB contiguous per instruction. Weights via wave-uniform s_load.
template<bool FIRST>
__global__ __launch_bounds__(512) void kA(const float* __restrict__ c_in,
    const float* __restrict__ nc_in, const float* __restrict__ nimg,
    const float* __restrict__ Xmat, const float* __restrict__ atomsT,
    const float* __restrict__ scalars, const float* __restrict__ lmbda_p,
    const float* __restrict__ red_in,
    float* __restrict__ c_out, float* __restrict__ nc_out, float mom)
{
    int b=blockIdx.y, st=blockIdx.x;
    int tid=threadIdx.x;
    int wv = __builtin_amdgcn_readfirstlane(tid>>6);   // wave id 0..7
    int lane = tid&63;
    int co = wv*8;                                      // 8-channel slice
    int h0 = st*2;
    int px = lane*4;                                    // 0..252 (4-aligned)
    int prow = px>>7, pcol = px&127;                    // never crosses a row
    __shared__ float simg[10*128];
    __shared__ float sAct;
    if (FIRST){ if (tid==0) sAct=1.f; }
    else if (tid<64){
        float sd=red_in[(b<<7)+(tid<<1)], si=red_in[(b<<7)+(tid<<1)+1];
        #pragma unroll
        for (int off=32; off; off>>=1){ sd+=__shfl_down(sd,off); si+=__shfl_down(si,off); }
        if (tid==0) sAct = (sd > TOLV*TOLV*si) ? 1.f : 0.f;
    }
    for (int e=tid; e<1280; e+=512)
        simg[e]=nimg[b*NPIX + (((h0-4+(e>>7))&127)<<7) + (e&127)];
    __syncthreads();
    size_t pbase = (size_t)b*NPB + (h0<<7) + px;        // strip-linear pixel
    const float* Xo = Xmat + co;                        // wave-uniform
    const float* Ao = atomsT + co;
    float acc[32];                                      // [oc][j]
    #pragma unroll
    for (int i=0;i<32;++i) acc[i]=0.f;
    if (!FIRST){
        for (int c=0;c<64;++c){
            float4 cv=*reinterpret_cast<const float4*>(c_in + pbase + (size_t)c*NPIX);
            float4 nv=*reinterpret_cast<const float4*>(nc_in + pbase + (size_t)c*NPIX);
            float t0=fmaf(mom,nv.x-cv.x,nv.x);
            float t1=fmaf(mom,nv.y-cv.y,nv.y);
            float t2=fmaf(mom,nv.z-cv.z,nv.z);
            float t3=fmaf(mom,nv.w-cv.w,nv.w);
            const float* Xr = Xo + (c<<6);              // s_load 8 floats
            #pragma unroll
            for (int oc=0;oc<8;++oc){
                float x=Xr[oc];
                acc[oc*4+0]=fmaf(x,t0,acc[oc*4+0]);
                acc[oc*4+1]=fmaf(x,t1,acc[oc*4+1]);
                acc[oc*4+2]=fmaf(x,t2,acc[oc*4+2]);
                acc[oc*4+3]=fmaf(x,t3,acc[oc*4+3]);
            }
        }
    }
    // conv phase: in12 window per p-row (3 aligned float4 from LDS)
    for (int p=0;p<9;++p){
        const float* srow = simg + (prow+p)*128;
        float in12[12];
        #pragma unroll
        for (int k4=0;k4<3;++k4){
            int col=(pcol-4+(k4<<2))&127;               // 4-aligned, no wrap inside
            const float4 vv=*reinterpret_cast<const float4*>(srow+col);
            in12[k4*4+0]=vv.x; in12[k4*4+1]=vv.y;
            in12[k4*4+2]=vv.z; in12[k4*4+3]=vv.w;
        }
        #pragma unroll 3
        for (int q=0;q<9;++q){
            const float* Ar = Ao + ((p*9+q)<<6);        // s_load 8 floats
            #pragma unroll
            for (int oc=0;oc<8;++oc){
                float a=Ar[oc];
                acc[oc*4+0]=fmaf(a,-in12[q+0],acc[oc*4+0]);
                acc[oc*4+1]=fmaf(a,-in12[q+1],acc[oc*4+1]);
                acc[oc*4+2]=fmaf(a,-in12[q+2],acc[oc*4+2]);
                acc[oc*4+3]=fmaf(a,-in12[q+3],acc[oc*4+3]);
            }
        }
    }
    float beta=scalars[SC_BETA], lmb=lmbda_p[0];
    bool act = (sAct!=0.f);
    #pragma unroll
    for (int oc=0;oc<8;++oc){
        size_t a = pbase + (size_t)(co+oc)*NPIX;
        float4 nv, cv;
        if (FIRST){ nv=make_float4(0.f,0.f,0.f,0.f); cv=nv; }
        else {
            nv=*reinterpret_cast<const float4*>(nc_in + a);
            cv=*reinterpret_cast<const float4*>(c_in  + a);
        }
        float4 nw, cw;
        {
            float t=FIRST?0.f:fmaf(mom,nv.x-cv.x,nv.x);
            float u=fmaf(-beta,acc[oc*4+0],t); float au=fabsf(u)-lmb;
            u=(au>0.f)?copysignf(au,u):0.f; nw.x=act?u:nv.x; cw.x=act?nv.x:cv.x;
        }{
            float t=FIRST?0.f:fmaf(mom,nv.y-cv.y,nv.y);
            float u=fmaf(-beta,acc[oc*4+1],t); float au=fabsf(u)-lmb;
            u=(au>0.f)?copysignf(au,u):0.f; nw.y=act?u:nv.y; cw.y=act?nv.y:cv.y;
        }{
            float t=FIRST?0.f:fmaf(mom,nv.z-cv.z,nv.z);
            float u=fmaf(-beta,acc[oc*4+2],t); float au=fabsf(u)-lmb;
            u=(au>0.f)?copysignf(au,u):0.f; nw.z=act?u:nv.z; cw.z=act?nv.z:cv.z;
        }{
            float t=FIRST?0.f:fmaf(mom,nv.w-cv.w,nv.w);
            float u=fmaf(-beta,acc[oc*4+3],t); float au=fabsf(u)-lmb;
            u=(au>0.f)?copysignf(au,u):0.f; nw.w=act?u:nv.w; cw.w=act?nv.w:cv.w;
        }
        *reinterpret_cast<float4*>(c_out  + a) = cw;
        *reinterpret_cast<float4*>(nc_out + a) = nw;
    }
}

// kB1: dict_pred partials, CHANNEL-split. grid (8 rowblk, 16 cgroup, 4 b)
// = 512 blocks of 256 thr. 16 rows/block, 8 px/thread, 4 ch per cgroup.
__global__ __launch_bounds__(256,4) void kB1(const float* __restrict__ nc2,
    const float* __restrict__ atoms_f, float* __restrict__ part)
{
    int b=blockIdx.z, cg=blockIdx.y, pb=blockIdx.x;
    int t=threadIdx.x;
    int row = pb*16 + (t>>4);
    int cb  = (t&15)*8;
    const float* src = nc2 + (b*NCH + cg*4)*NPIX;
    float acc[8];
    #pragma unroll
    for (int k=0;k<8;++k) acc[k]=0.f;
    for (int c=0;c<4;++c){
        const float* chan = src + c*NPIX;
        const float* arow = atoms_f + (cg*4+c)*81;
        #pragma unroll 3
        for (int p=0;p<9;++p){
            int r=(row+4-p)&127;
            const float* rp_ = chan + (r<<7);
            float in16[16];
            #pragma unroll
            for (int k4=0;k4<4;++k4){
                int col=(cb-4+(k4<<2))&127;
                const float4 vv = *reinterpret_cast<const float4*>(rp_+col);
                in16[(k4<<2)+0]=vv.x; in16[(k4<<2)+1]=vv.y;
                in16[(k4<<2)+2]=vv.z; in16[(k4<<2)+3]=vv.w;
            }
            #pragma unroll
            for (int q=0;q<9;++q){
                float a = arow[p*9+q];
                #pragma unroll
                for (int k=0;k<8;++k) acc[k]=fmaf(in16[k+8-q], a, acc[k]);
            }
        }
    }
    float* dst = part + (cg*NB+b)*NPIX + (row<<7) + cb;
    #pragma unroll
    for (int k=0;k<8;++k) dst[k]=acc[k];
}

// kB2: image update + residual block partials (+ in-block active flag)
template<bool FIRST>
__global__ __launch_bounds__(256) void kB2(const float* __restrict__ img,
    const float* __restrict__ nimg, const float* __restrict__ y,
    const float* __restrict__ part, const float* __restrict__ pi,
    const float* __restrict__ scalars, const float* __restrict__ red_in,
    float* __restrict__ img_out, float* __restrict__ nimg_out,
    float* __restrict__ red_out, float mom)
{
    int b=blockIdx.y, rp=blockIdx.x;
    int tid=threadIdx.x, ty=tid>>7, w=tid&127;
    int h0=rp*2;
    __shared__ float sti[18*128];
    __shared__ float spi[289];
    __shared__ float rsd[4], rsi[4];
    __shared__ float sAct;
    if (FIRST){ if (tid==0) sAct=1.f; }
    else if (tid<64){
        float sd=red_in[(b<<7)+(tid<<1)], si=red_in[(b<<7)+(tid<<1)+1];
        #pragma unroll
        for (int off=32; off; off>>=1){ sd+=__shfl_down(sd,off); si+=__shfl_down(si,off); }
        if (tid==0) sAct = (sd > TOLV*TOLV*si) ? 1.f : 0.f;
    }
    const float* ib  = img  + b*NPIX;
    const float* nib = nimg + b*NPIX;
    for (int e=tid; e<2304; e+=256){
        int r=e>>7, cc=e&127;
        int idx=(((h0-8+r)&127)<<7)+cc;
        float nv=nib[idx], v=ib[idx];
        sti[e]=fmaf(mom, nv-v, nv);
    }
    for (int e=tid; e<289; e+=256) spi[e]=pi[e];
    __syncthreads();
    float sp=0.f;
    for (int p=0;p<17;++p){
        const float* srow = sti + (ty+p)*128;
        const float* pr = spi + p*17;
        #pragma unroll
        for (int q=0;q<17;++q) sp=fmaf(srow[(w+q-8)&127], pr[q], sp);
    }
    int pix=((h0+ty)<<7)+w;
    float dp=0.f;
    #pragma unroll
    for (int g=0; g<NPG; ++g) dp += part[(g*NB+b)*NPIX + pix];
    float ti = sti[(ty+8)*128 + w];
    float beta=scalars[SC_BETA], L=scalars[SC_L];
    float yv=y[b*NPIX+pix];
    float upd = ti - (ti - yv + beta*(sp - dp))/L;
    bool act = (sAct!=0.f);
    float iv=ib[pix], niv=nib[pix];
    float i2 = act? niv : iv;
    float ni2 = act? upd : niv;
    img_out[b*NPIX+pix]=i2;
    nimg_out[b*NPIX+pix]=ni2;
    float d=i2-ni2;
    float sd=d*d, si=i2*i2;
    #pragma unroll
    for (int off=32; off; off>>=1){ sd+=__shfl_down(sd,off); si+=__shfl_down(si,off); }
    if ((tid&63)==0){ rsd[tid>>6]=sd; rsi[tid>>6]=si; }
    __syncthreads();
    if (tid==0){
        float a=rsd[0]+rsd[1]+rsd[2]+rsd[3];
        float c2=rsi[0]+rsi[1]+rsi[2]+rsi[3];
        red_out[(b<<7)+(rp<<1)+0]=a;
        red_out[(b<<7)+(rp<<1)+1]=c2;
    }
}

// ---------------------------------------------------------------------------
extern "C" void kernel_launch(void* const* d_in, const int* in_sizes, int n_in,
                              void* d_out, int out_size, void* d_ws, size_t ws_size,
                              hipStream_t stream)
{
    const float* y        = (const float*)d_in[0];
    const float* atoms_p  = (const float*)d_in[1];
    const float* fatoms_p = (const float*)d_in[2];
    const float* beta_p   = (const float*)d_in[3];
    const float* lmbda_p  = (const float*)d_in[4];
    float* out = (float*)d_out;
    float* w = (float*)d_ws;

    size_t off=0;
    float* cb[2];  cb[0]=w+off;  off+=NCOEF; cb[1]=w+off;  off+=NCOEF;   // [b][ch][pix]
    float* ncb[2]; ncb[0]=w+off; off+=NCOEF; ncb[1]=w+off; off+=NCOEF;   // [b][ch][pix]
    float* ib[2];  ib[0]=w+off;  off+=NIMG;  ib[1]=w+off;  off+=NIMG;
    float* nib[2]; nib[0]=w+off; off+=NIMG;  nib[1]=w+off; off+=NIMG;
    float* part=w+off;    off+=NPG*NIMG;
    float* red[2]; red[0]=w+off; off+=512; red[1]=w+off; off+=512;
    float* gram=w+off;    off+=6561;
    float* pf=w+off;      off+=6561;
    float* PP=w+off;      off+=6561;
    float* pi=w+off;      off+=512;
    float* af_rn=w+off;   off+=5184;
    float* af_rnT=w+off;  off+=5184;
    float* Mmat=w+off;    off+=4096;
    float* atoms_f=w+off; off+=5184;
    float* atomsT=w+off;  off+=5184;
    float* Xmat=w+off;    off+=4096;
    float* scalars=w+off; off+=32;

    k_prep1<<<dim3(1),dim3(256),0,stream>>>(fatoms_p, beta_p, gram, pf, scalars);
    k_PP<<<dim3(26),dim3(256),0,stream>>>(pf, PP);
    k_impulse<<<dim3(1),dim3(320),0,stream>>>(PP, pi);
    k_dft<<<dim3(256),dim3(64),0,stream>>>(pi, scalars);
    k_atoms1<<<dim3(64),dim3(128),0,stream>>>(atoms_p, gram, af_rn, af_rnT);
    k_M<<<dim3(16),dim3(256),0,stream>>>(af_rn, af_rnT, Mmat);
    k_fin<<<dim3(1),dim3(256),0,stream>>>(Mmat, af_rn, scalars, atoms_f, atomsT, Xmat);

    int p=0;
    for (int k=1; k<=20; ++k){
        float mom = (float)(k-1)/(float)(k+2);
        const float* rin = red[(k-1)&1];
        float* rout = red[k&1];
        const float* img_i  = (k==1)? y : ib[p];
        const float* nimg_i = (k==1)? y : nib[p];
        float* nc_t  = (k==20)? (out+NIMG) : ncb[p^1];
        float* nimg_t= (k==20)? out : nib[p^1];
        if (k==1){
            kA<true><<<dim3(64,4),dim3(512),0,stream>>>(cb[p],ncb[p],nimg_i,Xmat,atomsT,
                scalars,lmbda_p,rin, cb[p^1],nc_t,mom);
        } else {
            kA<false><<<dim3(64,4),dim3(512),0,stream>>>(cb[p],ncb[p],nimg_i,Xmat,atomsT,
                scalars,lmbda_p,rin, cb[p^1],nc_t,mom);
        }
        kB1<<<dim3(8,16,4),dim3(256),0,stream>>>(nc_t, atoms_f, part);
        if (k==1){
            kB2<true><<<dim3(64,4),dim3(256),0,stream>>>(img_i,nimg_i,y,part,pi,scalars,rin,
                ib[p^1],nimg_t,rout,mom);
        } else {
            kB2<false><<<dim3(64,4),dim3(256),0,stream>>>(img_i,nimg_i,y,part,pi,scalars,rin,
                ib[p^1],nimg_t,rout,mom);
        }
        p^=1;
    }
}

// Round 15
// 1389.076 us; speedup vs baseline: 1.4404x; 1.0176x over previous
//
#include <hip/hip_runtime.h>
#include <math.h>

// ---------------------------------------------------------------------------
// Dictionary_56212531970303 : FISTA dictionary forward on MI355X, fp32.
// Layout: coefficient state [b][ch][pix]. Per-INSTRUCTION contiguity rule
// (round-13): every state load/store = 64 lanes x float4 = 1KB contiguous.
// Setup: prep1, k_PP, k_impulse, k_dft, atoms1, k_M, k_M2 (grid M^2 —
//        round-14: single-block LDS matmul in k_fin was 45us, same
//        single-block-Gram pathology as rounds 4-8), k_fin (slim).
// Loop (20 iters):
//   kA  — 512-thr blocks over 2-row strip; lane = 4 contiguous px (float4),
//         wave = 8-channel slice, weights via wave-uniform s_load.
//   kB1 — 16 cgroups x 4ch, 8 px/thread (round-9: split channels, not px).
//   kB2 — 512-thr blocks (round-14: was 1 wave/SIMD, round-5 floor): 17-tap
//         conv split across two 256-thr halves, merged via LDS.
// Iter 1 templated FIRST; iter 20 writes nc/img directly into d_out.
// NOTE: every "if (tid<N)" with N>blockDim must be a grid-stride loop —
// round-2/3 regression (absmax 0.134).
// ---------------------------------------------------------------------------

#define NB 4
#define NCH 64
#define NPIX 16384              // 128*128
#define NPB (NCH*NPIX)
#define NCOEF (NB*NCH*NPIX)     // 4194304
#define NIMG  (NB*NPIX)         // 65536
#define NPG 16                  // partial channel-groups (4 ch each)
#define TOLV 1e-4f

#define SC_BETA 0
#define SC_L    1
#define SC_G    4
#define SC_G2   5
#define SC_LPK2 6

// ---------------------------------------------------------------------------
// prep1: one block. bjorck via 8x8 gram-iteration; writes gram + pf + scalars.
__global__ __launch_bounds__(256) void k_prep1(const float* __restrict__ fatoms,
    const float* __restrict__ beta_p,
    float* __restrict__ gram_g, float* __restrict__ pf_g,
    float* __restrict__ scalars)
{
    __shared__ float sW[648], sWf[648];
    __shared__ float sG[64], sP[64], sF[64], sT[64], sTmp[64];
    __shared__ float sGr[6561];
    __shared__ float rs[81];
    __shared__ float sSig;
    int tid = threadIdx.x;
    if (tid==0){ float b=beta_p[0]; scalars[SC_BETA]=(b>0.f)?b:0.f;
                 ((unsigned*)scalars)[SC_LPK2]=0u; }
    for (int e=tid; e<648; e+=256) sW[e]=fatoms[e];
    __syncthreads();
    if (tid<64){ int r=tid>>3, s=tid&7; float a=0.f;
        for (int k=0;k<81;++k) a=fmaf(sW[r*81+k],sW[s*81+k],a); sG[tid]=a; }
    __syncthreads();
    if (tid<64){
        int r8 = tid&7;
        float v = 1.f;
        for (int it=0; it<128; ++it){
            float nv=0.f;
            #pragma unroll
            for (int j=0;j<8;++j) nv = fmaf(sG[r8*8+j], __shfl(v,j,8), nv);
            float m = fabsf(nv);
            m = fmaxf(m, __shfl_xor(m,1,8));
            m = fmaxf(m, __shfl_xor(m,2,8));
            m = fmaxf(m, __shfl_xor(m,4,8));
            v = nv/m;
        }
        float wv=0.f;
        #pragma unroll
        for (int j=0;j<8;++j) wv = fmaf(sG[r8*8+j], __shfl(v,j,8), wv);
        float num=v*wv, den=v*v;
        num += __shfl_xor(num,1,8); num += __shfl_xor(num,2,8); num += __shfl_xor(num,4,8);
        den += __shfl_xor(den,1,8); den += __shfl_xor(den,2,8); den += __shfl_xor(den,4,8);
        if (tid==0) sSig = sqrtf(num/den);
    }
    __syncthreads();
    float inv_s = 1.f/sSig;
    for (int e=tid; e<648; e+=256) sW[e]*=inv_s;
    if (tid<64){ sG[tid]*=inv_s*inv_s; sP[tid]=((tid>>3)==(tid&7))?1.f:0.f; }
    __syncthreads();
    for (int it=0; it<15; ++it){
        if (tid<64) sF[tid] = (((tid>>3)==(tid&7))?1.5f:0.f) - 0.5f*sG[tid];
        __syncthreads();
        if (tid<64){ int r=tid>>3, c=tid&7; float ap=0.f, ag=0.f;
            #pragma unroll
            for (int k=0;k<8;++k){ float f=sF[r*8+k]; ap=fmaf(f,sP[k*8+c],ap); ag=fmaf(f,sG[k*8+c],ag); }
            sTmp[tid]=ap; sT[tid]=ag; }
        __syncthreads();
        if (tid<64){ int r=tid>>3, c=tid&7; float g2=0.f;
            #pragma unroll
            for (int k=0;k<8;++k) g2=fmaf(sT[r*8+k],sF[k*8+c],g2);
            sG[tid]=g2; sP[tid]=sTmp[tid]; }
        __syncthreads();
    }
    for (int e=tid; e<648; e+=256){ int r=e/81, j=e%81; float a=0.f;
        #pragma unroll
        for (int k=0;k<8;++k) a=fmaf(sP[r*8+k], sW[k*81+j], a);
        sWf[e]=a; }
    __syncthreads();
    for (int e=tid; e<6561; e+=256){ int i=e/81, j=e%81; float a=0.f;
        #pragma unroll
        for (int r=0;r<8;++r) a=fmaf(sWf[r*81+i],sWf[r*81+j],a);
        sGr[e]=a; gram_g[e]=a; }
    __syncthreads();
    if (tid<81){ float s=0.f; for (int k=0;k<81;++k) s+=sGr[tid*81+k]; rs[tid]=(1.f-s)/81.f; }
    __syncthreads();
    for (int e=tid; e<6561; e+=256){ int i=e/81, j=e%81;
        pf_g[e] = ((i==j)?1.f:0.f) - sGr[e] - rs[j]; }
}

// PP = pf^T pf (81x81), pf staged in LDS. 26 blocks x 256 thr.
__global__ __launch_bounds__(256) void k_PP(const float* __restrict__ pf, float* __restrict__ PP)
{
    __shared__ float spf[6561];
    for (int e=threadIdx.x; e<6561; e+=256) spf[e]=pf[e];
    __syncthreads();
    int e = blockIdx.x*256 + threadIdx.x;
    if (e>=6561) return;
    int al=e/81, be=e%81; float a=0.f;
    for (int c=0;c<81;++c) a=fmaf(spf[c*81+al], spf[c*81+be], a);
    PP[e]=a;
}

// proj_impulse (17x17) via PP lookups. One block, 320 thr (guard: t<289).
__global__ void k_impulse(const float* __restrict__ PP, float* __restrict__ pi)
{
    int t = threadIdx.x;
    if (t>=289) return;
    int h=t/17, w=t%17;
    float acc=0.f;
    for (int p=0;p<9;++p){
        int i2=(h+p-4+17)%17;
        if (i2<4||i2>12) continue;
        for (int q=0;q<9;++q){
            int j2=(w+q-4+17)%17;
            if (j2<4||j2>12) continue;
            int al=(12-i2)*9+(12-j2);
            int be=(8-p)*9+(8-q);
            acc += PP[al*81+be];
        }
    }
    pi[t]=acc;
}

// |FFT2(pi zero-padded to 128x128)|^2 max. 256 blocks x 64 thr (1 wave).
__global__ __launch_bounds__(64) void k_dft(const float* __restrict__ pi, float* __restrict__ scalars)
{
    __shared__ float spi[289], ct[128], st[128];
    int tid=threadIdx.x; int gid=blockIdx.x*64+tid;
    for (int e=tid; e<289; e+=64) spi[e]=pi[e];
    for (int e=tid; e<128; e+=64){ float ang=(float)e*(6.28318530717958647692f/128.f);
                  ct[e]=cosf(ang); st[e]=sinf(ang); }
    __syncthreads();
    int u=gid>>7, v=gid&127;
    float re=0.f, im=0.f;
    for (int i=0;i<17;++i){
        int ku=(u*i)&127;
        const float* prow=spi+i*17;
        for (int j=0;j<17;++j){
            int k=(ku+v*j)&127;
            float x=prow[j];
            re=fmaf(x,ct[k],re); im=fmaf(x,st[k],im);
        }
    }
    float m2=re*re+im*im;
    #pragma unroll
    for (int d=32; d; d>>=1) m2=fmaxf(m2, __shfl_down(m2,d));
    if (tid==0) atomicMax(((unsigned*)scalars)+SC_LPK2, __float_as_uint(m2));
}

// per-atom: center, subtract af@gram, row-normalize. Writes af_rn AND af_rnT.
__global__ __launch_bounds__(128) void k_atoms1(const float* __restrict__ atoms_in,
    const float* __restrict__ gram, float* __restrict__ af_rn, float* __restrict__ af_rnT)
{
    int a=blockIdx.x, tid=threadIdx.x;
    __shared__ float a0[81], a1[81], rbuf[128];
    float v = (tid<81)? atoms_in[a*81+tid] : 0.f;
    rbuf[tid]=v; __syncthreads();
    for (int off=64; off; off>>=1){ if (tid<off) rbuf[tid]+=rbuf[tid+off]; __syncthreads(); }
    float mean = rbuf[0]/81.f;
    __syncthreads();
    if (tid<81) a0[tid]=v-mean;
    __syncthreads();
    float w=0.f;
    if (tid<81){ float dot=0.f;
        for (int k=0;k<81;++k) dot=fmaf(a0[k], gram[k*81+tid], dot);
        w=a0[tid]-dot; a1[tid]=w; }
    rbuf[tid]=(tid<81)? w*w : 0.f;
    __syncthreads();
    for (int off=64; off; off>>=1){ if (tid<off) rbuf[tid]+=rbuf[tid+off]; __syncthreads(); }
    float inv = 1.f/sqrtf(rbuf[0]);
    if (tid<81){ float r=a1[tid]*inv; af_rn[a*81+tid]=r; af_rnT[tid*64+a]=r; }
}

// M = af_rn af_rn^T. 16 blocks x 256.
__global__ __launch_bounds__(256) void k_M(const float* __restrict__ af_rn,
    const float* __restrict__ af_rnT, float* __restrict__ M)
{
    int e=blockIdx.x*256+threadIdx.x;
    int i=e>>6, j=e&63;
    float a=0.f;
    for (int k=0;k<81;++k) a=fmaf(af_rn[i*81+k], af_rnT[(k<<6)+j], a);
    M[e]=a;
}

// M2 = M*M (M symmetric -> row-row). 16 blocks x 256, k_M recipe:
// row i wave-uniform s_load, M[k*64+j] coalesced per lane.
__global__ __launch_bounds__(256) void k_M2(const float* __restrict__ M,
    float* __restrict__ M2)
{
    int e=blockIdx.x*256+threadIdx.x;
    int i=e>>6, j=e&63;
    float a=0.f;
    for (int k=0;k<64;++k) a=fmaf(M[(i<<6)+k], M[(k<<6)+j], a);
    M2[e]=a;
}

// k_fin: one block, slim. Power 48 on M^2 (rows from global), Rayleigh
// with M (LDS-staged), finalize atoms_f / atomsT / Xmat / scalars.
__global__ __launch_bounds__(256) void k_fin(const float* __restrict__ Mg,
    const float* __restrict__ M2g, const float* __restrict__ af_rn,
    float* __restrict__ scalars,
    float* __restrict__ atoms_f, float* __restrict__ atomsT, float* __restrict__ Xmat)
{
    __shared__ float sM[4096];
    __shared__ float sGc[2];
    int tid=threadIdx.x;
    for (int e=tid; e<4096; e+=256) sM[e]=Mg[e];
    __syncthreads();
    if (tid<64){
        float m[64];
        #pragma unroll
        for (int j=0;j<64;++j) m[j]=M2g[(tid<<6)+j];
        float v = 1.0f + 0.01f*(float)tid;
        for (int it=0; it<48; ++it){
            float a0=0.f,a1=0.f,a2=0.f,a3=0.f;
            #pragma unroll
            for (int j=0;j<64;j+=4){
                a0=fmaf(m[j+0], __shfl(v,j+0), a0);
                a1=fmaf(m[j+1], __shfl(v,j+1), a1);
                a2=fmaf(m[j+2], __shfl(v,j+2), a2);
                a3=fmaf(m[j+3], __shfl(v,j+3), a3);
            }
            float nv=(a0+a1)+(a2+a3);
            float mx=fabsf(nv);
            #pragma unroll
            for (int d=1; d<64; d<<=1) mx=fmaxf(mx, __shfl_xor(mx,d));
            v=nv/mx;
        }
        float w0=0.f,w1=0.f,w2=0.f,w3=0.f;
        #pragma unroll
        for (int j=0;j<64;j+=4){
            w0=fmaf(sM[(tid<<6)+j+0], __shfl(v,j+0), w0);
            w1=fmaf(sM[(tid<<6)+j+1], __shfl(v,j+1), w1);
            w2=fmaf(sM[(tid<<6)+j+2], __shfl(v,j+2), w2);
            w3=fmaf(sM[(tid<<6)+j+3], __shfl(v,j+3), w3);
        }
        float wv=(w0+w1)+(w2+w3);
        float num=v*wv, den=v*v;
        #pragma unroll
        for (int d=1; d<64; d<<=1){ num+=__shfl_xor(num,d); den+=__shfl_xor(den,d); }
        if (tid==0){
            float sig = sqrtf(num/den);
            float b = scalars[SC_BETA];
            float s = sqrtf(0.99f/fmaxf(b,0.1f));
            float g = s/sig;
            scalars[SC_G]=g; scalars[SC_G2]=g*g;
            float lpk = sqrtf(__uint_as_float(((unsigned*)scalars)[SC_LPK2]));
            scalars[SC_L] = 1.01f*b*lpk;
            sGc[0]=g; sGc[1]=g*g;
        }
    }
    __syncthreads();
    float g=sGc[0], g2=sGc[1];
    for (int idx=tid; idx<5184; idx+=256){
        int a=idx/81, pq=idx-a*81;
        float v=g*af_rn[idx];
        atoms_f[idx]=v;
        atomsT[pq*64+a]=v;
    }
    for (int e=tid; e<4096; e+=256) Xmat[e]=g2*sM[e];
}

// ---------------------------------------------------------------------------
// kA: coefficient update, [b][ch][pix]. grid (strip,b) = (64,4), 512 thr:
// wave owns 8 output channels; lane owns 4 contiguous px. All c/nc
// loads+stores 1KB-contiguous per instruction. Weights via s_load.
template<bool FIRST>
__global__ __launch_bounds__(512) void kA(const float* __restrict__ c_in,
    const float* __restrict__ nc_in, const float* __restrict__ nimg,
    const float* __restrict__ Xmat, const float* __restrict__ atomsT,
    const float* __restrict__ scalars, const float* __restrict__ lmbda_p,
    const float* __restrict__ red_in,
    float* __restrict__ c_out, float* __restrict__ nc_out, float mom)
{
    int b=blockIdx.y, st=blockIdx.x;
    int tid=threadIdx.x;
    int wv = __builtin_amdgcn_readfirstlane(tid>>6);   // wave id 0..7
    int lane = tid&63;
    int co = wv*8;
    int h0 = st*2;
    int px = lane*4;
    int prow = px>>7, pcol = px&127;
    __shared__ float simg[10*128];
    __shared__ float sAct;
    if (FIRST){ if (tid==0) sAct=1.f; }
    else if (tid<64){
        float sd=red_in[(b<<7)+(tid<<1)], si=red_in[(b<<7)+(tid<<1)+1];
        #pragma unroll
        for (int off=32; off; off>>=1){ sd+=__shfl_down(sd,off); si+=__shfl_down(si,off); }
        if (tid==0) sAct = (sd > TOLV*TOLV*si) ? 1.f : 0.f;
    }
    for (int e=tid; e<1280; e+=512)
        simg[e]=nimg[b*NPIX + (((h0-4+(e>>7))&127)<<7) + (e&127)];
    __syncthreads();
    size_t pbase = (size_t)b*NPB + (h0<<7) + px;
    const float* Xo = Xmat + co;
    const float* Ao = atomsT + co;
    float acc[32];
    #pragma unroll
    for (int i=0;i<32;++i) acc[i]=0.f;
    if (!FIRST){
        for (int c=0;c<64;++c){
            float4 cv=*reinterpret_cast<const float4*>(c_in + pbase + (size_t)c*NPIX);
            float4 nv=*reinterpret_cast<const float4*>(nc_in + pbase + (size_t)c*NPIX);
            float t0=fmaf(mom,nv.x-cv.x,nv.x);
            float t1=fmaf(mom,nv.y-cv.y,nv.y);
            float t2=fmaf(mom,nv.z-cv.z,nv.z);
            float t3=fmaf(mom,nv.w-cv.w,nv.w);
            const float* Xr = Xo + (c<<6);
            #pragma unroll
            for (int oc=0;oc<8;++oc){
                float x=Xr[oc];
                acc[oc*4+0]=fmaf(x,t0,acc[oc*4+0]);
                acc[oc*4+1]=fmaf(x,t1,acc[oc*4+1]);
                acc[oc*4+2]=fmaf(x,t2,acc[oc*4+2]);
                acc[oc*4+3]=fmaf(x,t3,acc[oc*4+3]);
            }
        }
    }
    for (int p=0;p<9;++p){
        const float* srow = simg + (prow+p)*128;
        float in12[12];
        #pragma unroll
        for (int k4=0;k4<3;++k4){
            int col=(pcol-4+(k4<<2))&127;
            const float4 vv=*reinterpret_cast<const float4*>(srow+col);
            in12[k4*4+0]=vv.x; in12[k4*4+1]=vv.y;
            in12[k4*4+2]=vv.z; in12[k4*4+3]=vv.w;
        }
        #pragma unroll 3
        for (int q=0;q<9;++q){
            const float* Ar = Ao + ((p*9+q)<<6);
            #pragma unroll
            for (int oc=0;oc<8;++oc){
                float a=Ar[oc];
                acc[oc*4+0]=fmaf(a,-in12[q+0],acc[oc*4+0]);
                acc[oc*4+1]=fmaf(a,-in12[q+1],acc[oc*4+1]);
                acc[oc*4+2]=fmaf(a,-in12[q+2],acc[oc*4+2]);
                acc[oc*4+3]=fmaf(a,-in12[q+3],acc[oc*4+3]);
            }
        }
    }
    float beta=scalars[SC_BETA], lmb=lmbda_p[0];
    bool act = (sAct!=0.f);
    #pragma unroll
    for (int oc=0;oc<8;++oc){
        size_t a = pbase + (size_t)(co+oc)*NPIX;
        float4 nv, cv;
        if (FIRST){ nv=make_float4(0.f,0.f,0.f,0.f); cv=nv; }
        else {
            nv=*reinterpret_cast<const float4*>(nc_in + a);
            cv=*reinterpret_cast<const float4*>(c_in  + a);
        }
        float4 nw, cw;
        {
            float t=FIRST?0.f:fmaf(mom,nv.x-cv.x,nv.x);
            float u=fmaf(-beta,acc[oc*4+0],t); float au=fabsf(u)-lmb;
            u=(au>0.f)?copysignf(au,u):0.f; nw.x=act?u:nv.x; cw.x=act?nv.x:cv.x;
        }{
            float t=FIRST?0.f:fmaf(mom,nv.y-cv.y,nv.y);
            float u=fmaf(-beta,acc[oc*4+1],t); float au=fabsf(u)-lmb;
            u=(au>0.f)?copysignf(au,u):0.f; nw.y=act?u:nv.y; cw.y=act?nv.y:cv.y;
        }{
            float t=FIRST?0.f:fmaf(mom,nv.z-cv.z,nv.z);
            float u=fmaf(-beta,acc[oc*4+2],t); float au=fabsf(u)-lmb;
            u=(au>0.f)?copysignf(au,u):0.f; nw.z=act?u:nv.z; cw.z=act?nv.z:cv.z;
        }{
            float t=FIRST?0.f:fmaf(mom,nv.w-cv.w,nv.w);
            float u=fmaf(-beta,acc[oc*4+3],t); float au=fabsf(u)-lmb;
            u=(au>0.f)?copysignf(au,u):0.f; nw.w=act?u:nv.w; cw.w=act?nv.w:cv.w;
        }
        *reinterpret_cast<float4*>(c_out  + a) = cw;
        *reinterpret_cast<float4*>(nc_out + a) = nw;
    }
}

// kB1: dict_pred partials, CHANNEL-split. grid (8 rowblk, 16 cgroup, 4 b)
// = 512 blocks of 256 thr. 16 rows/block, 8 px/thread, 4 ch per cgroup.
__global__ __launch_bounds__(256,4) void kB1(const float* __restrict__ nc2,
    const float* __restrict__ atoms_f, float* __restrict__ part)
{
    int b=blockIdx.z, cg=blockIdx.y, pb=blockIdx.x;
    int t=threadIdx.x;
    int row = pb*16 + (t>>4);
    int cb  = (t&15)*8;
    const float* src = nc2 + (b*NCH + cg*4)*NPIX;
    float acc[8];
    #pragma unroll
    for (int k=0;k<8;++k) acc[k]=0.f;
    for (int c=0;c<4;++c){
        const float* chan = src + c*NPIX;
        const float* arow = atoms_f + (cg*4+c)*81;
        #pragma unroll 3
        for (int p=0;p<9;++p){
            int r=(row+4-p)&127;
            const float* rp_ = chan + (r<<7);
            float in16[16];
            #pragma unroll
            for (int k4=0;k4<4;++k4){
                int col=(cb-4+(k4<<2))&127;
                const float4 vv = *reinterpret_cast<const float4*>(rp_+col);
                in16[(k4<<2)+0]=vv.x; in16[(k4<<2)+1]=vv.y;
                in16[(k4<<2)+2]=vv.z; in16[(k4<<2)+3]=vv.w;
            }
            #pragma unroll
            for (int q=0;q<9;++q){
                float a = arow[p*9+q];
                #pragma unroll
                for (int k=0;k<8;++k) acc[k]=fmaf(in16[k+8-q], a, acc[k]);
            }
        }
    }
    float* dst = part + (cg*NB+b)*NPIX + (row<<7) + cb;
    #pragma unroll
    for (int k=0;k<8;++k) dst[k]=acc[k];
}

// kB2: image update + residual partials. 512 thr: halves split the 17-tap
// p-loop (9/8), merged via LDS; px work+writes by half 0.
template<bool FIRST>
__global__ __launch_bounds__(512) void kB2(const float* __restrict__ img,
    const float* __restrict__ nimg, const float* __restrict__ y,
    const float* __restrict__ part, const float* __restrict__ pi,
    const float* __restrict__ scalars, const float* __restrict__ red_in,
    float* __restrict__ img_out, float* __restrict__ nimg_out,
    float* __restrict__ red_out, float mom)
{
    int b=blockIdx.y, rp=blockIdx.x;
    int tid=threadIdx.x;
    int half=tid>>8, lid=tid&255;
    int ty=lid>>7, w=lid&127;
    int h0=rp*2;
    __shared__ float sti[18*128];
    __shared__ float spi[289];
    __shared__ float sP2[256];
    __shared__ float rsd[4], rsi[4];
    __shared__ float sAct;
    if (FIRST){ if (tid==0) sAct=1.f; }
    else if (tid<64){
        float sd=red_in[(b<<7)+(tid<<1)], si=red_in[(b<<7)+(tid<<1)+1];
        #pragma unroll
        for (int off=32; off; off>>=1){ sd+=__shfl_down(sd,off); si+=__shfl_down(si,off); }
        if (tid==0) sAct = (sd > TOLV*TOLV*si) ? 1.f : 0.f;
    }
    const float* ib  = img  + b*NPIX;
    const float* nib = nimg + b*NPIX;
    for (int e=tid; e<2304; e+=512){
        int r=e>>7, cc=e&127;
        int idx=(((h0-8+r)&127)<<7)+cc;
        float nv=nib[idx], v=ib[idx];
        sti[e]=fmaf(mom, nv-v, nv);
    }
    for (int e=tid; e<289; e+=512) spi[e]=pi[e];
    __syncthreads();
    float sp=0.f;
    int pn = 9 - half;              // half 0: p=0..8; half 1: p=9..16
    for (int pk=0; pk<pn; ++pk){
        int p = half*9 + pk;
        const float* srow = sti + (ty+p)*128;
        const float* pr = spi + p*17;
        #pragma unroll
        for (int q=0;q<17;++q) sp=fmaf(srow[(w+q-8)&127], pr[q], sp);
    }
    if (half==1) sP2[lid]=sp;
    __syncthreads();
    if (tid<256){
        sp += sP2[lid];
        int pix=((h0+ty)<<7)+w;
        float dp=0.f;
        #pragma unroll
        for (int g=0; g<NPG; ++g) dp += part[(g*NB+b)*NPIX + pix];
        float ti = sti[(ty+8)*128 + w];
        float beta=scalars[SC_BETA], L=scalars[SC_L];
        float yv=y[b*NPIX+pix];
        float upd = ti - (ti - yv + beta*(sp - dp))/L;
        bool act = (sAct!=0.f);
        float iv=ib[pix], niv=nib[pix];
        float i2 = act? niv : iv;
        float ni2 = act? upd : niv;
        img_out[b*NPIX+pix]=i2;
        nimg_out[b*NPIX+pix]=ni2;
        float d=i2-ni2;
        float sd=d*d, si=i2*i2;
        #pragma unroll
        for (int off=32; off; off>>=1){ sd+=__shfl_down(sd,off); si+=__shfl_down(si,off); }
        if ((tid&63)==0){ rsd[tid>>6]=sd; rsi[tid>>6]=si; }
    }
    __syncthreads();
    if (tid==0){
        float a=rsd[0]+rsd[1]+rsd[2]+rsd[3];
        float c2=rsi[0]+rsi[1]+rsi[2]+rsi[3];
        red_out[(b<<7)+(rp<<1)+0]=a;
        red_out[(b<<7)+(rp<<1)+1]=c2;
    }
}

// ---------------------------------------------------------------------------
extern "C" void kernel_launch(void* const* d_in, const int* in_sizes, int n_in,
                              void* d_out, int out_size, void* d_ws, size_t ws_size,
                              hipStream_t stream)
{
    const float* y        = (const float*)d_in[0];
    const float* atoms_p  = (const float*)d_in[1];
    const float* fatoms_p = (const float*)d_in[2];
    const float* beta_p   = (const float*)d_in[3];
    const float* lmbda_p  = (const float*)d_in[4];
    float* out = (float*)d_out;
    float* w = (float*)d_ws;

    size_t off=0;
    float* cb[2];  cb[0]=w+off;  off+=NCOEF; cb[1]=w+off;  off+=NCOEF;   // [b][ch][pix]
    float* ncb[2]; ncb[0]=w+off; off+=NCOEF; ncb[1]=w+off; off+=NCOEF;   // [b][ch][pix]
    float* ib[2];  ib[0]=w+off;  off+=NIMG;  ib[1]=w+off;  off+=NIMG;
    float* nib[2]; nib[0]=w+off; off+=NIMG;  nib[1]=w+off; off+=NIMG;
    float* part=w+off;    off+=NPG*NIMG;
    float* red[2]; red[0]=w+off; off+=512; red[1]=w+off; off+=512;
    float* gram=w+off;    off+=6561;
    float* pf=w+off;      off+=6561;
    float* PP=w+off;      off+=6561;
    float* pi=w+off;      off+=512;
    float* af_rn=w+off;   off+=5184;
    float* af_rnT=w+off;  off+=5184;
    float* Mmat=w+off;    off+=4096;
    float* M2mat=w+off;   off+=4096;
    float* atoms_f=w+off; off+=5184;
    float* atomsT=w+off;  off+=5184;
    float* Xmat=w+off;    off+=4096;
    float* scalars=w+off; off+=32;

    k_prep1<<<dim3(1),dim3(256),0,stream>>>(fatoms_p, beta_p, gram, pf, scalars);
    k_PP<<<dim3(26),dim3(256),0,stream>>>(pf, PP);
    k_impulse<<<dim3(1),dim3(320),0,stream>>>(PP, pi);
    k_dft<<<dim3(256),dim3(64),0,stream>>>(pi, scalars);
    k_atoms1<<<dim3(64),dim3(128),0,stream>>>(atoms_p, gram, af_rn, af_rnT);
    k_M<<<dim3(16),dim3(256),0,stream>>>(af_rn, af_rnT, Mmat);
    k_M2<<<dim3(16),dim3(256),0,stream>>>(Mmat, M2mat);
    k_fin<<<dim3(1),dim3(256),0,stream>>>(Mmat, M2mat, af_rn, scalars, atoms_f, atomsT, Xmat);

    int p=0;
    for (int k=1; k<=20; ++k){
        float mom = (float)(k-1)/(float)(k+2);
        const float* rin = red[(k-1)&1];
        float* rout = red[k&1];
        const float* img_i  = (k==1)? y : ib[p];
        const float* nimg_i = (k==1)? y : nib[p];
        float* nc_t  = (k==20)? (out+NIMG) : ncb[p^1];
        float* nimg_t= (k==20)? out : nib[p^1];
        if (k==1){
            kA<true><<<dim3(64,4),dim3(512),0,stream>>>(cb[p],ncb[p],nimg_i,Xmat,atomsT,
                scalars,lmbda_p,rin, cb[p^1],nc_t,mom);
        } else {
            kA<false><<<dim3(64,4),dim3(512),0,stream>>>(cb[p],ncb[p],nimg_i,Xmat,atomsT,
                scalars,lmbda_p,rin, cb[p^1],nc_t,mom);
        }
        kB1<<<dim3(8,16,4),dim3(256),0,stream>>>(nc_t, atoms_f, part);
        if (k==1){
            kB2<true><<<dim3(64,4),dim3(512),0,stream>>>(img_i,nimg_i,y,part,pi,scalars,rin,
                ib[p^1],nimg_t,rout,mom);
        } else {
            kB2<false><<<dim3(64,4),dim3(512),0,stream>>>(img_i,nimg_i,y,part,pi,scalars,rin,
                ib[p^1],nimg_t,rout,mom);
        }
        p^=1;
    }
}

// Round 16
// 1359.429 us; speedup vs baseline: 1.4718x; 1.0218x over previous
//
#include <hip/hip_runtime.h>
#include <math.h>

// ---------------------------------------------------------------------------
// Dictionary_56212531970303 : FISTA dictionary forward on MI355X, fp32.
// Layout: coefficient state [b][ch][pix]. Per-INSTRUCTION contiguity rule
// (round-13): every state load/store = 64 lanes x float4 = 1KB contiguous.
// Loop (20 iters):
//   kA  — 512-thr blocks over 2-row strip. Phase 0 stages temp=nc+mom(nc-c)
//         in LDS [64][256] ONCE (round-15 diagnosis: all 8 waves re-read all
//         64 input channels -> 8x L2 amplification, 2MB/block); GEMM reads
//         temp via conflict-free ds_read_b128. Wave = 8-oc slice, lane = 4px.
//   kB1 — 16 cgroups x 4ch, 8 px/thread (round-9: split channels, not px).
//   kB2 — 512-thr blocks, 17-tap conv split across two halves (round-14).
// Iter 1 templated FIRST; iter 20 writes nc/img directly into d_out.
// NOTE: every "if (tid<N)" with N>blockDim must be a grid-stride loop —
// round-2/3 regression (absmax 0.134).
// ---------------------------------------------------------------------------

#define NB 4
#define NCH 64
#define NPIX 16384              // 128*128
#define NPB (NCH*NPIX)
#define NCOEF (NB*NCH*NPIX)     // 4194304
#define NIMG  (NB*NPIX)         // 65536
#define NPG 16                  // partial channel-groups (4 ch each)
#define TOLV 1e-4f

#define SC_BETA 0
#define SC_L    1
#define SC_G    4
#define SC_G2   5
#define SC_LPK2 6

// ---------------------------------------------------------------------------
// prep1: one block. bjorck via 8x8 gram-iteration; writes gram + pf + scalars.
__global__ __launch_bounds__(256) void k_prep1(const float* __restrict__ fatoms,
    const float* __restrict__ beta_p,
    float* __restrict__ gram_g, float* __restrict__ pf_g,
    float* __restrict__ scalars)
{
    __shared__ float sW[648], sWf[648];
    __shared__ float sG[64], sP[64], sF[64], sT[64], sTmp[64];
    __shared__ float sGr[6561];
    __shared__ float rs[81];
    __shared__ float sSig;
    int tid = threadIdx.x;
    if (tid==0){ float b=beta_p[0]; scalars[SC_BETA]=(b>0.f)?b:0.f;
                 ((unsigned*)scalars)[SC_LPK2]=0u; }
    for (int e=tid; e<648; e+=256) sW[e]=fatoms[e];
    __syncthreads();
    if (tid<64){ int r=tid>>3, s=tid&7; float a=0.f;
        for (int k=0;k<81;++k) a=fmaf(sW[r*81+k],sW[s*81+k],a); sG[tid]=a; }
    __syncthreads();
    if (tid<64){
        int r8 = tid&7;
        float v = 1.f;
        for (int it=0; it<128; ++it){
            float nv=0.f;
            #pragma unroll
            for (int j=0;j<8;++j) nv = fmaf(sG[r8*8+j], __shfl(v,j,8), nv);
            float m = fabsf(nv);
            m = fmaxf(m, __shfl_xor(m,1,8));
            m = fmaxf(m, __shfl_xor(m,2,8));
            m = fmaxf(m, __shfl_xor(m,4,8));
            v = nv/m;
        }
        float wv=0.f;
        #pragma unroll
        for (int j=0;j<8;++j) wv = fmaf(sG[r8*8+j], __shfl(v,j,8), wv);
        float num=v*wv, den=v*v;
        num += __shfl_xor(num,1,8); num += __shfl_xor(num,2,8); num += __shfl_xor(num,4,8);
        den += __shfl_xor(den,1,8); den += __shfl_xor(den,2,8); den += __shfl_xor(den,4,8);
        if (tid==0) sSig = sqrtf(num/den);
    }
    __syncthreads();
    float inv_s = 1.f/sSig;
    for (int e=tid; e<648; e+=256) sW[e]*=inv_s;
    if (tid<64){ sG[tid]*=inv_s*inv_s; sP[tid]=((tid>>3)==(tid&7))?1.f:0.f; }
    __syncthreads();
    for (int it=0; it<15; ++it){
        if (tid<64) sF[tid] = (((tid>>3)==(tid&7))?1.5f:0.f) - 0.5f*sG[tid];
        __syncthreads();
        if (tid<64){ int r=tid>>3, c=tid&7; float ap=0.f, ag=0.f;
            #pragma unroll
            for (int k=0;k<8;++k){ float f=sF[r*8+k]; ap=fmaf(f,sP[k*8+c],ap); ag=fmaf(f,sG[k*8+c],ag); }
            sTmp[tid]=ap; sT[tid]=ag; }
        __syncthreads();
        if (tid<64){ int r=tid>>3, c=tid&7; float g2=0.f;
            #pragma unroll
            for (int k=0;k<8;++k) g2=fmaf(sT[r*8+k],sF[k*8+c],g2);
            sG[tid]=g2; sP[tid]=sTmp[tid]; }
        __syncthreads();
    }
    for (int e=tid; e<648; e+=256){ int r=e/81, j=e%81; float a=0.f;
        #pragma unroll
        for (int k=0;k<8;++k) a=fmaf(sP[r*8+k], sW[k*81+j], a);
        sWf[e]=a; }
    __syncthreads();
    for (int e=tid; e<6561; e+=256){ int i=e/81, j=e%81; float a=0.f;
        #pragma unroll
        for (int r=0;r<8;++r) a=fmaf(sWf[r*81+i],sWf[r*81+j],a);
        sGr[e]=a; gram_g[e]=a; }
    __syncthreads();
    if (tid<81){ float s=0.f; for (int k=0;k<81;++k) s+=sGr[tid*81+k]; rs[tid]=(1.f-s)/81.f; }
    __syncthreads();
    for (int e=tid; e<6561; e+=256){ int i=e/81, j=e%81;
        pf_g[e] = ((i==j)?1.f:0.f) - sGr[e] - rs[j]; }
}

// PP = pf^T pf (81x81), pf staged in LDS. 26 blocks x 256 thr.
__global__ __launch_bounds__(256) void k_PP(const float* __restrict__ pf, float* __restrict__ PP)
{
    __shared__ float spf[6561];
    for (int e=threadIdx.x; e<6561; e+=256) spf[e]=pf[e];
    __syncthreads();
    int e = blockIdx.x*256 + threadIdx.x;
    if (e>=6561) return;
    int al=e/81, be=e%81; float a=0.f;
    for (int c=0;c<81;++c) a=fmaf(spf[c*81+al], spf[c*81+be], a);
    PP[e]=a;
}

// proj_impulse (17x17) via PP lookups. One block, 320 thr (guard: t<289).
__global__ void k_impulse(const float* __restrict__ PP, float* __restrict__ pi)
{
    int t = threadIdx.x;
    if (t>=289) return;
    int h=t/17, w=t%17;
    float acc=0.f;
    for (int p=0;p<9;++p){
        int i2=(h+p-4+17)%17;
        if (i2<4||i2>12) continue;
        for (int q=0;q<9;++q){
            int j2=(w+q-4+17)%17;
            if (j2<4||j2>12) continue;
            int al=(12-i2)*9+(12-j2);
            int be=(8-p)*9+(8-q);
            acc += PP[al*81+be];
        }
    }
    pi[t]=acc;
}

// |FFT2(pi zero-padded to 128x128)|^2 max. 256 blocks x 64 thr (1 wave).
__global__ __launch_bounds__(64) void k_dft(const float* __restrict__ pi, float* __restrict__ scalars)
{
    __shared__ float spi[289], ct[128], st[128];
    int tid=threadIdx.x; int gid=blockIdx.x*64+tid;
    for (int e=tid; e<289; e+=64) spi[e]=pi[e];
    for (int e=tid; e<128; e+=64){ float ang=(float)e*(6.28318530717958647692f/128.f);
                  ct[e]=cosf(ang); st[e]=sinf(ang); }
    __syncthreads();
    int u=gid>>7, v=gid&127;
    float re=0.f, im=0.f;
    for (int i=0;i<17;++i){
        int ku=(u*i)&127;
        const float* prow=spi+i*17;
        for (int j=0;j<17;++j){
            int k=(ku+v*j)&127;
            float x=prow[j];
            re=fmaf(x,ct[k],re); im=fmaf(x,st[k],im);
        }
    }
    float m2=re*re+im*im;
    #pragma unroll
    for (int d=32; d; d>>=1) m2=fmaxf(m2, __shfl_down(m2,d));
    if (tid==0) atomicMax(((unsigned*)scalars)+SC_LPK2, __float_as_uint(m2));
}

// per-atom: center, subtract af@gram, row-normalize. Writes af_rn AND af_rnT.
__global__ __launch_bounds__(128) void k_atoms1(const float* __restrict__ atoms_in,
    const float* __restrict__ gram, float* __restrict__ af_rn, float* __restrict__ af_rnT)
{
    int a=blockIdx.x, tid=threadIdx.x;
    __shared__ float a0[81], a1[81], rbuf[128];
    float v = (tid<81)? atoms_in[a*81+tid] : 0.f;
    rbuf[tid]=v; __syncthreads();
    for (int off=64; off; off>>=1){ if (tid<off) rbuf[tid]+=rbuf[tid+off]; __syncthreads(); }
    float mean = rbuf[0]/81.f;
    __syncthreads();
    if (tid<81) a0[tid]=v-mean;
    __syncthreads();
    float w=0.f;
    if (tid<81){ float dot=0.f;
        for (int k=0;k<81;++k) dot=fmaf(a0[k], gram[k*81+tid], dot);
        w=a0[tid]-dot; a1[tid]=w; }
    rbuf[tid]=(tid<81)? w*w : 0.f;
    __syncthreads();
    for (int off=64; off; off>>=1){ if (tid<off) rbuf[tid]+=rbuf[tid+off]; __syncthreads(); }
    float inv = 1.f/sqrtf(rbuf[0]);
    if (tid<81){ float r=a1[tid]*inv; af_rn[a*81+tid]=r; af_rnT[tid*64+a]=r; }
}

// M = af_rn af_rn^T. 16 blocks x 256.
__global__ __launch_bounds__(256) void k_M(const float* __restrict__ af_rn,
    const float* __restrict__ af_rnT, float* __restrict__ M)
{
    int e=blockIdx.x*256+threadIdx.x;
    int i=e>>6, j=e&63;
    float a=0.f;
    for (int k=0;k<81;++k) a=fmaf(af_rn[i*81+k], af_rnT[(k<<6)+j], a);
    M[e]=a;
}

// M2 = M*M (M symmetric). 16 blocks x 256.
__global__ __launch_bounds__(256) void k_M2(const float* __restrict__ M,
    float* __restrict__ M2)
{
    int e=blockIdx.x*256+threadIdx.x;
    int i=e>>6, j=e&63;
    float a=0.f;
    for (int k=0;k<64;++k) a=fmaf(M[(i<<6)+k], M[(k<<6)+j], a);
    M2[e]=a;
}

// k_fin: one block, slim. Power 48 on M^2, Rayleigh with M, finalize.
__global__ __launch_bounds__(256) void k_fin(const float* __restrict__ Mg,
    const float* __restrict__ M2g, const float* __restrict__ af_rn,
    float* __restrict__ scalars,
    float* __restrict__ atoms_f, float* __restrict__ atomsT, float* __restrict__ Xmat)
{
    __shared__ float sM[4096];
    __shared__ float sGc[2];
    int tid=threadIdx.x;
    for (int e=tid; e<4096; e+=256) sM[e]=Mg[e];
    __syncthreads();
    if (tid<64){
        float m[64];
        #pragma unroll
        for (int j=0;j<64;++j) m[j]=M2g[(tid<<6)+j];
        float v = 1.0f + 0.01f*(float)tid;
        for (int it=0; it<48; ++it){
            float a0=0.f,a1=0.f,a2=0.f,a3=0.f;
            #pragma unroll
            for (int j=0;j<64;j+=4){
                a0=fmaf(m[j+0], __shfl(v,j+0), a0);
                a1=fmaf(m[j+1], __shfl(v,j+1), a1);
                a2=fmaf(m[j+2], __shfl(v,j+2), a2);
                a3=fmaf(m[j+3], __shfl(v,j+3), a3);
            }
            float nv=(a0+a1)+(a2+a3);
            float mx=fabsf(nv);
            #pragma unroll
            for (int d=1; d<64; d<<=1) mx=fmaxf(mx, __shfl_xor(mx,d));
            v=nv/mx;
        }
        float w0=0.f,w1=0.f,w2=0.f,w3=0.f;
        #pragma unroll
        for (int j=0;j<64;j+=4){
            w0=fmaf(sM[(tid<<6)+j+0], __shfl(v,j+0), w0);
            w1=fmaf(sM[(tid<<6)+j+1], __shfl(v,j+1), w1);
            w2=fmaf(sM[(tid<<6)+j+2], __shfl(v,j+2), w2);
            w3=fmaf(sM[(tid<<6)+j+3], __shfl(v,j+3), w3);
        }
        float wv=(w0+w1)+(w2+w3);
        float num=v*wv, den=v*v;
        #pragma unroll
        for (int d=1; d<64; d<<=1){ num+=__shfl_xor(num,d); den+=__shfl_xor(den,d); }
        if (tid==0){
            float sig = sqrtf(num/den);
            float b = scalars[SC_BETA];
            float s = sqrtf(0.99f/fmaxf(b,0.1f));
            float g = s/sig;
            scalars[SC_G]=g; scalars[SC_G2]=g*g;
            float lpk = sqrtf(__uint_as_float(((unsigned*)scalars)[SC_LPK2]));
            scalars[SC_L] = 1.01f*b*lpk;
            sGc[0]=g; sGc[1]=g*g;
        }
    }
    __syncthreads();
    float g=sGc[0], g2=sGc[1];
    for (int idx=tid; idx<5184; idx+=256){
        int a=idx/81, pq=idx-a*81;
        float v=g*af_rn[idx];
        atoms_f[idx]=v;
        atomsT[pq*64+a]=v;
    }
    for (int e=tid; e<4096; e+=256) Xmat[e]=g2*sM[e];
}

// ---------------------------------------------------------------------------
// kA: coefficient update, [b][ch][pix]. grid (strip,b) = (64,4), 512 thr.
// Phase 0: stage temp[64][256] in LDS (each global value read ONCE).
// Phase 1: GEMM from LDS temp (ds_read_b128, 2-way bank alias = free).
// Conv phase: simg in LDS. Phase 3: writes 1KB-contiguous; re-reads own
// 8-ch c/nc slice from L2-hot global.
template<bool FIRST>
__global__ __launch_bounds__(512) void kA(const float* __restrict__ c_in,
    const float* __restrict__ nc_in, const float* __restrict__ nimg,
    const float* __restrict__ Xmat, const float* __restrict__ atomsT,
    const float* __restrict__ scalars, const float* __restrict__ lmbda_p,
    const float* __restrict__ red_in,
    float* __restrict__ c_out, float* __restrict__ nc_out, float mom)
{
    int b=blockIdx.y, st=blockIdx.x;
    int tid=threadIdx.x;
    int wv = __builtin_amdgcn_readfirstlane(tid>>6);   // wave id 0..7
    int lane = tid&63;
    int co = wv*8;
    int h0 = st*2;
    int px = lane*4;
    int prow = px>>7, pcol = px&127;
    __shared__ float sTemp[64*256];   // 64 KB: temp [ch][px-in-strip]
    __shared__ float simg[10*128];
    __shared__ float sAct;
    if (FIRST){ if (tid==0) sAct=1.f; }
    else if (tid<64){
        float sd=red_in[(b<<7)+(tid<<1)], si=red_in[(b<<7)+(tid<<1)+1];
        #pragma unroll
        for (int off=32; off; off>>=1){ sd+=__shfl_down(sd,off); si+=__shfl_down(si,off); }
        if (tid==0) sAct = (sd > TOLV*TOLV*si) ? 1.f : 0.f;
    }
    for (int e=tid; e<1280; e+=512)
        simg[e]=nimg[b*NPIX + (((h0-4+(e>>7))&127)<<7) + (e&127)];
    size_t sbase = (size_t)b*NPB + (h0<<7);
    if (!FIRST){
        // phase 0: stage temp once. e = ch*64 + pxg (float4 granules)
        for (int e=tid; e<4096; e+=512){
            int ch = e>>6, pxg = e&63;
            size_t a = sbase + (size_t)ch*NPIX + pxg*4;
            float4 cv=*reinterpret_cast<const float4*>(c_in + a);
            float4 nv=*reinterpret_cast<const float4*>(nc_in + a);
            float4 t;
            t.x=fmaf(mom,nv.x-cv.x,nv.x); t.y=fmaf(mom,nv.y-cv.y,nv.y);
            t.z=fmaf(mom,nv.z-cv.z,nv.z); t.w=fmaf(mom,nv.w-cv.w,nv.w);
            *reinterpret_cast<float4*>(sTemp + ch*256 + pxg*4) = t;
        }
    }
    __syncthreads();
    const float* Xo = Xmat + co;
    const float* Ao = atomsT + co;
    float acc[32];
    #pragma unroll
    for (int i=0;i<32;++i) acc[i]=0.f;
    if (!FIRST){
        for (int c=0;c<64;++c){
            float4 t=*reinterpret_cast<const float4*>(sTemp + c*256 + px);
            const float* Xr = Xo + (c<<6);
            #pragma unroll
            for (int oc=0;oc<8;++oc){
                float x=Xr[oc];
                acc[oc*4+0]=fmaf(x,t.x,acc[oc*4+0]);
                acc[oc*4+1]=fmaf(x,t.y,acc[oc*4+1]);
                acc[oc*4+2]=fmaf(x,t.z,acc[oc*4+2]);
                acc[oc*4+3]=fmaf(x,t.w,acc[oc*4+3]);
            }
        }
    }
    for (int p=0;p<9;++p){
        const float* srow = simg + (prow+p)*128;
        float in12[12];
        #pragma unroll
        for (int k4=0;k4<3;++k4){
            int col=(pcol-4+(k4<<2))&127;
            const float4 vv=*reinterpret_cast<const float4*>(srow+col);
            in12[k4*4+0]=vv.x; in12[k4*4+1]=vv.y;
            in12[k4*4+2]=vv.z; in12[k4*4+3]=vv.w;
        }
        #pragma unroll 3
        for (int q=0;q<9;++q){
            const float* Ar = Ao + ((p*9+q)<<6);
            #pragma unroll
            for (int oc=0;oc<8;++oc){
                float a=Ar[oc];
                acc[oc*4+0]=fmaf(a,-in12[q+0],acc[oc*4+0]);
                acc[oc*4+1]=fmaf(a,-in12[q+1],acc[oc*4+1]);
                acc[oc*4+2]=fmaf(a,-in12[q+2],acc[oc*4+2]);
                acc[oc*4+3]=fmaf(a,-in12[q+3],acc[oc*4+3]);
            }
        }
    }
    float beta=scalars[SC_BETA], lmb=lmbda_p[0];
    bool act = (sAct!=0.f);
    #pragma unroll
    for (int oc=0;oc<8;++oc){
        size_t a = sbase + (size_t)(co+oc)*NPIX + px;
        float4 nv, cv;
        if (FIRST){ nv=make_float4(0.f,0.f,0.f,0.f); cv=nv; }
        else {
            nv=*reinterpret_cast<const float4*>(nc_in + a);
            cv=*reinterpret_cast<const float4*>(c_in  + a);
        }
        float4 nw, cw;
        {
            float t=FIRST?0.f:fmaf(mom,nv.x-cv.x,nv.x);
            float u=fmaf(-beta,acc[oc*4+0],t); float au=fabsf(u)-lmb;
            u=(au>0.f)?copysignf(au,u):0.f; nw.x=act?u:nv.x; cw.x=act?nv.x:cv.x;
        }{
            float t=FIRST?0.f:fmaf(mom,nv.y-cv.y,nv.y);
            float u=fmaf(-beta,acc[oc*4+1],t); float au=fabsf(u)-lmb;
            u=(au>0.f)?copysignf(au,u):0.f; nw.y=act?u:nv.y; cw.y=act?nv.y:cv.y;
        }{
            float t=FIRST?0.f:fmaf(mom,nv.z-cv.z,nv.z);
            float u=fmaf(-beta,acc[oc*4+2],t); float au=fabsf(u)-lmb;
            u=(au>0.f)?copysignf(au,u):0.f; nw.z=act?u:nv.z; cw.z=act?nv.z:cv.z;
        }{
            float t=FIRST?0.f:fmaf(mom,nv.w-cv.w,nv.w);
            float u=fmaf(-beta,acc[oc*4+3],t); float au=fabsf(u)-lmb;
            u=(au>0.f)?copysignf(au,u):0.f; nw.w=act?u:nv.w; cw.w=act?nv.w:cv.w;
        }
        *reinterpret_cast<float4*>(c_out  + a) = cw;
        *reinterpret_cast<float4*>(nc_out + a) = nw;
    }
}

// kB1: dict_pred partials, CHANNEL-split. grid (8 rowblk, 16 cgroup, 4 b)
// = 512 blocks of 256 thr. 16 rows/block, 8 px/thread, 4 ch per cgroup.
__global__ __launch_bounds__(256,4) void kB1(const float* __restrict__ nc2,
    const float* __restrict__ atoms_f, float* __restrict__ part)
{
    int b=blockIdx.z, cg=blockIdx.y, pb=blockIdx.x;
    int t=threadIdx.x;
    int row = pb*16 + (t>>4);
    int cb  = (t&15)*8;
    const float* src = nc2 + (b*NCH + cg*4)*NPIX;
    float acc[8];
    #pragma unroll
    for (int k=0;k<8;++k) acc[k]=0.f;
    for (int c=0;c<4;++c){
        const float* chan = src + c*NPIX;
        const float* arow = atoms_f + (cg*4+c)*81;
        #pragma unroll 3
        for (int p=0;p<9;++p){
            int r=(row+4-p)&127;
            const float* rp_ = chan + (r<<7);
            float in16[16];
            #pragma unroll
            for (int k4=0;k4<4;++k4){
                int col=(cb-4+(k4<<2))&127;
                const float4 vv = *reinterpret_cast<const float4*>(rp_+col);
                in16[(k4<<2)+0]=vv.x; in16[(k4<<2)+1]=vv.y;
                in16[(k4<<2)+2]=vv.z; in16[(k4<<2)+3]=vv.w;
            }
            #pragma unroll
            for (int q=0;q<9;++q){
                float a = arow[p*9+q];
                #pragma unroll
                for (int k=0;k<8;++k) acc[k]=fmaf(in16[k+8-q], a, acc[k]);
            }
        }
    }
    float* dst = part + (cg*NB+b)*NPIX + (row<<7) + cb;
    #pragma unroll
    for (int k=0;k<8;++k) dst[k]=acc[k];
}

// kB2: image update + residual partials. 512 thr: halves split the 17-tap
// p-loop (9/8), merged via LDS; px work+writes by half 0.
template<bool FIRST>
__global__ __launch_bounds__(512) void kB2(const float* __restrict__ img,
    const float* __restrict__ nimg, const float* __restrict__ y,
    const float* __restrict__ part, const float* __restrict__ pi,
    const float* __restrict__ scalars, const float* __restrict__ red_in,
    float* __restrict__ img_out, float* __restrict__ nimg_out,
    float* __restrict__ red_out, float mom)
{
    int b=blockIdx.y, rp=blockIdx.x;
    int tid=threadIdx.x;
    int half=tid>>8, lid=tid&255;
    int ty=lid>>7, w=lid&127;
    int h0=rp*2;
    __shared__ float sti[18*128];
    __shared__ float spi[289];
    __shared__ float sP2[256];
    __shared__ float rsd[4], rsi[4];
    __shared__ float sAct;
    if (FIRST){ if (tid==0) sAct=1.f; }
    else if (tid<64){
        float sd=red_in[(b<<7)+(tid<<1)], si=red_in[(b<<7)+(tid<<1)+1];
        #pragma unroll
        for (int off=32; off; off>>=1){ sd+=__shfl_down(sd,off); si+=__shfl_down(si,off); }
        if (tid==0) sAct = (sd > TOLV*TOLV*si) ? 1.f : 0.f;
    }
    const float* ib  = img  + b*NPIX;
    const float* nib = nimg + b*NPIX;
    for (int e=tid; e<2304; e+=512){
        int r=e>>7, cc=e&127;
        int idx=(((h0-8+r)&127)<<7)+cc;
        float nv=nib[idx], v=ib[idx];
        sti[e]=fmaf(mom, nv-v, nv);
    }
    for (int e=tid; e<289; e+=512) spi[e]=pi[e];
    __syncthreads();
    float sp=0.f;
    int pn = 9 - half;              // half 0: p=0..8; half 1: p=9..16
    for (int pk=0; pk<pn; ++pk){
        int p = half*9 + pk;
        const float* srow = sti + (ty+p)*128;
        const float* pr = spi + p*17;
        #pragma unroll
        for (int q=0;q<17;++q) sp=fmaf(srow[(w+q-8)&127], pr[q], sp);
    }
    if (half==1) sP2[lid]=sp;
    __syncthreads();
    if (tid<256){
        sp += sP2[lid];
        int pix=((h0+ty)<<7)+w;
        float dp=0.f;
        #pragma unroll
        for (int g=0; g<NPG; ++g) dp += part[(g*NB+b)*NPIX + pix];
        float ti = sti[(ty+8)*128 + w];
        float beta=scalars[SC_BETA], L=scalars[SC_L];
        float yv=y[b*NPIX+pix];
        float upd = ti - (ti - yv + beta*(sp - dp))/L;
        bool act = (sAct!=0.f);
        float iv=ib[pix], niv=nib[pix];
        float i2 = act? niv : iv;
        float ni2 = act? upd : niv;
        img_out[b*NPIX+pix]=i2;
        nimg_out[b*NPIX+pix]=ni2;
        float d=i2-ni2;
        float sd=d*d, si=i2*i2;
        #pragma unroll
        for (int off=32; off; off>>=1){ sd+=__shfl_down(sd,off); si+=__shfl_down(si,off); }
        if ((tid&63)==0){ rsd[tid>>6]=sd; rsi[tid>>6]=si; }
    }
    __syncthreads();
    if (tid==0){
        float a=rsd[0]+rsd[1]+rsd[2]+rsd[3];
        float c2=rsi[0]+rsi[1]+rsi[2]+rsi[3];
        red_out[(b<<7)+(rp<<1)+0]=a;
        red_out[(b<<7)+(rp<<1)+1]=c2;
    }
}

// ---------------------------------------------------------------------------
extern "C" void kernel_launch(void* const* d_in, const int* in_sizes, int n_in,
                              void* d_out, int out_size, void* d_ws, size_t ws_size,
                              hipStream_t stream)
{
    const float* y        = (const float*)d_in[0];
    const float* atoms_p  = (const float*)d_in[1];
    const float* fatoms_p = (const float*)d_in[2];
    const float* beta_p   = (const float*)d_in[3];
    const float* lmbda_p  = (const float*)d_in[4];
    float* out = (float*)d_out;
    float* w = (float*)d_ws;

    size_t off=0;
    float* cb[2];  cb[0]=w+off;  off+=NCOEF; cb[1]=w+off;  off+=NCOEF;   // [b][ch][pix]
    float* ncb[2]; ncb[0]=w+off; off+=NCOEF; ncb[1]=w+off; off+=NCOEF;   // [b][ch][pix]
    float* ib[2];  ib[0]=w+off;  off+=NIMG;  ib[1]=w+off;  off+=NIMG;
    float* nib[2]; nib[0]=w+off; off+=NIMG;  nib[1]=w+off; off+=NIMG;
    float* part=w+off;    off+=NPG*NIMG;
    float* red[2]; red[0]=w+off; off+=512; red[1]=w+off; off+=512;
    float* gram=w+off;    off+=6561;
    float* pf=w+off;      off+=6561;
    float* PP=w+off;      off+=6561;
    float* pi=w+off;      off+=512;
    float* af_rn=w+off;   off+=5184;
    float* af_rnT=w+off;  off+=5184;
    float* Mmat=w+off;    off+=4096;
    float* M2mat=w+off;   off+=4096;
    float* atoms_f=w+off; off+=5184;
    float* atomsT=w+off;  off+=5184;
    float* Xmat=w+off;    off+=4096;
    float* scalars=w+off; off+=32;

    k_prep1<<<dim3(1),dim3(256),0,stream>>>(fatoms_p, beta_p, gram, pf, scalars);
    k_PP<<<dim3(26),dim3(256),0,stream>>>(pf, PP);
    k_impulse<<<dim3(1),dim3(320),0,stream>>>(PP, pi);
    k_dft<<<dim3(256),dim3(64),0,stream>>>(pi, scalars);
    k_atoms1<<<dim3(64),dim3(128),0,stream>>>(atoms_p, gram, af_rn, af_rnT);
    k_M<<<dim3(16),dim3(256),0,stream>>>(af_rn, af_rnT, Mmat);
    k_M2<<<dim3(16),dim3(256),0,stream>>>(Mmat, M2mat);
    k_fin<<<dim3(1),dim3(256),0,stream>>>(Mmat, M2mat, af_rn, scalars, atoms_f, atomsT, Xmat);

    int p=0;
    for (int k=1; k<=20; ++k){
        float mom = (float)(k-1)/(float)(k+2);
        const float* rin = red[(k-1)&1];
        float* rout = red[k&1];
        const float* img_i  = (k==1)? y : ib[p];
        const float* nimg_i = (k==1)? y : nib[p];
        float* nc_t  = (k==20)? (out+NIMG) : ncb[p^1];
        float* nimg_t= (k==20)? out : nib[p^1];
        if (k==1){
            kA<true><<<dim3(64,4),dim3(512),0,stream>>>(cb[p],ncb[p],nimg_i,Xmat,atomsT,
                scalars,lmbda_p,rin, cb[p^1],nc_t,mom);
        } else {
            kA<false><<<dim3(64,4),dim3(512),0,stream>>>(cb[p],ncb[p],nimg_i,Xmat,atomsT,
                scalars,lmbda_p,rin, cb[p^1],nc_t,mom);
        }
        kB1<<<dim3(8,16,4),dim3(256),0,stream>>>(nc_t, atoms_f, part);
        if (k==1){
            kB2<true><<<dim3(64,4),dim3(512),0,stream>>>(img_i,nimg_i,y,part,pi,scalars,rin,
                ib[p^1],nimg_t,rout,mom);
        } else {
            kB2<false><<<dim3(64,4),dim3(512),0,stream>>>(img_i,nimg_i,y,part,pi,scalars,rin,
                ib[p^1],nimg_t,rout,mom);
        }
        p^=1;
    }
}

// Round 17
// 1306.557 us; speedup vs baseline: 1.5313x; 1.0405x over previous
//
#include <hip/hip_runtime.h>
#include <math.h>

// ---------------------------------------------------------------------------
// Dictionary_56212531970303 : FISTA dictionary forward on MI355X, fp32.
// Layout: coefficient state [b][ch][pix]. Per-INSTRUCTION contiguity rule
// (round-13): every state load/store = 64 lanes x float4 = 1KB contiguous.
// Setup: prep1 (64-iter 8x8 power — proven identical to 128), k_PP,
//        k_impulse, k_dft, atoms1, k_M, k_M2 x4 (M^2,M^4,M^8,M^16 — round-16:
//        the 48-iter serial shfl power loop in k_fin was ~72us of cross-lane
//        latency; repeated SQUARING moves that work to cheap grid kernels),
//        k_fin (8 power iters on M^16 = M^128 contraction).
// Loop (20 iters):
//   kA  — 512-thr blocks; LDS-staged temp[64][256] (round-15: kills 8x L2
//         re-read); wave = 8-oc slice, lane = 4px float4.
//   kB1 — 16 cgroups x 4ch, 8 px/thread (round-9: split channels, not px).
//   kB2 — 512-thr, 17-tap conv split across halves (round-14).
// Iter 1 templated FIRST; iter 20 writes nc/img directly into d_out.
// NOTE: every "if (tid<N)" with N>blockDim must be a grid-stride loop —
// round-2/3 regression (absmax 0.134).
// ---------------------------------------------------------------------------

#define NB 4
#define NCH 64
#define NPIX 16384              // 128*128
#define NPB (NCH*NPIX)
#define NCOEF (NB*NCH*NPIX)     // 4194304
#define NIMG  (NB*NPIX)         // 65536
#define NPG 16                  // partial channel-groups (4 ch each)
#define TOLV 1e-4f

#define SC_BETA 0
#define SC_L    1
#define SC_G    4
#define SC_G2   5
#define SC_LPK2 6

// ---------------------------------------------------------------------------
// prep1: one block. bjorck via 8x8 gram-iteration; writes gram + pf + scalars.
__global__ __launch_bounds__(256) void k_prep1(const float* __restrict__ fatoms,
    const float* __restrict__ beta_p,
    float* __restrict__ gram_g, float* __restrict__ pf_g,
    float* __restrict__ scalars)
{
    __shared__ float sW[648], sWf[648];
    __shared__ float sG[64], sP[64], sF[64], sT[64], sTmp[64];
    __shared__ float sGr[6561];
    __shared__ float rs[81];
    __shared__ float sSig;
    int tid = threadIdx.x;
    if (tid==0){ float b=beta_p[0]; scalars[SC_BETA]=(b>0.f)?b:0.f;
                 ((unsigned*)scalars)[SC_LPK2]=0u; }
    for (int e=tid; e<648; e+=256) sW[e]=fatoms[e];
    __syncthreads();
    if (tid<64){ int r=tid>>3, s=tid&7; float a=0.f;
        for (int k=0;k<81;++k) a=fmaf(sW[r*81+k],sW[s*81+k],a); sG[tid]=a; }
    __syncthreads();
    if (tid<64){
        int r8 = tid&7;
        float v = 1.f;
        for (int it=0; it<64; ++it){
            float nv=0.f;
            #pragma unroll
            for (int j=0;j<8;++j) nv = fmaf(sG[r8*8+j], __shfl(v,j,8), nv);
            float m = fabsf(nv);
            m = fmaxf(m, __shfl_xor(m,1,8));
            m = fmaxf(m, __shfl_xor(m,2,8));
            m = fmaxf(m, __shfl_xor(m,4,8));
            v = nv/m;
        }
        float wv=0.f;
        #pragma unroll
        for (int j=0;j<8;++j) wv = fmaf(sG[r8*8+j], __shfl(v,j,8), wv);
        float num=v*wv, den=v*v;
        num += __shfl_xor(num,1,8); num += __shfl_xor(num,2,8); num += __shfl_xor(num,4,8);
        den += __shfl_xor(den,1,8); den += __shfl_xor(den,2,8); den += __shfl_xor(den,4,8);
        if (tid==0) sSig = sqrtf(num/den);
    }
    __syncthreads();
    float inv_s = 1.f/sSig;
    for (int e=tid; e<648; e+=256) sW[e]*=inv_s;
    if (tid<64){ sG[tid]*=inv_s*inv_s; sP[tid]=((tid>>3)==(tid&7))?1.f:0.f; }
    __syncthreads();
    for (int it=0; it<15; ++it){
        if (tid<64) sF[tid] = (((tid>>3)==(tid&7))?1.5f:0.f) - 0.5f*sG[tid];
        __syncthreads();
        if (tid<64){ int r=tid>>3, c=tid&7; float ap=0.f, ag=0.f;
            #pragma unroll
            for (int k=0;k<8;++k){ float f=sF[r*8+k]; ap=fmaf(f,sP[k*8+c],ap); ag=fmaf(f,sG[k*8+c],ag); }
            sTmp[tid]=ap; sT[tid]=ag; }
        __syncthreads();
        if (tid<64){ int r=tid>>3, c=tid&7; float g2=0.f;
            #pragma unroll
            for (int k=0;k<8;++k) g2=fmaf(sT[r*8+k],sF[k*8+c],g2);
            sG[tid]=g2; sP[tid]=sTmp[tid]; }
        __syncthreads();
    }
    for (int e=tid; e<648; e+=256){ int r=e/81, j=e%81; float a=0.f;
        #pragma unroll
        for (int k=0;k<8;++k) a=fmaf(sP[r*8+k], sW[k*81+j], a);
        sWf[e]=a; }
    __syncthreads();
    for (int e=tid; e<6561; e+=256){ int i=e/81, j=e%81; float a=0.f;
        #pragma unroll
        for (int r=0;r<8;++r) a=fmaf(sWf[r*81+i],sWf[r*81+j],a);
        sGr[e]=a; gram_g[e]=a; }
    __syncthreads();
    if (tid<81){ float s=0.f; for (int k=0;k<81;++k) s+=sGr[tid*81+k]; rs[tid]=(1.f-s)/81.f; }
    __syncthreads();
    for (int e=tid; e<6561; e+=256){ int i=e/81, j=e%81;
        pf_g[e] = ((i==j)?1.f:0.f) - sGr[e] - rs[j]; }
}

// PP = pf^T pf (81x81), pf staged in LDS. 26 blocks x 256 thr.
__global__ __launch_bounds__(256) void k_PP(const float* __restrict__ pf, float* __restrict__ PP)
{
    __shared__ float spf[6561];
    for (int e=threadIdx.x; e<6561; e+=256) spf[e]=pf[e];
    __syncthreads();
    int e = blockIdx.x*256 + threadIdx.x;
    if (e>=6561) return;
    int al=e/81, be=e%81; float a=0.f;
    for (int c=0;c<81;++c) a=fmaf(spf[c*81+al], spf[c*81+be], a);
    PP[e]=a;
}

// proj_impulse (17x17) via PP lookups. One block, 320 thr (guard: t<289).
__global__ void k_impulse(const float* __restrict__ PP, float* __restrict__ pi)
{
    int t = threadIdx.x;
    if (t>=289) return;
    int h=t/17, w=t%17;
    float acc=0.f;
    for (int p=0;p<9;++p){
        int i2=(h+p-4+17)%17;
        if (i2<4||i2>12) continue;
        for (int q=0;q<9;++q){
            int j2=(w+q-4+17)%17;
            if (j2<4||j2>12) continue;
            int al=(12-i2)*9+(12-j2);
            int be=(8-p)*9+(8-q);
            acc += PP[al*81+be];
        }
    }
    pi[t]=acc;
}

// |FFT2(pi zero-padded to 128x128)|^2 max. 256 blocks x 64 thr (1 wave).
__global__ __launch_bounds__(64) void k_dft(const float* __restrict__ pi, float* __restrict__ scalars)
{
    __shared__ float spi[289], ct[128], st[128];
    int tid=threadIdx.x; int gid=blockIdx.x*64+tid;
    for (int e=tid; e<289; e+=64) spi[e]=pi[e];
    for (int e=tid; e<128; e+=64){ float ang=(float)e*(6.28318530717958647692f/128.f);
                  ct[e]=cosf(ang); st[e]=sinf(ang); }
    __syncthreads();
    int u=gid>>7, v=gid&127;
    float re=0.f, im=0.f;
    for (int i=0;i<17;++i){
        int ku=(u*i)&127;
        const float* prow=spi+i*17;
        for (int j=0;j<17;++j){
            int k=(ku+v*j)&127;
            float x=prow[j];
            re=fmaf(x,ct[k],re); im=fmaf(x,st[k],im);
        }
    }
    float m2=re*re+im*im;
    #pragma unroll
    for (int d=32; d; d>>=1) m2=fmaxf(m2, __shfl_down(m2,d));
    if (tid==0) atomicMax(((unsigned*)scalars)+SC_LPK2, __float_as_uint(m2));
}

// per-atom: center, subtract af@gram, row-normalize. Writes af_rn AND af_rnT.
__global__ __launch_bounds__(128) void k_atoms1(const float* __restrict__ atoms_in,
    const float* __restrict__ gram, float* __restrict__ af_rn, float* __restrict__ af_rnT)
{
    int a=blockIdx.x, tid=threadIdx.x;
    __shared__ float a0[81], a1[81], rbuf[128];
    float v = (tid<81)? atoms_in[a*81+tid] : 0.f;
    rbuf[tid]=v; __syncthreads();
    for (int off=64; off; off>>=1){ if (tid<off) rbuf[tid]+=rbuf[tid+off]; __syncthreads(); }
    float mean = rbuf[0]/81.f;
    __syncthreads();
    if (tid<81) a0[tid]=v-mean;
    __syncthreads();
    float w=0.f;
    if (tid<81){ float dot=0.f;
        for (int k=0;k<81;++k) dot=fmaf(a0[k], gram[k*81+tid], dot);
        w=a0[tid]-dot; a1[tid]=w; }
    rbuf[tid]=(tid<81)? w*w : 0.f;
    __syncthreads();
    for (int off=64; off; off>>=1){ if (tid<off) rbuf[tid]+=rbuf[tid+off]; __syncthreads(); }
    float inv = 1.f/sqrtf(rbuf[0]);
    if (tid<81){ float r=a1[tid]*inv; af_rn[a*81+tid]=r; af_rnT[tid*64+a]=r; }
}

// M = af_rn af_rn^T. 16 blocks x 256.
__global__ __launch_bounds__(256) void k_M(const float* __restrict__ af_rn,
    const float* __restrict__ af_rnT, float* __restrict__ M)
{
    int e=blockIdx.x*256+threadIdx.x;
    int i=e>>6, j=e&63;
    float a=0.f;
    for (int k=0;k<81;++k) a=fmaf(af_rn[i*81+k], af_rnT[(k<<6)+j], a);
    M[e]=a;
}

// OUT = IN*IN (symmetric). 16 blocks x 256. Chained for M^2,M^4,M^8,M^16.
// (1 <= lam1(M) <= 64 since af rows unit-norm => M^16 in fp32 range.)
__global__ __launch_bounds__(256) void k_M2(const float* __restrict__ IN,
    float* __restrict__ OUT)
{
    int e=blockIdx.x*256+threadIdx.x;
    int i=e>>6, j=e&63;
    float a=0.f;
    for (int k=0;k<64;++k) a=fmaf(IN[(i<<6)+k], IN[(k<<6)+j], a);
    OUT[e]=a;
}

// k_fin: one block. Power 8 iters on M^16 (m rows via float4), Rayleigh
// with M (LDS-staged), finalize atoms_f / atomsT / Xmat / scalars.
__global__ __launch_bounds__(256) void k_fin(const float* __restrict__ Mg,
    const float* __restrict__ MPg, const float* __restrict__ af_rn,
    float* __restrict__ scalars,
    float* __restrict__ atoms_f, float* __restrict__ atomsT, float* __restrict__ Xmat)
{
    __shared__ float sM[4096];
    __shared__ float sGc[2];
    int tid=threadIdx.x;
    for (int e=tid; e<4096; e+=256) sM[e]=Mg[e];
    __syncthreads();
    if (tid<64){
        float m[64];
        const float4* mp = reinterpret_cast<const float4*>(MPg + (tid<<6));
        #pragma unroll
        for (int j4=0;j4<16;++j4){
            float4 v4=mp[j4];
            m[j4*4+0]=v4.x; m[j4*4+1]=v4.y; m[j4*4+2]=v4.z; m[j4*4+3]=v4.w;
        }
        float v = 1.0f + 0.01f*(float)tid;
        for (int it=0; it<8; ++it){
            float a0=0.f,a1=0.f,a2=0.f,a3=0.f;
            #pragma unroll
            for (int j=0;j<64;j+=4){
                a0=fmaf(m[j+0], __shfl(v,j+0), a0);
                a1=fmaf(m[j+1], __shfl(v,j+1), a1);
                a2=fmaf(m[j+2], __shfl(v,j+2), a2);
                a3=fmaf(m[j+3], __shfl(v,j+3), a3);
            }
            float nv=(a0+a1)+(a2+a3);
            float mx=fabsf(nv);
            #pragma unroll
            for (int d=1; d<64; d<<=1) mx=fmaxf(mx, __shfl_xor(mx,d));
            v=nv/mx;
        }
        float w0=0.f,w1=0.f,w2=0.f,w3=0.f;
        #pragma unroll
        for (int j=0;j<64;j+=4){
            w0=fmaf(sM[(tid<<6)+j+0], __shfl(v,j+0), w0);
            w1=fmaf(sM[(tid<<6)+j+1], __shfl(v,j+1), w1);
            w2=fmaf(sM[(tid<<6)+j+2], __shfl(v,j+2), w2);
            w3=fmaf(sM[(tid<<6)+j+3], __shfl(v,j+3), w3);
        }
        float wv=(w0+w1)+(w2+w3);
        float num=v*wv, den=v*v;
        #pragma unroll
        for (int d=1; d<64; d<<=1){ num+=__shfl_xor(num,d); den+=__shfl_xor(den,d); }
        if (tid==0){
            float sig = sqrtf(num/den);
            float b = scalars[SC_BETA];
            float s = sqrtf(0.99f/fmaxf(b,0.1f));
            float g = s/sig;
            scalars[SC_G]=g; scalars[SC_G2]=g*g;
            float lpk = sqrtf(__uint_as_float(((unsigned*)scalars)[SC_LPK2]));
            scalars[SC_L] = 1.01f*b*lpk;
            sGc[0]=g; sGc[1]=g*g;
        }
    }
    __syncthreads();
    float g=sGc[0], g2=sGc[1];
    for (int idx=tid; idx<5184; idx+=256){
        int a=idx/81, pq=idx-a*81;
        float v=g*af_rn[idx];
        atoms_f[idx]=v;
        atomsT[pq*64+a]=v;
    }
    for (int e=tid; e<4096; e+=256) Xmat[e]=g2*sM[e];
}

// ---------------------------------------------------------------------------
// kA: coefficient update, [b][ch][pix]. grid (strip,b) = (64,4), 512 thr.
// Phase 0: stage temp[64][256] in LDS (each global value read ONCE).
// Phase 1: GEMM from LDS temp. Conv: simg in LDS. Phase 3: 1KB-contiguous.
template<bool FIRST>
__global__ __launch_bounds__(512) void kA(const float* __restrict__ c_in,
    const float* __restrict__ nc_in, const float* __restrict__ nimg,
    const float* __restrict__ Xmat, const float* __restrict__ atomsT,
    const float* __restrict__ scalars, const float* __restrict__ lmbda_p,
    const float* __restrict__ red_in,
    float* __restrict__ c_out, float* __restrict__ nc_out, float mom)
{
    int b=blockIdx.y, st=blockIdx.x;
    int tid=threadIdx.x;
    int wv = __builtin_amdgcn_readfirstlane(tid>>6);   // wave id 0..7
    int lane = tid&63;
    int co = wv*8;
    int h0 = st*2;
    int px = lane*4;
    int prow = px>>7, pcol = px&127;
    __shared__ float sTemp[64*256];   // 64 KB: temp [ch][px-in-strip]
    __shared__ float simg[10*128];
    __shared__ float sAct;
    if (FIRST){ if (tid==0) sAct=1.f; }
    else if (tid<64){
        float sd=red_in[(b<<7)+(tid<<1)], si=red_in[(b<<7)+(tid<<1)+1];
        #pragma unroll
        for (int off=32; off; off>>=1){ sd+=__shfl_down(sd,off); si+=__shfl_down(si,off); }
        if (tid==0) sAct = (sd > TOLV*TOLV*si) ? 1.f : 0.f;
    }
    for (int e=tid; e<1280; e+=512)
        simg[e]=nimg[b*NPIX + (((h0-4+(e>>7))&127)<<7) + (e&127)];
    size_t sbase = (size_t)b*NPB + (h0<<7);
    if (!FIRST){
        for (int e=tid; e<4096; e+=512){
            int ch = e>>6, pxg = e&63;
            size_t a = sbase + (size_t)ch*NPIX + pxg*4;
            float4 cv=*reinterpret_cast<const float4*>(c_in + a);
            float4 nv=*reinterpret_cast<const float4*>(nc_in + a);
            float4 t;
            t.x=fmaf(mom,nv.x-cv.x,nv.x); t.y=fmaf(mom,nv.y-cv.y,nv.y);
            t.z=fmaf(mom,nv.z-cv.z,nv.z); t.w=fmaf(mom,nv.w-cv.w,nv.w);
            *reinterpret_cast<float4*>(sTemp + ch*256 + pxg*4) = t;
        }
    }
    __syncthreads();
    const float* Xo = Xmat + co;
    const float* Ao = atomsT + co;
    float acc[32];
    #pragma unroll
    for (int i=0;i<32;++i) acc[i]=0.f;
    if (!FIRST){
        for (int c=0;c<64;++c){
            float4 t=*reinterpret_cast<const float4*>(sTemp + c*256 + px);
            const float* Xr = Xo + (c<<6);
            #pragma unroll
            for (int oc=0;oc<8;++oc){
                float x=Xr[oc];
                acc[oc*4+0]=fmaf(x,t.x,acc[oc*4+0]);
                acc[oc*4+1]=fmaf(x,t.y,acc[oc*4+1]);
                acc[oc*4+2]=fmaf(x,t.z,acc[oc*4+2]);
                acc[oc*4+3]=fmaf(x,t.w,acc[oc*4+3]);
            }
        }
    }
    for (int p=0;p<9;++p){
        const float* srow = simg + (prow+p)*128;
        float in12[12];
        #pragma unroll
        for (int k4=0;k4<3;++k4){
            int col=(pcol-4+(k4<<2))&127;
            const float4 vv=*reinterpret_cast<const float4*>(srow+col);
            in12[k4*4+0]=vv.x; in12[k4*4+1]=vv.y;
            in12[k4*4+2]=vv.z; in12[k4*4+3]=vv.w;
        }
        #pragma unroll 3
        for (int q=0;q<9;++q){
            const float* Ar = Ao + ((p*9+q)<<6);
            #pragma unroll
            for (int oc=0;oc<8;++oc){
                float a=Ar[oc];
                acc[oc*4+0]=fmaf(a,-in12[q+0],acc[oc*4+0]);
                acc[oc*4+1]=fmaf(a,-in12[q+1],acc[oc*4+1]);
                acc[oc*4+2]=fmaf(a,-in12[q+2],acc[oc*4+2]);
                acc[oc*4+3]=fmaf(a,-in12[q+3],acc[oc*4+3]);
            }
        }
    }
    float beta=scalars[SC_BETA], lmb=lmbda_p[0];
    bool act = (sAct!=0.f);
    #pragma unroll
    for (int oc=0;oc<8;++oc){
        size_t a = sbase + (size_t)(co+oc)*NPIX + px;
        float4 nv, cv;
        if (FIRST){ nv=make_float4(0.f,0.f,0.f,0.f); cv=nv; }
        else {
            nv=*reinterpret_cast<const float4*>(nc_in + a);
            cv=*reinterpret_cast<const float4*>(c_in  + a);
        }
        float4 nw, cw;
        {
            float t=FIRST?0.f:fmaf(mom,nv.x-cv.x,nv.x);
            float u=fmaf(-beta,acc[oc*4+0],t); float au=fabsf(u)-lmb;
            u=(au>0.f)?copysignf(au,u):0.f; nw.x=act?u:nv.x; cw.x=act?nv.x:cv.x;
        }{
            float t=FIRST?0.f:fmaf(mom,nv.y-cv.y,nv.y);
            float u=fmaf(-beta,acc[oc*4+1],t); float au=fabsf(u)-lmb;
            u=(au>0.f)?copysignf(au,u):0.f; nw.y=act?u:nv.y; cw.y=act?nv.y:cv.y;
        }{
            float t=FIRST?0.f:fmaf(mom,nv.z-cv.z,nv.z);
            float u=fmaf(-beta,acc[oc*4+2],t); float au=fabsf(u)-lmb;
            u=(au>0.f)?copysignf(au,u):0.f; nw.z=act?u:nv.z; cw.z=act?nv.z:cv.z;
        }{
            float t=FIRST?0.f:fmaf(mom,nv.w-cv.w,nv.w);
            float u=fmaf(-beta,acc[oc*4+3],t); float au=fabsf(u)-lmb;
            u=(au>0.f)?copysignf(au,u):0.f; nw.w=act?u:nv.w; cw.w=act?nv.w:cv.w;
        }
        *reinterpret_cast<float4*>(c_out  + a) = cw;
        *reinterpret_cast<float4*>(nc_out + a) = nw;
    }
}

// kB1: dict_pred partials, CHANNEL-split. grid (8 rowblk, 16 cgroup, 4 b)
// = 512 blocks of 256 thr. 16 rows/block, 8 px/thread, 4 ch per cgroup.
__global__ __launch_bounds__(256,4) void kB1(const float* __restrict__ nc2,
    const float* __restrict__ atoms_f, float* __restrict__ part)
{
    int b=blockIdx.z, cg=blockIdx.y, pb=blockIdx.x;
    int t=threadIdx.x;
    int row = pb*16 + (t>>4);
    int cb  = (t&15)*8;
    const float* src = nc2 + (b*NCH + cg*4)*NPIX;
    float acc[8];
    #pragma unroll
    for (int k=0;k<8;++k) acc[k]=0.f;
    for (int c=0;c<4;++c){
        const float* chan = src + c*NPIX;
        const float* arow = atoms_f + (cg*4+c)*81;
        #pragma unroll 3
        for (int p=0;p<9;++p){
            int r=(row+4-p)&127;
            const float* rp_ = chan + (r<<7);
            float in16[16];
            #pragma unroll
            for (int k4=0;k4<4;++k4){
                int col=(cb-4+(k4<<2))&127;
                const float4 vv = *reinterpret_cast<const float4*>(rp_+col);
                in16[(k4<<2)+0]=vv.x; in16[(k4<<2)+1]=vv.y;
                in16[(k4<<2)+2]=vv.z; in16[(k4<<2)+3]=vv.w;
            }
            #pragma unroll
            for (int q=0;q<9;++q){
                float a = arow[p*9+q];
                #pragma unroll
                for (int k=0;k<8;++k) acc[k]=fmaf(in16[k+8-q], a, acc[k]);
            }
        }
    }
    float* dst = part + (cg*NB+b)*NPIX + (row<<7) + cb;
    #pragma unroll
    for (int k=0;k<8;++k) dst[k]=acc[k];
}

// kB2: image update + residual partials. 512 thr: halves split the 17-tap
// p-loop (9/8), merged via LDS; px work+writes by half 0.
template<bool FIRST>
__global__ __launch_bounds__(512) void kB2(const float* __restrict__ img,
    const float* __restrict__ nimg, const float* __restrict__ y,
    const float* __restrict__ part, const float* __restrict__ pi,
    const float* __restrict__ scalars, const float* __restrict__ red_in,
    float* __restrict__ img_out, float* __restrict__ nimg_out,
    float* __restrict__ red_out, float mom)
{
    int b=blockIdx.y, rp=blockIdx.x;
    int tid=threadIdx.x;
    int half=tid>>8, lid=tid&255;
    int ty=lid>>7, w=lid&127;
    int h0=rp*2;
    __shared__ float sti[18*128];
    __shared__ float spi[289];
    __shared__ float sP2[256];
    __shared__ float rsd[4], rsi[4];
    __shared__ float sAct;
    if (FIRST){ if (tid==0) sAct=1.f; }
    else if (tid<64){
        float sd=red_in[(b<<7)+(tid<<1)], si=red_in[(b<<7)+(tid<<1)+1];
        #pragma unroll
        for (int off=32; off; off>>=1){ sd+=__shfl_down(sd,off); si+=__shfl_down(si,off); }
        if (tid==0) sAct = (sd > TOLV*TOLV*si) ? 1.f : 0.f;
    }
    const float* ib  = img  + b*NPIX;
    const float* nib = nimg + b*NPIX;
    for (int e=tid; e<2304; e+=512){
        int r=e>>7, cc=e&127;
        int idx=(((h0-8+r)&127)<<7)+cc;
        float nv=nib[idx], v=ib[idx];
        sti[e]=fmaf(mom, nv-v, nv);
    }
    for (int e=tid; e<289; e+=512) spi[e]=pi[e];
    __syncthreads();
    float sp=0.f;
    int pn = 9 - half;              // half 0: p=0..8; half 1: p=9..16
    for (int pk=0; pk<pn; ++pk){
        int p = half*9 + pk;
        const float* srow = sti + (ty+p)*128;
        const float* pr = spi + p*17;
        #pragma unroll
        for (int q=0;q<17;++q) sp=fmaf(srow[(w+q-8)&127], pr[q], sp);
    }
    if (half==1) sP2[lid]=sp;
    __syncthreads();
    if (tid<256){
        sp += sP2[lid];
        int pix=((h0+ty)<<7)+w;
        float dp=0.f;
        #pragma unroll
        for (int g=0; g<NPG; ++g) dp += part[(g*NB+b)*NPIX + pix];
        float ti = sti[(ty+8)*128 + w];
        float beta=scalars[SC_BETA], L=scalars[SC_L];
        float yv=y[b*NPIX+pix];
        float upd = ti - (ti - yv + beta*(sp - dp))/L;
        bool act = (sAct!=0.f);
        float iv=ib[pix], niv=nib[pix];
        float i2 = act? niv : iv;
        float ni2 = act? upd : niv;
        img_out[b*NPIX+pix]=i2;
        nimg_out[b*NPIX+pix]=ni2;
        float d=i2-ni2;
        float sd=d*d, si=i2*i2;
        #pragma unroll
        for (int off=32; off; off>>=1){ sd+=__shfl_down(sd,off); si+=__shfl_down(si,off); }
        if ((tid&63)==0){ rsd[tid>>6]=sd; rsi[tid>>6]=si; }
    }
    __syncthreads();
    if (tid==0){
        float a=rsd[0]+rsd[1]+rsd[2]+rsd[3];
        float c2=rsi[0]+rsi[1]+rsi[2]+rsi[3];
        red_out[(b<<7)+(rp<<1)+0]=a;
        red_out[(b<<7)+(rp<<1)+1]=c2;
    }
}

// ---------------------------------------------------------------------------
extern "C" void kernel_launch(void* const* d_in, const int* in_sizes, int n_in,
                              void* d_out, int out_size, void* d_ws, size_t ws_size,
                              hipStream_t stream)
{
    const float* y        = (const float*)d_in[0];
    const float* atoms_p  = (const float*)d_in[1];
    const float* fatoms_p = (const float*)d_in[2];
    const float* beta_p   = (const float*)d_in[3];
    const float* lmbda_p  = (const float*)d_in[4];
    float* out = (float*)d_out;
    float* w = (float*)d_ws;

    size_t off=0;
    float* cb[2];  cb[0]=w+off;  off+=NCOEF; cb[1]=w+off;  off+=NCOEF;   // [b][ch][pix]
    float* ncb[2]; ncb[0]=w+off; off+=NCOEF; ncb[1]=w+off; off+=NCOEF;   // [b][ch][pix]
    float* ib[2];  ib[0]=w+off;  off+=NIMG;  ib[1]=w+off;  off+=NIMG;
    float* nib[2]; nib[0]=w+off; off+=NIMG;  nib[1]=w+off; off+=NIMG;
    float* part=w+off;    off+=NPG*NIMG;
    float* red[2]; red[0]=w+off; off+=512; red[1]=w+off; off+=512;
    float* gram=w+off;    off+=6561;
    float* pf=w+off;      off+=6561;
    float* PP=w+off;      off+=6561;
    float* pi=w+off;      off+=512;
    float* af_rn=w+off;   off+=5184;
    float* af_rnT=w+off;  off+=5184;
    float* Mmat=w+off;    off+=4096;
    float* MA=w+off;      off+=4096;
    float* MB=w+off;      off+=4096;
    float* atoms_f=w+off; off+=5184;
    float* atomsT=w+off;  off+=5184;
    float* Xmat=w+off;    off+=4096;
    float* scalars=w+off; off+=32;

    k_prep1<<<dim3(1),dim3(256),0,stream>>>(fatoms_p, beta_p, gram, pf, scalars);
    k_PP<<<dim3(26),dim3(256),0,stream>>>(pf, PP);
    k_impulse<<<dim3(1),dim3(320),0,stream>>>(PP, pi);
    k_dft<<<dim3(256),dim3(64),0,stream>>>(pi, scalars);
    k_atoms1<<<dim3(64),dim3(128),0,stream>>>(atoms_p, gram, af_rn, af_rnT);
    k_M<<<dim3(16),dim3(256),0,stream>>>(af_rn, af_rnT, Mmat);
    k_M2<<<dim3(16),dim3(256),0,stream>>>(Mmat, MA);   // M^2
    k_M2<<<dim3(16),dim3(256),0,stream>>>(MA, MB);     // M^4
    k_M2<<<dim3(16),dim3(256),0,stream>>>(MB, MA);     // M^8
    k_M2<<<dim3(16),dim3(256),0,stream>>>(MA, MB);     // M^16
    k_fin<<<dim3(1),dim3(256),0,stream>>>(Mmat, MB, af_rn, scalars, atoms_f, atomsT, Xmat);

    int p=0;
    for (int k=1; k<=20; ++k){
        float mom = (float)(k-1)/(float)(k+2);
        const float* rin = red[(k-1)&1];
        float* rout = red[k&1];
        const float* img_i  = (k==1)? y : ib[p];
        const float* nimg_i = (k==1)? y : nib[p];
        float* nc_t  = (k==20)? (out+NIMG) : ncb[p^1];
        float* nimg_t= (k==20)? out : nib[p^1];
        if (k==1){
            kA<true><<<dim3(64,4),dim3(512),0,stream>>>(cb[p],ncb[p],nimg_i,Xmat,atomsT,
                scalars,lmbda_p,rin, cb[p^1],nc_t,mom);
        } else {
            kA<false><<<dim3(64,4),dim3(512),0,stream>>>(cb[p],ncb[p],nimg_i,Xmat,atomsT,
                scalars,lmbda_p,rin, cb[p^1],nc_t,mom);
        }
        kB1<<<dim3(8,16,4),dim3(256),0,stream>>>(nc_t, atoms_f, part);
        if (k==1){
            kB2<true><<<dim3(64,4),dim3(512),0,stream>>>(img_i,nimg_i,y,part,pi,scalars,rin,
                ib[p^1],nimg_t,rout,mom);
        } else {
            kB2<false><<<dim3(64,4),dim3(512),0,stream>>>(img_i,nimg_i,y,part,pi,scalars,rin,
                ib[p^1],nimg_t,rout,mom);
        }
        p^=1;
    }
}

// Round 18
// 1251.593 us; speedup vs baseline: 1.5986x; 1.0439x over previous
//
#include <hip/hip_runtime.h>
#include <math.h>

// ---------------------------------------------------------------------------
// Dictionary_56212531970303 : FISTA dictionary forward on MI355X, fp32.
// Layout: coefficient state [b][ch][pix]. Per-INSTRUCTION contiguity rule
// (round-13): state loads/stores = 64 lanes x (float4|float2) contiguous.
// Setup: prep1, k_PP, k_impulse, k_dft, atoms1, k_M, k_M2 x4 (repeated
//        squaring; round-16), k_fin (8 power iters on M^16).
// Loop (20 iters):
//   kA  — 1-ROW strips, grid (128,4)=512 blocks (round-17: 256 blocks was
//         1 blk/CU = 2 waves/SIMD, 30% duty). sTemp[64][128]=32KB -> 2
//         blocks/CU = 4 waves/SIMD. Wave = 8-oc slice, lane = 2px float2.
//   kB1 — 32 cgroups x 2ch (channel split, zero amplification), 1024 blocks
//         = 4 waves/SIMD.
//   kB2 — 512-thr, 17-tap conv split across halves; sums 32 partials.
// Iter 1 templated FIRST; iter 20 writes nc/img directly into d_out.
// NOTE: every "if (tid<N)" with N>blockDim must be a grid-stride loop —
// round-2/3 regression (absmax 0.134).
// ---------------------------------------------------------------------------

#define NB 4
#define NCH 64
#define NPIX 16384              // 128*128
#define NPB (NCH*NPIX)
#define NCOEF (NB*NCH*NPIX)     // 4194304
#define NIMG  (NB*NPIX)         // 65536
#define NPG 32                  // partial channel-groups (2 ch each)
#define TOLV 1e-4f

#define SC_BETA 0
#define SC_L    1
#define SC_G    4
#define SC_G2   5
#define SC_LPK2 6

// ---------------------------------------------------------------------------
// prep1: one block. bjorck via 8x8 gram-iteration; writes gram + pf + scalars.
__global__ __launch_bounds__(256) void k_prep1(const float* __restrict__ fatoms,
    const float* __restrict__ beta_p,
    float* __restrict__ gram_g, float* __restrict__ pf_g,
    float* __restrict__ scalars)
{
    __shared__ float sW[648], sWf[648];
    __shared__ float sG[64], sP[64], sF[64], sT[64], sTmp[64];
    __shared__ float sGr[6561];
    __shared__ float rs[81];
    __shared__ float sSig;
    int tid = threadIdx.x;
    if (tid==0){ float b=beta_p[0]; scalars[SC_BETA]=(b>0.f)?b:0.f;
                 ((unsigned*)scalars)[SC_LPK2]=0u; }
    for (int e=tid; e<648; e+=256) sW[e]=fatoms[e];
    __syncthreads();
    if (tid<64){ int r=tid>>3, s=tid&7; float a=0.f;
        for (int k=0;k<81;++k) a=fmaf(sW[r*81+k],sW[s*81+k],a); sG[tid]=a; }
    __syncthreads();
    if (tid<64){
        int r8 = tid&7;
        float v = 1.f;
        for (int it=0; it<64; ++it){
            float nv=0.f;
            #pragma unroll
            for (int j=0;j<8;++j) nv = fmaf(sG[r8*8+j], __shfl(v,j,8), nv);
            float m = fabsf(nv);
            m = fmaxf(m, __shfl_xor(m,1,8));
            m = fmaxf(m, __shfl_xor(m,2,8));
            m = fmaxf(m, __shfl_xor(m,4,8));
            v = nv/m;
        }
        float wv=0.f;
        #pragma unroll
        for (int j=0;j<8;++j) wv = fmaf(sG[r8*8+j], __shfl(v,j,8), wv);
        float num=v*wv, den=v*v;
        num += __shfl_xor(num,1,8); num += __shfl_xor(num,2,8); num += __shfl_xor(num,4,8);
        den += __shfl_xor(den,1,8); den += __shfl_xor(den,2,8); den += __shfl_xor(den,4,8);
        if (tid==0) sSig = sqrtf(num/den);
    }
    __syncthreads();
    float inv_s = 1.f/sSig;
    for (int e=tid; e<648; e+=256) sW[e]*=inv_s;
    if (tid<64){ sG[tid]*=inv_s*inv_s; sP[tid]=((tid>>3)==(tid&7))?1.f:0.f; }
    __syncthreads();
    for (int it=0; it<15; ++it){
        if (tid<64) sF[tid] = (((tid>>3)==(tid&7))?1.5f:0.f) - 0.5f*sG[tid];
        __syncthreads();
        if (tid<64){ int r=tid>>3, c=tid&7; float ap=0.f, ag=0.f;
            #pragma unroll
            for (int k=0;k<8;++k){ float f=sF[r*8+k]; ap=fmaf(f,sP[k*8+c],ap); ag=fmaf(f,sG[k*8+c],ag); }
            sTmp[tid]=ap; sT[tid]=ag; }
        __syncthreads();
        if (tid<64){ int r=tid>>3, c=tid&7; float g2=0.f;
            #pragma unroll
            for (int k=0;k<8;++k) g2=fmaf(sT[r*8+k],sF[k*8+c],g2);
            sG[tid]=g2; sP[tid]=sTmp[tid]; }
        __syncthreads();
    }
    for (int e=tid; e<648; e+=256){ int r=e/81, j=e%81; float a=0.f;
        #pragma unroll
        for (int k=0;k<8;++k) a=fmaf(sP[r*8+k], sW[k*81+j], a);
        sWf[e]=a; }
    __syncthreads();
    for (int e=tid; e<6561; e+=256){ int i=e/81, j=e%81; float a=0.f;
        #pragma unroll
        for (int r=0;r<8;++r) a=fmaf(sWf[r*81+i],sWf[r*81+j],a);
        sGr[e]=a; gram_g[e]=a; }
    __syncthreads();
    if (tid<81){ float s=0.f; for (int k=0;k<81;++k) s+=sGr[tid*81+k]; rs[tid]=(1.f-s)/81.f; }
    __syncthreads();
    for (int e=tid; e<6561; e+=256){ int i=e/81, j=e%81;
        pf_g[e] = ((i==j)?1.f:0.f) - sGr[e] - rs[j]; }
}

// PP = pf^T pf (81x81), pf staged in LDS. 26 blocks x 256 thr.
__global__ __launch_bounds__(256) void k_PP(const float* __restrict__ pf, float* __restrict__ PP)
{
    __shared__ float spf[6561];
    for (int e=threadIdx.x; e<6561; e+=256) spf[e]=pf[e];
    __syncthreads();
    int e = blockIdx.x*256 + threadIdx.x;
    if (e>=6561) return;
    int al=e/81, be=e%81; float a=0.f;
    for (int c=0;c<81;++c) a=fmaf(spf[c*81+al], spf[c*81+be], a);
    PP[e]=a;
}

// proj_impulse (17x17) via PP lookups. One block, 320 thr (guard: t<289).
__global__ void k_impulse(const float* __restrict__ PP, float* __restrict__ pi)
{
    int t = threadIdx.x;
    if (t>=289) return;
    int h=t/17, w=t%17;
    float acc=0.f;
    for (int p=0;p<9;++p){
        int i2=(h+p-4+17)%17;
        if (i2<4||i2>12) continue;
        for (int q=0;q<9;++q){
            int j2=(w+q-4+17)%17;
            if (j2<4||j2>12) continue;
            int al=(12-i2)*9+(12-j2);
            int be=(8-p)*9+(8-q);
            acc += PP[al*81+be];
        }
    }
    pi[t]=acc;
}

// |FFT2(pi zero-padded to 128x128)|^2 max. 256 blocks x 64 thr (1 wave).
__global__ __launch_bounds__(64) void k_dft(const float* __restrict__ pi, float* __restrict__ scalars)
{
    __shared__ float spi[289], ct[128], st[128];
    int tid=threadIdx.x; int gid=blockIdx.x*64+tid;
    for (int e=tid; e<289; e+=64) spi[e]=pi[e];
    for (int e=tid; e<128; e+=64){ float ang=(float)e*(6.28318530717958647692f/128.f);
                  ct[e]=cosf(ang); st[e]=sinf(ang); }
    __syncthreads();
    int u=gid>>7, v=gid&127;
    float re=0.f, im=0.f;
    for (int i=0;i<17;++i){
        int ku=(u*i)&127;
        const float* prow=spi+i*17;
        for (int j=0;j<17;++j){
            int k=(ku+v*j)&127;
            float x=prow[j];
            re=fmaf(x,ct[k],re); im=fmaf(x,st[k],im);
        }
    }
    float m2=re*re+im*im;
    #pragma unroll
    for (int d=32; d; d>>=1) m2=fmaxf(m2, __shfl_down(m2,d));
    if (tid==0) atomicMax(((unsigned*)scalars)+SC_LPK2, __float_as_uint(m2));
}

// per-atom: center, subtract af@gram, row-normalize. Writes af_rn AND af_rnT.
__global__ __launch_bounds__(128) void k_atoms1(const float* __restrict__ atoms_in,
    const float* __restrict__ gram, float* __restrict__ af_rn, float* __restrict__ af_rnT)
{
    int a=blockIdx.x, tid=threadIdx.x;
    __shared__ float a0[81], a1[81], rbuf[128];
    float v = (tid<81)? atoms_in[a*81+tid] : 0.f;
    rbuf[tid]=v; __syncthreads();
    for (int off=64; off; off>>=1){ if (tid<off) rbuf[tid]+=rbuf[tid+off]; __syncthreads(); }
    float mean = rbuf[0]/81.f;
    __syncthreads();
    if (tid<81) a0[tid]=v-mean;
    __syncthreads();
    float w=0.f;
    if (tid<81){ float dot=0.f;
        for (int k=0;k<81;++k) dot=fmaf(a0[k], gram[k*81+tid], dot);
        w=a0[tid]-dot; a1[tid]=w; }
    rbuf[tid]=(tid<81)? w*w : 0.f;
    __syncthreads();
    for (int off=64; off; off>>=1){ if (tid<off) rbuf[tid]+=rbuf[tid+off]; __syncthreads(); }
    float inv = 1.f/sqrtf(rbuf[0]);
    if (tid<81){ float r=a1[tid]*inv; af_rn[a*81+tid]=r; af_rnT[tid*64+a]=r; }
}

// M = af_rn af_rn^T. 16 blocks x 256.
__global__ __launch_bounds__(256) void k_M(const float* __restrict__ af_rn,
    const float* __restrict__ af_rnT, float* __restrict__ M)
{
    int e=blockIdx.x*256+threadIdx.x;
    int i=e>>6, j=e&63;
    float a=0.f;
    for (int k=0;k<81;++k) a=fmaf(af_rn[i*81+k], af_rnT[(k<<6)+j], a);
    M[e]=a;
}

// OUT = IN*IN (symmetric). 16 blocks x 256. Chained for M^2..M^16.
__global__ __launch_bounds__(256) void k_M2(const float* __restrict__ IN,
    float* __restrict__ OUT)
{
    int e=blockIdx.x*256+threadIdx.x;
    int i=e>>6, j=e&63;
    float a=0.f;
    for (int k=0;k<64;++k) a=fmaf(IN[(i<<6)+k], IN[(k<<6)+j], a);
    OUT[e]=a;
}

// k_fin: one block. Power 8 iters on M^16, Rayleigh with M, finalize.
__global__ __launch_bounds__(256) void k_fin(const float* __restrict__ Mg,
    const float* __restrict__ MPg, const float* __restrict__ af_rn,
    float* __restrict__ scalars,
    float* __restrict__ atoms_f, float* __restrict__ atomsT, float* __restrict__ Xmat)
{
    __shared__ float sM[4096];
    __shared__ float sGc[2];
    int tid=threadIdx.x;
    for (int e=tid; e<4096; e+=256) sM[e]=Mg[e];
    __syncthreads();
    if (tid<64){
        float m[64];
        const float4* mp = reinterpret_cast<const float4*>(MPg + (tid<<6));
        #pragma unroll
        for (int j4=0;j4<16;++j4){
            float4 v4=mp[j4];
            m[j4*4+0]=v4.x; m[j4*4+1]=v4.y; m[j4*4+2]=v4.z; m[j4*4+3]=v4.w;
        }
        float v = 1.0f + 0.01f*(float)tid;
        for (int it=0; it<8; ++it){
            float a0=0.f,a1=0.f,a2=0.f,a3=0.f;
            #pragma unroll
            for (int j=0;j<64;j+=4){
                a0=fmaf(m[j+0], __shfl(v,j+0), a0);
                a1=fmaf(m[j+1], __shfl(v,j+1), a1);
                a2=fmaf(m[j+2], __shfl(v,j+2), a2);
                a3=fmaf(m[j+3], __shfl(v,j+3), a3);
            }
            float nv=(a0+a1)+(a2+a3);
            float mx=fabsf(nv);
            #pragma unroll
            for (int d=1; d<64; d<<=1) mx=fmaxf(mx, __shfl_xor(mx,d));
            v=nv/mx;
        }
        float w0=0.f,w1=0.f,w2=0.f,w3=0.f;
        #pragma unroll
        for (int j=0;j<64;j+=4){
            w0=fmaf(sM[(tid<<6)+j+0], __shfl(v,j+0), w0);
            w1=fmaf(sM[(tid<<6)+j+1], __shfl(v,j+1), w1);
            w2=fmaf(sM[(tid<<6)+j+2], __shfl(v,j+2), w2);
            w3=fmaf(sM[(tid<<6)+j+3], __shfl(v,j+3), w3);
        }
        float wv=(w0+w1)+(w2+w3);
        float num=v*wv, den=v*v;
        #pragma unroll
        for (int d=1; d<64; d<<=1){ num+=__shfl_xor(num,d); den+=__shfl_xor(den,d); }
        if (tid==0){
            float sig = sqrtf(num/den);
            float b = scalars[SC_BETA];
            float s = sqrtf(0.99f/fmaxf(b,0.1f));
            float g = s/sig;
            scalars[SC_G]=g; scalars[SC_G2]=g*g;
            float lpk = sqrtf(__uint_as_float(((unsigned*)scalars)[SC_LPK2]));
            scalars[SC_L] = 1.01f*b*lpk;
            sGc[0]=g; sGc[1]=g*g;
        }
    }
    __syncthreads();
    float g=sGc[0], g2=sGc[1];
    for (int idx=tid; idx<5184; idx+=256){
        int a=idx/81, pq=idx-a*81;
        float v=g*af_rn[idx];
        atoms_f[idx]=v;
        atomsT[pq*64+a]=v;
    }
    for (int e=tid; e<4096; e+=256) Xmat[e]=g2*sM[e];
}

// ---------------------------------------------------------------------------
// kA: coefficient update, [b][ch][pix]. 1-ROW strips: grid (128,4), 512 thr
// (2 blocks/CU = 4 waves/SIMD). Wave = 8-oc slice; lane = 2 px (float2).
// Phase 0: stage temp[64][128] in LDS once. Phase 1: GEMM from LDS.
// Conv: simg 9 rows, compile-time-indexed scalar LDS reads.
template<bool FIRST>
__global__ __launch_bounds__(512) void kA(const float* __restrict__ c_in,
    const float* __restrict__ nc_in, const float* __restrict__ nimg,
    const float* __restrict__ Xmat, const float* __restrict__ atomsT,
    const float* __restrict__ scalars, const float* __restrict__ lmbda_p,
    const float* __restrict__ red_in,
    float* __restrict__ c_out, float* __restrict__ nc_out, float mom)
{
    int b=blockIdx.y, h0=blockIdx.x;       // one image row per block
    int tid=threadIdx.x;
    int wv = __builtin_amdgcn_readfirstlane(tid>>6);   // wave id 0..7
    int lane = tid&63;
    int co = wv*8;
    int px = lane*2;                        // 0..126, even
    __shared__ float sTemp[64*128];         // 32 KB
    __shared__ float simg[9*128];
    __shared__ float sAct;
    if (FIRST){ if (tid==0) sAct=1.f; }
    else if (tid<64){
        float sd=red_in[(b<<7)+(tid<<1)], si=red_in[(b<<7)+(tid<<1)+1];
        #pragma unroll
        for (int off=32; off; off>>=1){ sd+=__shfl_down(sd,off); si+=__shfl_down(si,off); }
        if (tid==0) sAct = (sd > TOLV*TOLV*si) ? 1.f : 0.f;
    }
    for (int e=tid; e<1152; e+=512)
        simg[e]=nimg[b*NPIX + (((h0-4+(e>>7))&127)<<7) + (e&127)];
    size_t sbase = (size_t)b*NPB + (h0<<7);
    if (!FIRST){
        // stage temp once: 2048 float4 granules over 512 thr
        for (int e=tid; e<2048; e+=512){
            int ch = e>>5, pxg = e&31;
            size_t a = sbase + (size_t)ch*NPIX + pxg*4;
            float4 cv=*reinterpret_cast<const float4*>(c_in + a);
            float4 nv=*reinterpret_cast<const float4*>(nc_in + a);
            float4 t;
            t.x=fmaf(mom,nv.x-cv.x,nv.x); t.y=fmaf(mom,nv.y-cv.y,nv.y);
            t.z=fmaf(mom,nv.z-cv.z,nv.z); t.w=fmaf(mom,nv.w-cv.w,nv.w);
            *reinterpret_cast<float4*>(sTemp + ch*128 + pxg*4) = t;
        }
    }
    __syncthreads();
    const float* Xo = Xmat + co;
    const float* Ao = atomsT + co;
    float acc[16];                          // [oc][2px]
    #pragma unroll
    for (int i=0;i<16;++i) acc[i]=0.f;
    if (!FIRST){
        for (int c=0;c<64;++c){
            float2 t=*reinterpret_cast<const float2*>(sTemp + c*128 + px);
            const float* Xr = Xo + (c<<6);
            #pragma unroll
            for (int oc=0;oc<8;++oc){
                float x=Xr[oc];
                acc[oc*2+0]=fmaf(x,t.x,acc[oc*2+0]);
                acc[oc*2+1]=fmaf(x,t.y,acc[oc*2+1]);
            }
        }
    }
    for (int p=0;p<9;++p){
        const float* srow = simg + p*128;
        float in10[10];
        #pragma unroll
        for (int j=0;j<10;++j) in10[j]=srow[(px-4+j)&127];
        #pragma unroll 3
        for (int q=0;q<9;++q){
            const float* Ar = Ao + ((p*9+q)<<6);
            #pragma unroll
            for (int oc=0;oc<8;++oc){
                float a=Ar[oc];
                acc[oc*2+0]=fmaf(a,-in10[q+0],acc[oc*2+0]);
                acc[oc*2+1]=fmaf(a,-in10[q+1],acc[oc*2+1]);
            }
        }
    }
    float beta=scalars[SC_BETA], lmb=lmbda_p[0];
    bool act = (sAct!=0.f);
    #pragma unroll
    for (int oc=0;oc<8;++oc){
        size_t a = sbase + (size_t)(co+oc)*NPIX + px;
        float2 nv, cv;
        if (FIRST){ nv=make_float2(0.f,0.f); cv=nv; }
        else {
            nv=*reinterpret_cast<const float2*>(nc_in + a);
            cv=*reinterpret_cast<const float2*>(c_in  + a);
        }
        float2 nw, cw;
        {
            float t=FIRST?0.f:fmaf(mom,nv.x-cv.x,nv.x);
            float u=fmaf(-beta,acc[oc*2+0],t); float au=fabsf(u)-lmb;
            u=(au>0.f)?copysignf(au,u):0.f; nw.x=act?u:nv.x; cw.x=act?nv.x:cv.x;
        }{
            float t=FIRST?0.f:fmaf(mom,nv.y-cv.y,nv.y);
            float u=fmaf(-beta,acc[oc*2+1],t); float au=fabsf(u)-lmb;
            u=(au>0.f)?copysignf(au,u):0.f; nw.y=act?u:nv.y; cw.y=act?nv.y:cv.y;
        }
        *reinterpret_cast<float2*>(c_out  + a) = cw;
        *reinterpret_cast<float2*>(nc_out + a) = nw;
    }
}

// kB1: dict_pred partials, CHANNEL-split. grid (8 rowblk, 32 cgroup, 4 b)
// = 1024 blocks of 256 thr (4 waves/SIMD). 16 rows/block, 8 px/thread,
// 2 ch per cgroup (18 fma per float4 load preserved).
__global__ __launch_bounds__(256,4) void kB1(const float* __restrict__ nc2,
    const float* __restrict__ atoms_f, float* __restrict__ part)
{
    int b=blockIdx.z, cg=blockIdx.y, pb=blockIdx.x;
    int t=threadIdx.x;
    int row = pb*16 + (t>>4);
    int cb  = (t&15)*8;
    const float* src = nc2 + (b*NCH + cg*2)*NPIX;
    float acc[8];
    #pragma unroll
    for (int k=0;k<8;++k) acc[k]=0.f;
    for (int c=0;c<2;++c){
        const float* chan = src + c*NPIX;
        const float* arow = atoms_f + (cg*2+c)*81;
        #pragma unroll 3
        for (int p=0;p<9;++p){
            int r=(row+4-p)&127;
            const float* rp_ = chan + (r<<7);
            float in16[16];
            #pragma unroll
            for (int k4=0;k4<4;++k4){
                int col=(cb-4+(k4<<2))&127;
                const float4 vv = *reinterpret_cast<const float4*>(rp_+col);
                in16[(k4<<2)+0]=vv.x; in16[(k4<<2)+1]=vv.y;
                in16[(k4<<2)+2]=vv.z; in16[(k4<<2)+3]=vv.w;
            }
            #pragma unroll
            for (int q=0;q<9;++q){
                float a = arow[p*9+q];
                #pragma unroll
                for (int k=0;k<8;++k) acc[k]=fmaf(in16[k+8-q], a, acc[k]);
            }
        }
    }
    float* dst = part + (cg*NB+b)*NPIX + (row<<7) + cb;
    #pragma unroll
    for (int k=0;k<8;++k) dst[k]=acc[k];
}

// kB2: image update + residual partials. 512 thr: halves split the 17-tap
// p-loop (9/8), merged via LDS; px work+writes by half 0. Sums 32 partials.
template<bool FIRST>
__global__ __launch_bounds__(512) void kB2(const float* __restrict__ img,
    const float* __restrict__ nimg, const float* __restrict__ y,
    const float* __restrict__ part, const float* __restrict__ pi,
    const float* __restrict__ scalars, const float* __restrict__ red_in,
    float* __restrict__ img_out, float* __restrict__ nimg_out,
    float* __restrict__ red_out, float mom)
{
    int b=blockIdx.y, rp=blockIdx.x;
    int tid=threadIdx.x;
    int half=tid>>8, lid=tid&255;
    int ty=lid>>7, w=lid&127;
    int h0=rp*2;
    __shared__ float sti[18*128];
    __shared__ float spi[289];
    __shared__ float sP2[256];
    __shared__ float rsd[4], rsi[4];
    __shared__ float sAct;
    if (FIRST){ if (tid==0) sAct=1.f; }
    else if (tid<64){
        float sd=red_in[(b<<7)+(tid<<1)], si=red_in[(b<<7)+(tid<<1)+1];
        #pragma unroll
        for (int off=32; off; off>>=1){ sd+=__shfl_down(sd,off); si+=__shfl_down(si,off); }
        if (tid==0) sAct = (sd > TOLV*TOLV*si) ? 1.f : 0.f;
    }
    const float* ib  = img  + b*NPIX;
    const float* nib = nimg + b*NPIX;
    for (int e=tid; e<2304; e+=512){
        int r=e>>7, cc=e&127;
        int idx=(((h0-8+r)&127)<<7)+cc;
        float nv=nib[idx], v=ib[idx];
        sti[e]=fmaf(mom, nv-v, nv);
    }
    for (int e=tid; e<289; e+=512) spi[e]=pi[e];
    __syncthreads();
    float sp=0.f;
    int pn = 9 - half;
    for (int pk=0; pk<pn; ++pk){
        int p = half*9 + pk;
        const float* srow = sti + (ty+p)*128;
        const float* pr = spi + p*17;
        #pragma unroll
        for (int q=0;q<17;++q) sp=fmaf(srow[(w+q-8)&127], pr[q], sp);
    }
    if (half==1) sP2[lid]=sp;
    __syncthreads();
    if (tid<256){
        sp += sP2[lid];
        int pix=((h0+ty)<<7)+w;
        float dp=0.f;
        #pragma unroll
        for (int g=0; g<NPG; ++g) dp += part[(g*NB+b)*NPIX + pix];
        float ti = sti[(ty+8)*128 + w];
        float beta=scalars[SC_BETA], L=scalars[SC_L];
        float yv=y[b*NPIX+pix];
        float upd = ti - (ti - yv + beta*(sp - dp))/L;
        bool act = (sAct!=0.f);
        float iv=ib[pix], niv=nib[pix];
        float i2 = act? niv : iv;
        float ni2 = act? upd : niv;
        img_out[b*NPIX+pix]=i2;
        nimg_out[b*NPIX+pix]=ni2;
        float d=i2-ni2;
        float sd=d*d, si=i2*i2;
        #pragma unroll
        for (int off=32; off; off>>=1){ sd+=__shfl_down(sd,off); si+=__shfl_down(si,off); }
        if ((tid&63)==0){ rsd[tid>>6]=sd; rsi[tid>>6]=si; }
    }
    __syncthreads();
    if (tid==0){
        float a=rsd[0]+rsd[1]+rsd[2]+rsd[3];
        float c2=rsi[0]+rsi[1]+rsi[2]+rsi[3];
        red_out[(b<<7)+(rp<<1)+0]=a;
        red_out[(b<<7)+(rp<<1)+1]=c2;
    }
}

// ---------------------------------------------------------------------------
extern "C" void kernel_launch(void* const* d_in, const int* in_sizes, int n_in,
                              void* d_out, int out_size, void* d_ws, size_t ws_size,
                              hipStream_t stream)
{
    const float* y        = (const float*)d_in[0];
    const float* atoms_p  = (const float*)d_in[1];
    const float* fatoms_p = (const float*)d_in[2];
    const float* beta_p   = (const float*)d_in[3];
    const float* lmbda_p  = (const float*)d_in[4];
    float* out = (float*)d_out;
    float* w = (float*)d_ws;

    size_t off=0;
    float* cb[2];  cb[0]=w+off;  off+=NCOEF; cb[1]=w+off;  off+=NCOEF;   // [b][ch][pix]
    float* ncb[2]; ncb[0]=w+off; off+=NCOEF; ncb[1]=w+off; off+=NCOEF;   // [b][ch][pix]
    float* ib[2];  ib[0]=w+off;  off+=NIMG;  ib[1]=w+off;  off+=NIMG;
    float* nib[2]; nib[0]=w+off; off+=NIMG;  nib[1]=w+off; off+=NIMG;
    float* part=w+off;    off+=NPG*NIMG;
    float* red[2]; red[0]=w+off; off+=512; red[1]=w+off; off+=512;
    float* gram=w+off;    off+=6561;
    float* pf=w+off;      off+=6561;
    float* PP=w+off;      off+=6561;
    float* pi=w+off;      off+=512;
    float* af_rn=w+off;   off+=5184;
    float* af_rnT=w+off;  off+=5184;
    float* Mmat=w+off;    off+=4096;
    float* MA=w+off;      off+=4096;
    float* MB=w+off;      off+=4096;
    float* atoms_f=w+off; off+=5184;
    float* atomsT=w+off;  off+=5184;
    float* Xmat=w+off;    off+=4096;
    float* scalars=w+off; off+=32;

    k_prep1<<<dim3(1),dim3(256),0,stream>>>(fatoms_p, beta_p, gram, pf, scalars);
    k_PP<<<dim3(26),dim3(256),0,stream>>>(pf, PP);
    k_impulse<<<dim3(1),dim3(320),0,stream>>>(PP, pi);
    k_dft<<<dim3(256),dim3(64),0,stream>>>(pi, scalars);
    k_atoms1<<<dim3(64),dim3(128),0,stream>>>(atoms_p, gram, af_rn, af_rnT);
    k_M<<<dim3(16),dim3(256),0,stream>>>(af_rn, af_rnT, Mmat);
    k_M2<<<dim3(16),dim3(256),0,stream>>>(Mmat, MA);   // M^2
    k_M2<<<dim3(16),dim3(256),0,stream>>>(MA, MB);     // M^4
    k_M2<<<dim3(16),dim3(256),0,stream>>>(MB, MA);     // M^8
    k_M2<<<dim3(16),dim3(256),0,stream>>>(MA, MB);     // M^16
    k_fin<<<dim3(1),dim3(256),0,stream>>>(Mmat, MB, af_rn, scalars, atoms_f, atomsT, Xmat);

    int p=0;
    for (int k=1; k<=20; ++k){
        float mom = (float)(k-1)/(float)(k+2);
        const float* rin = red[(k-1)&1];
        float* rout = red[k&1];
        const float* img_i  = (k==1)? y : ib[p];
        const float* nimg_i = (k==1)? y : nib[p];
        float* nc_t  = (k==20)? (out+NIMG) : ncb[p^1];
        float* nimg_t= (k==20)? out : nib[p^1];
        if (k==1){
            kA<true><<<dim3(128,4),dim3(512),0,stream>>>(cb[p],ncb[p],nimg_i,Xmat,atomsT,
                scalars,lmbda_p,rin, cb[p^1],nc_t,mom);
        } else {
            kA<false><<<dim3(128,4),dim3(512),0,stream>>>(cb[p],ncb[p],nimg_i,Xmat,atomsT,
                scalars,lmbda_p,rin, cb[p^1],nc_t,mom);
        }
        kB1<<<dim3(8,32,4),dim3(256),0,stream>>>(nc_t, atoms_f, part);
        if (k==1){
            kB2<true><<<dim3(64,4),dim3(512),0,stream>>>(img_i,nimg_i,y,part,pi,scalars,rin,
                ib[p^1],nimg_t,rout,mom);
        } else {
            kB2<false><<<dim3(64,4),dim3(512),0,stream>>>(img_i,nimg_i,y,part,pi,scalars,rin,
                ib[p^1],nimg_t,rout,mom);
        }
        p^=1;
    }
}

// Round 19
// 1188.297 us; speedup vs baseline: 1.6837x; 1.0533x over previous
//
#include <hip/hip_runtime.h>
#include <math.h>

// ---------------------------------------------------------------------------
// Dictionary_56212531970303 : FISTA dictionary forward on MI355X, fp32.
// Layout: coefficient state [b][ch][pix]. Per-INSTRUCTION contiguity rule
// (round-13): state loads/stores = 64 lanes x (float4|float2) contiguous.
// Setup: prep1, k_PP, k_impulse, k_dft, atoms1, k_M, k_M2 x4 (repeated
//        squaring; round-16), k_fin (8 power iters on M^16).
// Loop (20 iters):
//   kA  — 1-row strips, grid (128,4), 512 thr, 2 blocks/CU (4 waves/SIMD).
//         Round-18: phase-0 staging assignment == phase-3 output tile
//         (thread owns 8ch x 2px): nv/cv stay in 32 registers, phase 3 does
//         ZERO global re-reads (was 33.6 MB/iter through L2).
//   kB1 — 32 cgroups x 2ch, 1024 blocks = 4 waves/SIMD (round-17).
//   kB2 — 512-thr, 17-tap conv split across halves; sums 32 partials.
// Iter 1 templated FIRST; iter 20 writes nc/img directly into d_out.
// NOTE: every "if (tid<N)" with N>blockDim must be a grid-stride loop —
// round-2/3 regression (absmax 0.134).
// ---------------------------------------------------------------------------

#define NB 4
#define NCH 64
#define NPIX 16384              // 128*128
#define NPB (NCH*NPIX)
#define NCOEF (NB*NCH*NPIX)     // 4194304
#define NIMG  (NB*NPIX)         // 65536
#define NPG 32                  // partial channel-groups (2 ch each)
#define TOLV 1e-4f

#define SC_BETA 0
#define SC_L    1
#define SC_G    4
#define SC_G2   5
#define SC_LPK2 6

// ---------------------------------------------------------------------------
// prep1: one block. bjorck via 8x8 gram-iteration; writes gram + pf + scalars.
__global__ __launch_bounds__(256) void k_prep1(const float* __restrict__ fatoms,
    const float* __restrict__ beta_p,
    float* __restrict__ gram_g, float* __restrict__ pf_g,
    float* __restrict__ scalars)
{
    __shared__ float sW[648], sWf[648];
    __shared__ float sG[64], sP[64], sF[64], sT[64], sTmp[64];
    __shared__ float sGr[6561];
    __shared__ float rs[81];
    __shared__ float sSig;
    int tid = threadIdx.x;
    if (tid==0){ float b=beta_p[0]; scalars[SC_BETA]=(b>0.f)?b:0.f;
                 ((unsigned*)scalars)[SC_LPK2]=0u; }
    for (int e=tid; e<648; e+=256) sW[e]=fatoms[e];
    __syncthreads();
    if (tid<64){ int r=tid>>3, s=tid&7; float a=0.f;
        for (int k=0;k<81;++k) a=fmaf(sW[r*81+k],sW[s*81+k],a); sG[tid]=a; }
    __syncthreads();
    if (tid<64){
        int r8 = tid&7;
        float v = 1.f;
        for (int it=0; it<64; ++it){
            float nv=0.f;
            #pragma unroll
            for (int j=0;j<8;++j) nv = fmaf(sG[r8*8+j], __shfl(v,j,8), nv);
            float m = fabsf(nv);
            m = fmaxf(m, __shfl_xor(m,1,8));
            m = fmaxf(m, __shfl_xor(m,2,8));
            m = fmaxf(m, __shfl_xor(m,4,8));
            v = nv/m;
        }
        float wv=0.f;
        #pragma unroll
        for (int j=0;j<8;++j) wv = fmaf(sG[r8*8+j], __shfl(v,j,8), wv);
        float num=v*wv, den=v*v;
        num += __shfl_xor(num,1,8); num += __shfl_xor(num,2,8); num += __shfl_xor(num,4,8);
        den += __shfl_xor(den,1,8); den += __shfl_xor(den,2,8); den += __shfl_xor(den,4,8);
        if (tid==0) sSig = sqrtf(num/den);
    }
    __syncthreads();
    float inv_s = 1.f/sSig;
    for (int e=tid; e<648; e+=256) sW[e]*=inv_s;
    if (tid<64){ sG[tid]*=inv_s*inv_s; sP[tid]=((tid>>3)==(tid&7))?1.f:0.f; }
    __syncthreads();
    for (int it=0; it<15; ++it){
        if (tid<64) sF[tid] = (((tid>>3)==(tid&7))?1.5f:0.f) - 0.5f*sG[tid];
        __syncthreads();
        if (tid<64){ int r=tid>>3, c=tid&7; float ap=0.f, ag=0.f;
            #pragma unroll
            for (int k=0;k<8;++k){ float f=sF[r*8+k]; ap=fmaf(f,sP[k*8+c],ap); ag=fmaf(f,sG[k*8+c],ag); }
            sTmp[tid]=ap; sT[tid]=ag; }
        __syncthreads();
        if (tid<64){ int r=tid>>3, c=tid&7; float g2=0.f;
            #pragma unroll
            for (int k=0;k<8;++k) g2=fmaf(sT[r*8+k],sF[k*8+c],g2);
            sG[tid]=g2; sP[tid]=sTmp[tid]; }
        __syncthreads();
    }
    for (int e=tid; e<648; e+=256){ int r=e/81, j=e%81; float a=0.f;
        #pragma unroll
        for (int k=0;k<8;++k) a=fmaf(sP[r*8+k], sW[k*81+j], a);
        sWf[e]=a; }
    __syncthreads();
    for (int e=tid; e<6561; e+=256){ int i=e/81, j=e%81; float a=0.f;
        #pragma unroll
        for (int r=0;r<8;++r) a=fmaf(sWf[r*81+i],sWf[r*81+j],a);
        sGr[e]=a; gram_g[e]=a; }
    __syncthreads();
    if (tid<81){ float s=0.f; for (int k=0;k<81;++k) s+=sGr[tid*81+k]; rs[tid]=(1.f-s)/81.f; }
    __syncthreads();
    for (int e=tid; e<6561; e+=256){ int i=e/81, j=e%81;
        pf_g[e] = ((i==j)?1.f:0.f) - sGr[e] - rs[j]; }
}

// PP = pf^T pf (81x81), pf staged in LDS. 26 blocks x 256 thr.
__global__ __launch_bounds__(256) void k_PP(const float* __restrict__ pf, float* __restrict__ PP)
{
    __shared__ float spf[6561];
    for (int e=threadIdx.x; e<6561; e+=256) spf[e]=pf[e];
    __syncthreads();
    int e = blockIdx.x*256 + threadIdx.x;
    if (e>=6561) return;
    int al=e/81, be=e%81; float a=0.f;
    for (int c=0;c<81;++c) a=fmaf(spf[c*81+al], spf[c*81+be], a);
    PP[e]=a;
}

// proj_impulse (17x17) via PP lookups. One block, 320 thr (guard: t<289).
__global__ void k_impulse(const float* __restrict__ PP, float* __restrict__ pi)
{
    int t = threadIdx.x;
    if (t>=289) return;
    int h=t/17, w=t%17;
    float acc=0.f;
    for (int p=0;p<9;++p){
        int i2=(h+p-4+17)%17;
        if (i2<4||i2>12) continue;
        for (int q=0;q<9;++q){
            int j2=(w+q-4+17)%17;
            if (j2<4||j2>12) continue;
            int al=(12-i2)*9+(12-j2);
            int be=(8-p)*9+(8-q);
            acc += PP[al*81+be];
        }
    }
    pi[t]=acc;
}

// |FFT2(pi zero-padded to 128x128)|^2 max. 256 blocks x 64 thr (1 wave).
__global__ __launch_bounds__(64) void k_dft(const float* __restrict__ pi, float* __restrict__ scalars)
{
    __shared__ float spi[289], ct[128], st[128];
    int tid=threadIdx.x; int gid=blockIdx.x*64+tid;
    for (int e=tid; e<289; e+=64) spi[e]=pi[e];
    for (int e=tid; e<128; e+=64){ float ang=(float)e*(6.28318530717958647692f/128.f);
                  ct[e]=cosf(ang); st[e]=sinf(ang); }
    __syncthreads();
    int u=gid>>7, v=gid&127;
    float re=0.f, im=0.f;
    for (int i=0;i<17;++i){
        int ku=(u*i)&127;
        const float* prow=spi+i*17;
        for (int j=0;j<17;++j){
            int k=(ku+v*j)&127;
            float x=prow[j];
            re=fmaf(x,ct[k],re); im=fmaf(x,st[k],im);
        }
    }
    float m2=re*re+im*im;
    #pragma unroll
    for (int d=32; d; d>>=1) m2=fmaxf(m2, __shfl_down(m2,d));
    if (tid==0) atomicMax(((unsigned*)scalars)+SC_LPK2, __float_as_uint(m2));
}

// per-atom: center, subtract af@gram, row-normalize. Writes af_rn AND af_rnT.
__global__ __launch_bounds__(128) void k_atoms1(const float* __restrict__ atoms_in,
    const float* __restrict__ gram, float* __restrict__ af_rn, float* __restrict__ af_rnT)
{
    int a=blockIdx.x, tid=threadIdx.x;
    __shared__ float a0[81], a1[81], rbuf[128];
    float v = (tid<81)? atoms_in[a*81+tid] : 0.f;
    rbuf[tid]=v; __syncthreads();
    for (int off=64; off; off>>=1){ if (tid<off) rbuf[tid]+=rbuf[tid+off]; __syncthreads(); }
    float mean = rbuf[0]/81.f;
    __syncthreads();
    if (tid<81) a0[tid]=v-mean;
    __syncthreads();
    float w=0.f;
    if (tid<81){ float dot=0.f;
        for (int k=0;k<81;++k) dot=fmaf(a0[k], gram[k*81+tid], dot);
        w=a0[tid]-dot; a1[tid]=w; }
    rbuf[tid]=(tid<81)? w*w : 0.f;
    __syncthreads();
    for (int off=64; off; off>>=1){ if (tid<off) rbuf[tid]+=rbuf[tid+off]; __syncthreads(); }
    float inv = 1.f/sqrtf(rbuf[0]);
    if (tid<81){ float r=a1[tid]*inv; af_rn[a*81+tid]=r; af_rnT[tid*64+a]=r; }
}

// M = af_rn af_rn^T. 16 blocks x 256.
__global__ __launch_bounds__(256) void k_M(const float* __restrict__ af_rn,
    const float* __restrict__ af_rnT, float* __restrict__ M)
{
    int e=blockIdx.x*256+threadIdx.x;
    int i=e>>6, j=e&63;
    float a=0.f;
    for (int k=0;k<81;++k) a=fmaf(af_rn[i*81+k], af_rnT[(k<<6)+j], a);
    M[e]=a;
}

// OUT = IN*IN (symmetric). 16 blocks x 256. Chained for M^2..M^16.
__global__ __launch_bounds__(256) void k_M2(const float* __restrict__ IN,
    float* __restrict__ OUT)
{
    int e=blockIdx.x*256+threadIdx.x;
    int i=e>>6, j=e&63;
    float a=0.f;
    for (int k=0;k<64;++k) a=fmaf(IN[(i<<6)+k], IN[(k<<6)+j], a);
    OUT[e]=a;
}

// k_fin: one block. Power 8 iters on M^16, Rayleigh with M, finalize.
__global__ __launch_bounds__(256) void k_fin(const float* __restrict__ Mg,
    const float* __restrict__ MPg, const float* __restrict__ af_rn,
    float* __restrict__ scalars,
    float* __restrict__ atoms_f, float* __restrict__ atomsT, float* __restrict__ Xmat)
{
    __shared__ float sM[4096];
    __shared__ float sGc[2];
    int tid=threadIdx.x;
    for (int e=tid; e<4096; e+=256) sM[e]=Mg[e];
    __syncthreads();
    if (tid<64){
        float m[64];
        const float4* mp = reinterpret_cast<const float4*>(MPg + (tid<<6));
        #pragma unroll
        for (int j4=0;j4<16;++j4){
            float4 v4=mp[j4];
            m[j4*4+0]=v4.x; m[j4*4+1]=v4.y; m[j4*4+2]=v4.z; m[j4*4+3]=v4.w;
        }
        float v = 1.0f + 0.01f*(float)tid;
        for (int it=0; it<8; ++it){
            float a0=0.f,a1=0.f,a2=0.f,a3=0.f;
            #pragma unroll
            for (int j=0;j<64;j+=4){
                a0=fmaf(m[j+0], __shfl(v,j+0), a0);
                a1=fmaf(m[j+1], __shfl(v,j+1), a1);
                a2=fmaf(m[j+2], __shfl(v,j+2), a2);
                a3=fmaf(m[j+3], __shfl(v,j+3), a3);
            }
            float nv=(a0+a1)+(a2+a3);
            float mx=fabsf(nv);
            #pragma unroll
            for (int d=1; d<64; d<<=1) mx=fmaxf(mx, __shfl_xor(mx,d));
            v=nv/mx;
        }
        float w0=0.f,w1=0.f,w2=0.f,w3=0.f;
        #pragma unroll
        for (int j=0;j<64;j+=4){
            w0=fmaf(sM[(tid<<6)+j+0], __shfl(v,j+0), w0);
            w1=fmaf(sM[(tid<<6)+j+1], __shfl(v,j+1), w1);
            w2=fmaf(sM[(tid<<6)+j+2], __shfl(v,j+2), w2);
            w3=fmaf(sM[(tid<<6)+j+3], __shfl(v,j+3), w3);
        }
        float wv=(w0+w1)+(w2+w3);
        float num=v*wv, den=v*v;
        #pragma unroll
        for (int d=1; d<64; d<<=1){ num+=__shfl_xor(num,d); den+=__shfl_xor(den,d); }
        if (tid==0){
            float sig = sqrtf(num/den);
            float b = scalars[SC_BETA];
            float s = sqrtf(0.99f/fmaxf(b,0.1f));
            float g = s/sig;
            scalars[SC_G]=g; scalars[SC_G2]=g*g;
            float lpk = sqrtf(__uint_as_float(((unsigned*)scalars)[SC_LPK2]));
            scalars[SC_L] = 1.01f*b*lpk;
            sGc[0]=g; sGc[1]=g*g;
        }
    }
    __syncthreads();
    float g=sGc[0], g2=sGc[1];
    for (int idx=tid; idx<5184; idx+=256){
        int a=idx/81, pq=idx-a*81;
        float v=g*af_rn[idx];
        atoms_f[idx]=v;
        atomsT[pq*64+a]=v;
    }
    for (int e=tid; e<4096; e+=256) Xmat[e]=g2*sM[e];
}

// ---------------------------------------------------------------------------
// kA: coefficient update, [b][ch][pix]. 1-row strips: grid (128,4), 512 thr
// (2 blocks/CU = 4 waves/SIMD via launch_bounds(512,4)). Thread owns an
// [8ch x 2px] tile: stages its OWN c/nc (512B-contiguous float2 per instr),
// keeps nv/cv in registers -> phase 3 has no global re-reads (round-18).
template<bool FIRST>
__global__ __launch_bounds__(512,4) void kA(const float* __restrict__ c_in,
    const float* __restrict__ nc_in, const float* __restrict__ nimg,
    const float* __restrict__ Xmat, const float* __restrict__ atomsT,
    const float* __restrict__ scalars, const float* __restrict__ lmbda_p,
    const float* __restrict__ red_in,
    float* __restrict__ c_out, float* __restrict__ nc_out, float mom)
{
    int b=blockIdx.y, h0=blockIdx.x;       // one image row per block
    int tid=threadIdx.x;
    int wv = __builtin_amdgcn_readfirstlane(tid>>6);   // wave id 0..7
    int lane = tid&63;
    int co = wv*8;
    int px = lane*2;                        // 0..126, even
    __shared__ float sTemp[64*128];         // 32 KB
    __shared__ float simg[9*128];
    __shared__ float sAct;
    if (FIRST){ if (tid==0) sAct=1.f; }
    else if (tid<64){
        float sd=red_in[(b<<7)+(tid<<1)], si=red_in[(b<<7)+(tid<<1)+1];
        #pragma unroll
        for (int off=32; off; off>>=1){ sd+=__shfl_down(sd,off); si+=__shfl_down(si,off); }
        if (tid==0) sAct = (sd > TOLV*TOLV*si) ? 1.f : 0.f;
    }
    for (int e=tid; e<1152; e+=512)
        simg[e]=nimg[b*NPIX + (((h0-4+(e>>7))&127)<<7) + (e&127)];
    size_t sbase = (size_t)b*NPB + (h0<<7);
    float2 nv8[8], cv8[8];
    if (!FIRST){
        // stage own tile: 8 ch x 2 px; each instr = 64 lanes x float2 = 512B
        #pragma unroll
        for (int oc=0;oc<8;++oc){
            size_t a = sbase + (size_t)(co+oc)*NPIX + px;
            cv8[oc]=*reinterpret_cast<const float2*>(c_in + a);
            nv8[oc]=*reinterpret_cast<const float2*>(nc_in + a);
            float2 t;
            t.x=fmaf(mom,nv8[oc].x-cv8[oc].x,nv8[oc].x);
            t.y=fmaf(mom,nv8[oc].y-cv8[oc].y,nv8[oc].y);
            *reinterpret_cast<float2*>(sTemp + (co+oc)*128 + px) = t;
        }
    }
    __syncthreads();
    const float* Xo = Xmat + co;
    const float* Ao = atomsT + co;
    float acc[16];                          // [oc][2px]
    #pragma unroll
    for (int i=0;i<16;++i) acc[i]=0.f;
    if (!FIRST){
        for (int c=0;c<64;++c){
            float2 t=*reinterpret_cast<const float2*>(sTemp + c*128 + px);
            const float* Xr = Xo + (c<<6);
            #pragma unroll
            for (int oc=0;oc<8;++oc){
                float x=Xr[oc];
                acc[oc*2+0]=fmaf(x,t.x,acc[oc*2+0]);
                acc[oc*2+1]=fmaf(x,t.y,acc[oc*2+1]);
            }
        }
    }
    for (int p=0;p<9;++p){
        const float* srow = simg + p*128;
        float in10[10];
        #pragma unroll
        for (int j=0;j<10;++j) in10[j]=srow[(px-4+j)&127];
        #pragma unroll 3
        for (int q=0;q<9;++q){
            const float* Ar = Ao + ((p*9+q)<<6);
            #pragma unroll
            for (int oc=0;oc<8;++oc){
                float a=Ar[oc];
                acc[oc*2+0]=fmaf(a,-in10[q+0],acc[oc*2+0]);
                acc[oc*2+1]=fmaf(a,-in10[q+1],acc[oc*2+1]);
            }
        }
    }
    float beta=scalars[SC_BETA], lmb=lmbda_p[0];
    bool act = (sAct!=0.f);
    #pragma unroll
    for (int oc=0;oc<8;++oc){
        size_t a = sbase + (size_t)(co+oc)*NPIX + px;
        float2 nv, cv;
        if (FIRST){ nv=make_float2(0.f,0.f); cv=nv; }
        else { nv=nv8[oc]; cv=cv8[oc]; }
        float2 nw, cw;
        {
            float t=FIRST?0.f:fmaf(mom,nv.x-cv.x,nv.x);
            float u=fmaf(-beta,acc[oc*2+0],t); float au=fabsf(u)-lmb;
            u=(au>0.f)?copysignf(au,u):0.f; nw.x=act?u:nv.x; cw.x=act?nv.x:cv.x;
        }{
            float t=FIRST?0.f:fmaf(mom,nv.y-cv.y,nv.y);
            float u=fmaf(-beta,acc[oc*2+1],t); float au=fabsf(u)-lmb;
            u=(au>0.f)?copysignf(au,u):0.f; nw.y=act?u:nv.y; cw.y=act?nv.y:cv.y;
        }
        *reinterpret_cast<float2*>(c_out  + a) = cw;
        *reinterpret_cast<float2*>(nc_out + a) = nw;
    }
}

// kB1: dict_pred partials, CHANNEL-split. grid (8 rowblk, 32 cgroup, 4 b)
// = 1024 blocks of 256 thr (4 waves/SIMD). 16 rows/block, 8 px/thread,
// 2 ch per cgroup (18 fma per float4 load preserved).
__global__ __launch_bounds__(256,4) void kB1(const float* __restrict__ nc2,
    const float* __restrict__ atoms_f, float* __restrict__ part)
{
    int b=blockIdx.z, cg=blockIdx.y, pb=blockIdx.x;
    int t=threadIdx.x;
    int row = pb*16 + (t>>4);
    int cb  = (t&15)*8;
    const float* src = nc2 + (b*NCH + cg*2)*NPIX;
    float acc[8];
    #pragma unroll
    for (int k=0;k<8;++k) acc[k]=0.f;
    for (int c=0;c<2;++c){
        const float* chan = src + c*NPIX;
        const float* arow = atoms_f + (cg*2+c)*81;
        #pragma unroll 3
        for (int p=0;p<9;++p){
            int r=(row+4-p)&127;
            const float* rp_ = chan + (r<<7);
            float in16[16];
            #pragma unroll
            for (int k4=0;k4<4;++k4){
                int col=(cb-4+(k4<<2))&127;
                const float4 vv = *reinterpret_cast<const float4*>(rp_+col);
                in16[(k4<<2)+0]=vv.x; in16[(k4<<2)+1]=vv.y;
                in16[(k4<<2)+2]=vv.z; in16[(k4<<2)+3]=vv.w;
            }
            #pragma unroll
            for (int q=0;q<9;++q){
                float a = arow[p*9+q];
                #pragma unroll
                for (int k=0;k<8;++k) acc[k]=fmaf(in16[k+8-q], a, acc[k]);
            }
        }
    }
    float* dst = part + (cg*NB+b)*NPIX + (row<<7) + cb;
    #pragma unroll
    for (int k=0;k<8;++k) dst[k]=acc[k];
}

// kB2: image update + residual partials. 512 thr: halves split the 17-tap
// p-loop (9/8), merged via LDS; px work+writes by half 0. Sums 32 partials.
template<bool FIRST>
__global__ __launch_bounds__(512) void kB2(const float* __restrict__ img,
    const float* __restrict__ nimg, const float* __restrict__ y,
    const float* __restrict__ part, const float* __restrict__ pi,
    const float* __restrict__ scalars, const float* __restrict__ red_in,
    float* __restrict__ img_out, float* __restrict__ nimg_out,
    float* __restrict__ red_out, float mom)
{
    int b=blockIdx.y, rp=blockIdx.x;
    int tid=threadIdx.x;
    int half=tid>>8, lid=tid&255;
    int ty=lid>>7, w=lid&127;
    int h0=rp*2;
    __shared__ float sti[18*128];
    __shared__ float spi[289];
    __shared__ float sP2[256];
    __shared__ float rsd[4], rsi[4];
    __shared__ float sAct;
    if (FIRST){ if (tid==0) sAct=1.f; }
    else if (tid<64){
        float sd=red_in[(b<<7)+(tid<<1)], si=red_in[(b<<7)+(tid<<1)+1];
        #pragma unroll
        for (int off=32; off; off>>=1){ sd+=__shfl_down(sd,off); si+=__shfl_down(si,off); }
        if (tid==0) sAct = (sd > TOLV*TOLV*si) ? 1.f : 0.f;
    }
    const float* ib  = img  + b*NPIX;
    const float* nib = nimg + b*NPIX;
    for (int e=tid; e<2304; e+=512){
        int r=e>>7, cc=e&127;
        int idx=(((h0-8+r)&127)<<7)+cc;
        float nv=nib[idx], v=ib[idx];
        sti[e]=fmaf(mom, nv-v, nv);
    }
    for (int e=tid; e<289; e+=512) spi[e]=pi[e];
    __syncthreads();
    float sp=0.f;
    int pn = 9 - half;
    for (int pk=0; pk<pn; ++pk){
        int p = half*9 + pk;
        const float* srow = sti + (ty+p)*128;
        const float* pr = spi + p*17;
        #pragma unroll
        for (int q=0;q<17;++q) sp=fmaf(srow[(w+q-8)&127], pr[q], sp);
    }
    if (half==1) sP2[lid]=sp;
    __syncthreads();
    if (tid<256){
        sp += sP2[lid];
        int pix=((h0+ty)<<7)+w;
        float dp=0.f;
        #pragma unroll
        for (int g=0; g<NPG; ++g) dp += part[(g*NB+b)*NPIX + pix];
        float ti = sti[(ty+8)*128 + w];
        float beta=scalars[SC_BETA], L=scalars[SC_L];
        float yv=y[b*NPIX+pix];
        float upd = ti - (ti - yv + beta*(sp - dp))/L;
        bool act = (sAct!=0.f);
        float iv=ib[pix], niv=nib[pix];
        float i2 = act? niv : iv;
        float ni2 = act? upd : niv;
        img_out[b*NPIX+pix]=i2;
        nimg_out[b*NPIX+pix]=ni2;
        float d=i2-ni2;
        float sd=d*d, si=i2*i2;
        #pragma unroll
        for (int off=32; off; off>>=1){ sd+=__shfl_down(sd,off); si+=__shfl_down(si,off); }
        if ((tid&63)==0){ rsd[tid>>6]=sd; rsi[tid>>6]=si; }
    }
    __syncthreads();
    if (tid==0){
        float a=rsd[0]+rsd[1]+rsd[2]+rsd[3];
        float c2=rsi[0]+rsi[1]+rsi[2]+rsi[3];
        red_out[(b<<7)+(rp<<1)+0]=a;
        red_out[(b<<7)+(rp<<1)+1]=c2;
    }
}

// ---------------------------------------------------------------------------
extern "C" void kernel_launch(void* const* d_in, const int* in_sizes, int n_in,
                              void* d_out, int out_size, void* d_ws, size_t ws_size,
                              hipStream_t stream)
{
    const float* y        = (const float*)d_in[0];
    const float* atoms_p  = (const float*)d_in[1];
    const float* fatoms_p = (const float*)d_in[2];
    const float* beta_p   = (const float*)d_in[3];
    const float* lmbda_p  = (const float*)d_in[4];
    float* out = (float*)d_out;
    float* w = (float*)d_ws;

    size_t off=0;
    float* cb[2];  cb[0]=w+off;  off+=NCOEF; cb[1]=w+off;  off+=NCOEF;   // [b][ch][pix]
    float* ncb[2]; ncb[0]=w+off; off+=NCOEF; ncb[1]=w+off; off+=NCOEF;   // [b][ch][pix]
    float* ib[2];  ib[0]=w+off;  off+=NIMG;  ib[1]=w+off;  off+=NIMG;
    float* nib[2]; nib[0]=w+off; off+=NIMG;  nib[1]=w+off; off+=NIMG;
    float* part=w+off;    off+=NPG*NIMG;
    float* red[2]; red[0]=w+off; off+=512; red[1]=w+off; off+=512;
    float* gram=w+off;    off+=6561;
    float* pf=w+off;      off+=6561;
    float* PP=w+off;      off+=6561;
    float* pi=w+off;      off+=512;
    float* af_rn=w+off;   off+=5184;
    float* af_rnT=w+off;  off+=5184;
    float* Mmat=w+off;    off+=4096;
    float* MA=w+off;      off+=4096;
    float* MB=w+off;      off+=4096;
    float* atoms_f=w+off; off+=5184;
    float* atomsT=w+off;  off+=5184;
    float* Xmat=w+off;    off+=4096;
    float* scalars=w+off; off+=32;

    k_prep1<<<dim3(1),dim3(256),0,stream>>>(fatoms_p, beta_p, gram, pf, scalars);
    k_PP<<<dim3(26),dim3(256),0,stream>>>(pf, PP);
    k_impulse<<<dim3(1),dim3(320),0,stream>>>(PP, pi);
    k_dft<<<dim3(256),dim3(64),0,stream>>>(pi, scalars);
    k_atoms1<<<dim3(64),dim3(128),0,stream>>>(atoms_p, gram, af_rn, af_rnT);
    k_M<<<dim3(16),dim3(256),0,stream>>>(af_rn, af_rnT, Mmat);
    k_M2<<<dim3(16),dim3(256),0,stream>>>(Mmat, MA);   // M^2
    k_M2<<<dim3(16),dim3(256),0,stream>>>(MA, MB);     // M^4
    k_M2<<<dim3(16),dim3(256),0,stream>>>(MB, MA);     // M^8
    k_M2<<<dim3(16),dim3(256),0,stream>>>(MA, MB);     // M^16
    k_fin<<<dim3(1),dim3(256),0,stream>>>(Mmat, MB, af_rn, scalars, atoms_f, atomsT, Xmat);

    int p=0;
    for (int k=1; k<=20; ++k){
        float mom = (float)(k-1)/(float)(k+2);
        const float* rin = red[(k-1)&1];
        float* rout = red[k&1];
        const float* img_i  = (k==1)? y : ib[p];
        const float* nimg_i = (k==1)? y : nib[p];
        float* nc_t  = (k==20)? (out+NIMG) : ncb[p^1];
        float* nimg_t= (k==20)? out : nib[p^1];
        if (k==1){
            kA<true><<<dim3(128,4),dim3(512),0,stream>>>(cb[p],ncb[p],nimg_i,Xmat,atomsT,
                scalars,lmbda_p,rin, cb[p^1],nc_t,mom);
        } else {
            kA<false><<<dim3(128,4),dim3(512),0,stream>>>(cb[p],ncb[p],nimg_i,Xmat,atomsT,
                scalars,lmbda_p,rin, cb[p^1],nc_t,mom);
        }
        kB1<<<dim3(8,32,4),dim3(256),0,stream>>>(nc_t, atoms_f, part);
        if (k==1){
            kB2<true><<<dim3(64,4),dim3(512),0,stream>>>(img_i,nimg_i,y,part,pi,scalars,rin,
                ib[p^1],nimg_t,rout,mom);
        } else {
            kB2<false><<<dim3(64,4),dim3(512),0,stream>>>(img_i,nimg_i,y,part,pi,scalars,rin,
                ib[p^1],nimg_t,rout,mom);
        }
        p^=1;
    }
}

// Round 20
// 1161.540 us; speedup vs baseline: 1.7225x; 1.0230x over previous
//
#include <hip/hip_runtime.h>
#include <math.h>

// ---------------------------------------------------------------------------
// Dictionary_56212531970303 : FISTA dictionary forward on MI355X, fp32.
// Layout: coefficient state [b][ch][pix]. Per-INSTRUCTION contiguity rule
// (round-13): state loads/stores = 64 lanes x (float4|float2) contiguous.
// Round-19: c-buffer POINTER ROTATION — c_{k+1} buffer IS iter k's nc_in
// buffer (3-buffer cycle). Device writes c only in the rare !act case
// (fix-up of C_k values into the rotating buffer); act==1 writes nothing
// (values already there). Kills 16.8 MB/iter of pure-copy stores.
// Setup: prep1, k_PP, k_impulse, k_dft, atoms1, k_M, k_M2 x4, k_fin.
// Loop: kA (1-row strips, reg-tile, LDS temp), kB1 (32 cgroups x 2ch),
//       kB2 (512-thr split 17-tap conv).
// NOTE: every "if (tid<N)" with N>blockDim must be a grid-stride loop —
// round-2/3 regression (absmax 0.134).
// ---------------------------------------------------------------------------

#define NB 4
#define NCH 64
#define NPIX 16384              // 128*128
#define NPB (NCH*NPIX)
#define NCOEF (NB*NCH*NPIX)     // 4194304
#define NIMG  (NB*NPIX)         // 65536
#define NPG 32                  // partial channel-groups (2 ch each)
#define TOLV 1e-4f

#define SC_BETA 0
#define SC_L    1
#define SC_G    4
#define SC_G2   5
#define SC_LPK2 6

// ---------------------------------------------------------------------------
// prep1: one block. bjorck via 8x8 gram-iteration; writes gram + pf + scalars.
__global__ __launch_bounds__(256) void k_prep1(const float* __restrict__ fatoms,
    const float* __restrict__ beta_p,
    float* __restrict__ gram_g, float* __restrict__ pf_g,
    float* __restrict__ scalars)
{
    __shared__ float sW[648], sWf[648];
    __shared__ float sG[64], sP[64], sF[64], sT[64], sTmp[64];
    __shared__ float sGr[6561];
    __shared__ float rs[81];
    __shared__ float sSig;
    int tid = threadIdx.x;
    if (tid==0){ float b=beta_p[0]; scalars[SC_BETA]=(b>0.f)?b:0.f;
                 ((unsigned*)scalars)[SC_LPK2]=0u; }
    for (int e=tid; e<648; e+=256) sW[e]=fatoms[e];
    __syncthreads();
    if (tid<64){ int r=tid>>3, s=tid&7; float a=0.f;
        for (int k=0;k<81;++k) a=fmaf(sW[r*81+k],sW[s*81+k],a); sG[tid]=a; }
    __syncthreads();
    if (tid<64){
        int r8 = tid&7;
        float v = 1.f;
        for (int it=0; it<64; ++it){
            float nv=0.f;
            #pragma unroll
            for (int j=0;j<8;++j) nv = fmaf(sG[r8*8+j], __shfl(v,j,8), nv);
            float m = fabsf(nv);
            m = fmaxf(m, __shfl_xor(m,1,8));
            m = fmaxf(m, __shfl_xor(m,2,8));
            m = fmaxf(m, __shfl_xor(m,4,8));
            v = nv/m;
        }
        float wv=0.f;
        #pragma unroll
        for (int j=0;j<8;++j) wv = fmaf(sG[r8*8+j], __shfl(v,j,8), wv);
        float num=v*wv, den=v*v;
        num += __shfl_xor(num,1,8); num += __shfl_xor(num,2,8); num += __shfl_xor(num,4,8);
        den += __shfl_xor(den,1,8); den += __shfl_xor(den,2,8); den += __shfl_xor(den,4,8);
        if (tid==0) sSig = sqrtf(num/den);
    }
    __syncthreads();
    float inv_s = 1.f/sSig;
    for (int e=tid; e<648; e+=256) sW[e]*=inv_s;
    if (tid<64){ sG[tid]*=inv_s*inv_s; sP[tid]=((tid>>3)==(tid&7))?1.f:0.f; }
    __syncthreads();
    for (int it=0; it<15; ++it){
        if (tid<64) sF[tid] = (((tid>>3)==(tid&7))?1.5f:0.f) - 0.5f*sG[tid];
        __syncthreads();
        if (tid<64){ int r=tid>>3, c=tid&7; float ap=0.f, ag=0.f;
            #pragma unroll
            for (int k=0;k<8;++k){ float f=sF[r*8+k]; ap=fmaf(f,sP[k*8+c],ap); ag=fmaf(f,sG[k*8+c],ag); }
            sTmp[tid]=ap; sT[tid]=ag; }
        __syncthreads();
        if (tid<64){ int r=tid>>3, c=tid&7; float g2=0.f;
            #pragma unroll
            for (int k=0;k<8;++k) g2=fmaf(sT[r*8+k],sF[k*8+c],g2);
            sG[tid]=g2; sP[tid]=sTmp[tid]; }
        __syncthreads();
    }
    for (int e=tid; e<648; e+=256){ int r=e/81, j=e%81; float a=0.f;
        #pragma unroll
        for (int k=0;k<8;++k) a=fmaf(sP[r*8+k], sW[k*81+j], a);
        sWf[e]=a; }
    __syncthreads();
    for (int e=tid; e<6561; e+=256){ int i=e/81, j=e%81; float a=0.f;
        #pragma unroll
        for (int r=0;r<8;++r) a=fmaf(sWf[r*81+i],sWf[r*81+j],a);
        sGr[e]=a; gram_g[e]=a; }
    __syncthreads();
    if (tid<81){ float s=0.f; for (int k=0;k<81;++k) s+=sGr[tid*81+k]; rs[tid]=(1.f-s)/81.f; }
    __syncthreads();
    for (int e=tid; e<6561; e+=256){ int i=e/81, j=e%81;
        pf_g[e] = ((i==j)?1.f:0.f) - sGr[e] - rs[j]; }
}

// PP = pf^T pf (81x81), pf staged in LDS. 26 blocks x 256 thr.
__global__ __launch_bounds__(256) void k_PP(const float* __restrict__ pf, float* __restrict__ PP)
{
    __shared__ float spf[6561];
    for (int e=threadIdx.x; e<6561; e+=256) spf[e]=pf[e];
    __syncthreads();
    int e = blockIdx.x*256 + threadIdx.x;
    if (e>=6561) return;
    int al=e/81, be=e%81; float a=0.f;
    for (int c=0;c<81;++c) a=fmaf(spf[c*81+al], spf[c*81+be], a);
    PP[e]=a;
}

// proj_impulse (17x17) via PP lookups. One block, 320 thr (guard: t<289).
__global__ void k_impulse(const float* __restrict__ PP, float* __restrict__ pi)
{
    int t = threadIdx.x;
    if (t>=289) return;
    int h=t/17, w=t%17;
    float acc=0.f;
    for (int p=0;p<9;++p){
        int i2=(h+p-4+17)%17;
        if (i2<4||i2>12) continue;
        for (int q=0;q<9;++q){
            int j2=(w+q-4+17)%17;
            if (j2<4||j2>12) continue;
            int al=(12-i2)*9+(12-j2);
            int be=(8-p)*9+(8-q);
            acc += PP[al*81+be];
        }
    }
    pi[t]=acc;
}

// |FFT2(pi zero-padded to 128x128)|^2 max. 256 blocks x 64 thr (1 wave).
__global__ __launch_bounds__(64) void k_dft(const float* __restrict__ pi, float* __restrict__ scalars)
{
    __shared__ float spi[289], ct[128], st[128];
    int tid=threadIdx.x; int gid=blockIdx.x*64+tid;
    for (int e=tid; e<289; e+=64) spi[e]=pi[e];
    for (int e=tid; e<128; e+=64){ float ang=(float)e*(6.28318530717958647692f/128.f);
                  ct[e]=cosf(ang); st[e]=sinf(ang); }
    __syncthreads();
    int u=gid>>7, v=gid&127;
    float re=0.f, im=0.f;
    for (int i=0;i<17;++i){
        int ku=(u*i)&127;
        const float* prow=spi+i*17;
        for (int j=0;j<17;++j){
            int k=(ku+v*j)&127;
            float x=prow[j];
            re=fmaf(x,ct[k],re); im=fmaf(x,st[k],im);
        }
    }
    float m2=re*re+im*im;
    #pragma unroll
    for (int d=32; d; d>>=1) m2=fmaxf(m2, __shfl_down(m2,d));
    if (tid==0) atomicMax(((unsigned*)scalars)+SC_LPK2, __float_as_uint(m2));
}

// per-atom: center, subtract af@gram, row-normalize. Writes af_rn AND af_rnT.
__global__ __launch_bounds__(128) void k_atoms1(const float* __restrict__ atoms_in,
    const float* __restrict__ gram, float* __restrict__ af_rn, float* __restrict__ af_rnT)
{
    int a=blockIdx.x, tid=threadIdx.x;
    __shared__ float a0[81], a1[81], rbuf[128];
    float v = (tid<81)? atoms_in[a*81+tid] : 0.f;
    rbuf[tid]=v; __syncthreads();
    for (int off=64; off; off>>=1){ if (tid<off) rbuf[tid]+=rbuf[tid+off]; __syncthreads(); }
    float mean = rbuf[0]/81.f;
    __syncthreads();
    if (tid<81) a0[tid]=v-mean;
    __syncthreads();
    float w=0.f;
    if (tid<81){ float dot=0.f;
        for (int k=0;k<81;++k) dot=fmaf(a0[k], gram[k*81+tid], dot);
        w=a0[tid]-dot; a1[tid]=w; }
    rbuf[tid]=(tid<81)? w*w : 0.f;
    __syncthreads();
    for (int off=64; off; off>>=1){ if (tid<off) rbuf[tid]+=rbuf[tid+off]; __syncthreads(); }
    float inv = 1.f/sqrtf(rbuf[0]);
    if (tid<81){ float r=a1[tid]*inv; af_rn[a*81+tid]=r; af_rnT[tid*64+a]=r; }
}

// M = af_rn af_rn^T. 16 blocks x 256.
__global__ __launch_bounds__(256) void k_M(const float* __restrict__ af_rn,
    const float* __restrict__ af_rnT, float* __restrict__ M)
{
    int e=blockIdx.x*256+threadIdx.x;
    int i=e>>6, j=e&63;
    float a=0.f;
    for (int k=0;k<81;++k) a=fmaf(af_rn[i*81+k], af_rnT[(k<<6)+j], a);
    M[e]=a;
}

// OUT = IN*IN (symmetric). 16 blocks x 256. Chained for M^2..M^16.
__global__ __launch_bounds__(256) void k_M2(const float* __restrict__ IN,
    float* __restrict__ OUT)
{
    int e=blockIdx.x*256+threadIdx.x;
    int i=e>>6, j=e&63;
    float a=0.f;
    for (int k=0;k<64;++k) a=fmaf(IN[(i<<6)+k], IN[(k<<6)+j], a);
    OUT[e]=a;
}

// k_fin: one block. Power 8 iters on M^16, Rayleigh with M, finalize.
__global__ __launch_bounds__(256) void k_fin(const float* __restrict__ Mg,
    const float* __restrict__ MPg, const float* __restrict__ af_rn,
    float* __restrict__ scalars,
    float* __restrict__ atoms_f, float* __restrict__ atomsT, float* __restrict__ Xmat)
{
    __shared__ float sM[4096];
    __shared__ float sGc[2];
    int tid=threadIdx.x;
    for (int e=tid; e<4096; e+=256) sM[e]=Mg[e];
    __syncthreads();
    if (tid<64){
        float m[64];
        const float4* mp = reinterpret_cast<const float4*>(MPg + (tid<<6));
        #pragma unroll
        for (int j4=0;j4<16;++j4){
            float4 v4=mp[j4];
            m[j4*4+0]=v4.x; m[j4*4+1]=v4.y; m[j4*4+2]=v4.z; m[j4*4+3]=v4.w;
        }
        float v = 1.0f + 0.01f*(float)tid;
        for (int it=0; it<8; ++it){
            float a0=0.f,a1=0.f,a2=0.f,a3=0.f;
            #pragma unroll
            for (int j=0;j<64;j+=4){
                a0=fmaf(m[j+0], __shfl(v,j+0), a0);
                a1=fmaf(m[j+1], __shfl(v,j+1), a1);
                a2=fmaf(m[j+2], __shfl(v,j+2), a2);
                a3=fmaf(m[j+3], __shfl(v,j+3), a3);
            }
            float nv=(a0+a1)+(a2+a3);
            float mx=fabsf(nv);
            #pragma unroll
            for (int d=1; d<64; d<<=1) mx=fmaxf(mx, __shfl_xor(mx,d));
            v=nv/mx;
        }
        float w0=0.f,w1=0.f,w2=0.f,w3=0.f;
        #pragma unroll
        for (int j=0;j<64;j+=4){
            w0=fmaf(sM[(tid<<6)+j+0], __shfl(v,j+0), w0);
            w1=fmaf(sM[(tid<<6)+j+1], __shfl(v,j+1), w1);
            w2=fmaf(sM[(tid<<6)+j+2], __shfl(v,j+2), w2);
            w3=fmaf(sM[(tid<<6)+j+3], __shfl(v,j+3), w3);
        }
        float wv=(w0+w1)+(w2+w3);
        float num=v*wv, den=v*v;
        #pragma unroll
        for (int d=1; d<64; d<<=1){ num+=__shfl_xor(num,d); den+=__shfl_xor(den,d); }
        if (tid==0){
            float sig = sqrtf(num/den);
            float b = scalars[SC_BETA];
            float s = sqrtf(0.99f/fmaxf(b,0.1f));
            float g = s/sig;
            scalars[SC_G]=g; scalars[SC_G2]=g*g;
            float lpk = sqrtf(__uint_as_float(((unsigned*)scalars)[SC_LPK2]));
            scalars[SC_L] = 1.01f*b*lpk;
            sGc[0]=g; sGc[1]=g*g;
        }
    }
    __syncthreads();
    float g=sGc[0], g2=sGc[1];
    for (int idx=tid; idx<5184; idx+=256){
        int a=idx/81, pq=idx-a*81;
        float v=g*af_rn[idx];
        atoms_f[idx]=v;
        atomsT[pq*64+a]=v;
    }
    for (int e=tid; e<4096; e+=256) Xmat[e]=g2*sM[e];
}

// ---------------------------------------------------------------------------
// kA: coefficient update, [b][ch][pix]. 1-row strips: grid (128,4), 512 thr
// (4 waves/SIMD). Thread owns [8ch x 2px]; stages own c/nc into regs + LDS.
// c-buffer ROTATION (round-19): nc_in buffer becomes next iter's c buffer;
// only the !act case writes fix-up (C_k values) into it. FIRST writes zeros
// (c_2 = coeffs0 = 0; rotation buffer was uninitialized).
template<bool FIRST>
__global__ __launch_bounds__(512,4) void kA(const float* __restrict__ c_in,
    float* __restrict__ nc_in, const float* __restrict__ nimg,
    const float* __restrict__ Xmat, const float* __restrict__ atomsT,
    const float* __restrict__ scalars, const float* __restrict__ lmbda_p,
    const float* __restrict__ red_in,
    float* __restrict__ nc_out, float mom)
{
    int b=blockIdx.y, h0=blockIdx.x;       // one image row per block
    int tid=threadIdx.x;
    int wv = __builtin_amdgcn_readfirstlane(tid>>6);   // wave id 0..7
    int lane = tid&63;
    int co = wv*8;
    int px = lane*2;                        // 0..126, even
    __shared__ float sTemp[64*128];         // 32 KB
    __shared__ float simg[9*128];
    __shared__ float sAct;
    if (FIRST){ if (tid==0) sAct=1.f; }
    else if (tid<64){
        float sd=red_in[(b<<7)+(tid<<1)], si=red_in[(b<<7)+(tid<<1)+1];
        #pragma unroll
        for (int off=32; off; off>>=1){ sd+=__shfl_down(sd,off); si+=__shfl_down(si,off); }
        if (tid==0) sAct = (sd > TOLV*TOLV*si) ? 1.f : 0.f;
    }
    for (int e=tid; e<1152; e+=512)
        simg[e]=nimg[b*NPIX + (((h0-4+(e>>7))&127)<<7) + (e&127)];
    size_t sbase = (size_t)b*NPB + (h0<<7);
    float2 nv8[8], cv8[8];
    if (!FIRST){
        // stage own tile: 8 ch x 2 px; each instr = 64 lanes x float2 = 512B
        #pragma unroll
        for (int oc=0;oc<8;++oc){
            size_t a = sbase + (size_t)(co+oc)*NPIX + px;
            cv8[oc]=*reinterpret_cast<const float2*>(c_in + a);
            nv8[oc]=*reinterpret_cast<const float2*>(nc_in + a);
            float2 t;
            t.x=fmaf(mom,nv8[oc].x-cv8[oc].x,nv8[oc].x);
            t.y=fmaf(mom,nv8[oc].y-cv8[oc].y,nv8[oc].y);
            *reinterpret_cast<float2*>(sTemp + (co+oc)*128 + px) = t;
        }
    }
    __syncthreads();
    const float* Xo = Xmat + co;
    const float* Ao = atomsT + co;
    float acc[16];                          // [oc][2px]
    #pragma unroll
    for (int i=0;i<16;++i) acc[i]=0.f;
    if (!FIRST){
        for (int c=0;c<64;++c){
            float2 t=*reinterpret_cast<const float2*>(sTemp + c*128 + px);
            const float* Xr = Xo + (c<<6);
            #pragma unroll
            for (int oc=0;oc<8;++oc){
                float x=Xr[oc];
                acc[oc*2+0]=fmaf(x,t.x,acc[oc*2+0]);
                acc[oc*2+1]=fmaf(x,t.y,acc[oc*2+1]);
            }
        }
    }
    for (int p=0;p<9;++p){
        const float* srow = simg + p*128;
        float in10[10];
        #pragma unroll
        for (int j=0;j<10;++j) in10[j]=srow[(px-4+j)&127];
        #pragma unroll 3
        for (int q=0;q<9;++q){
            const float* Ar = Ao + ((p*9+q)<<6);
            #pragma unroll
            for (int oc=0;oc<8;++oc){
                float a=Ar[oc];
                acc[oc*2+0]=fmaf(a,-in10[q+0],acc[oc*2+0]);
                acc[oc*2+1]=fmaf(a,-in10[q+1],acc[oc*2+1]);
            }
        }
    }
    float beta=scalars[SC_BETA], lmb=lmbda_p[0];
    bool act = (sAct!=0.f);
    #pragma unroll
    for (int oc=0;oc<8;++oc){
        size_t a = sbase + (size_t)(co+oc)*NPIX + px;
        float2 nv, cv;
        if (FIRST){ nv=make_float2(0.f,0.f); cv=nv; }
        else { nv=nv8[oc]; cv=cv8[oc]; }
        float2 nw;
        {
            float t=FIRST?0.f:fmaf(mom,nv.x-cv.x,nv.x);
            float u=fmaf(-beta,acc[oc*2+0],t); float au=fabsf(u)-lmb;
            u=(au>0.f)?copysignf(au,u):0.f; nw.x=act?u:nv.x;
        }{
            float t=FIRST?0.f:fmaf(mom,nv.y-cv.y,nv.y);
            float u=fmaf(-beta,acc[oc*2+1],t); float au=fabsf(u)-lmb;
            u=(au>0.f)?copysignf(au,u):0.f; nw.y=act?u:nv.y;
        }
        *reinterpret_cast<float2*>(nc_out + a) = nw;
        if (FIRST){
            // rotation buffer (nc_in) becomes c for iter 2: must be 0
            *reinterpret_cast<float2*>(nc_in + a) = make_float2(0.f,0.f);
        } else if (!act){
            // fix-up: preserve C_k in the rotating buffer (block-uniform branch)
            *reinterpret_cast<float2*>(nc_in + a) = cv;
        }
    }
}

// kB1: dict_pred partials, CHANNEL-split. grid (8 rowblk, 32 cgroup, 4 b)
// = 1024 blocks of 256 thr (4 waves/SIMD). 16 rows/block, 8 px/thread,
// 2 ch per cgroup (18 fma per float4 load preserved).
__global__ __launch_bounds__(256,4) void kB1(const float* __restrict__ nc2,
    const float* __restrict__ atoms_f, float* __restrict__ part)
{
    int b=blockIdx.z, cg=blockIdx.y, pb=blockIdx.x;
    int t=threadIdx.x;
    int row = pb*16 + (t>>4);
    int cb  = (t&15)*8;
    const float* src = nc2 + (b*NCH + cg*2)*NPIX;
    float acc[8];
    #pragma unroll
    for (int k=0;k<8;++k) acc[k]=0.f;
    for (int c=0;c<2;++c){
        const float* chan = src + c*NPIX;
        const float* arow = atoms_f + (cg*2+c)*81;
        #pragma unroll 3
        for (int p=0;p<9;++p){
            int r=(row+4-p)&127;
            const float* rp_ = chan + (r<<7);
            float in16[16];
            #pragma unroll
            for (int k4=0;k4<4;++k4){
                int col=(cb-4+(k4<<2))&127;
                const float4 vv = *reinterpret_cast<const float4*>(rp_+col);
                in16[(k4<<2)+0]=vv.x; in16[(k4<<2)+1]=vv.y;
                in16[(k4<<2)+2]=vv.z; in16[(k4<<2)+3]=vv.w;
            }
            #pragma unroll
            for (int q=0;q<9;++q){
                float a = arow[p*9+q];
                #pragma unroll
                for (int k=0;k<8;++k) acc[k]=fmaf(in16[k+8-q], a, acc[k]);
            }
        }
    }
    float* dst = part + (cg*NB+b)*NPIX + (row<<7) + cb;
    #pragma unroll
    for (int k=0;k<8;++k) dst[k]=acc[k];
}

// kB2: image update + residual partials. 512 thr: halves split the 17-tap
// p-loop (9/8), merged via LDS; px work+writes by half 0. Sums 32 partials.
template<bool FIRST>
__global__ __launch_bounds__(512) void kB2(const float* __restrict__ img,
    const float* __restrict__ nimg, const float* __restrict__ y,
    const float* __restrict__ part, const float* __restrict__ pi,
    const float* __restrict__ scalars, const float* __restrict__ red_in,
    float* __restrict__ img_out, float* __restrict__ nimg_out,
    float* __restrict__ red_out, float mom)
{
    int b=blockIdx.y, rp=blockIdx.x;
    int tid=threadIdx.x;
    int half=tid>>8, lid=tid&255;
    int ty=lid>>7, w=lid&127;
    int h0=rp*2;
    __shared__ float sti[18*128];
    __shared__ float spi[289];
    __shared__ float sP2[256];
    __shared__ float rsd[4], rsi[4];
    __shared__ float sAct;
    if (FIRST){ if (tid==0) sAct=1.f; }
    else if (tid<64){
        float sd=red_in[(b<<7)+(tid<<1)], si=red_in[(b<<7)+(tid<<1)+1];
        #pragma unroll
        for (int off=32; off; off>>=1){ sd+=__shfl_down(sd,off); si+=__shfl_down(si,off); }
        if (tid==0) sAct = (sd > TOLV*TOLV*si) ? 1.f : 0.f;
    }
    const float* ib  = img  + b*NPIX;
    const float* nib = nimg + b*NPIX;
    for (int e=tid; e<2304; e+=512){
        int r=e>>7, cc=e&127;
        int idx=(((h0-8+r)&127)<<7)+cc;
        float nv=nib[idx], v=ib[idx];
        sti[e]=fmaf(mom, nv-v, nv);
    }
    for (int e=tid; e<289; e+=512) spi[e]=pi[e];
    __syncthreads();
    float sp=0.f;
    int pn = 9 - half;
    for (int pk=0; pk<pn; ++pk){
        int p = half*9 + pk;
        const float* srow = sti + (ty+p)*128;
        const float* pr = spi + p*17;
        #pragma unroll
        for (int q=0;q<17;++q) sp=fmaf(srow[(w+q-8)&127], pr[q], sp);
    }
    if (half==1) sP2[lid]=sp;
    __syncthreads();
    if (tid<256){
        sp += sP2[lid];
        int pix=((h0+ty)<<7)+w;
        float dp=0.f;
        #pragma unroll
        for (int g=0; g<NPG; ++g) dp += part[(g*NB+b)*NPIX + pix];
        float ti = sti[(ty+8)*128 + w];
        float beta=scalars[SC_BETA], L=scalars[SC_L];
        float yv=y[b*NPIX+pix];
        float upd = ti - (ti - yv + beta*(sp - dp))/L;
        bool act = (sAct!=0.f);
        float iv=ib[pix], niv=nib[pix];
        float i2 = act? niv : iv;
        float ni2 = act? upd : niv;
        img_out[b*NPIX+pix]=i2;
        nimg_out[b*NPIX+pix]=ni2;
        float d=i2-ni2;
        float sd=d*d, si=i2*i2;
        #pragma unroll
        for (int off=32; off; off>>=1){ sd+=__shfl_down(sd,off); si+=__shfl_down(si,off); }
        if ((tid&63)==0){ rsd[tid>>6]=sd; rsi[tid>>6]=si; }
    }
    __syncthreads();
    if (tid==0){
        float a=rsd[0]+rsd[1]+rsd[2]+rsd[3];
        float c2=rsi[0]+rsi[1]+rsi[2]+rsi[3];
        red_out[(b<<7)+(rp<<1)+0]=a;
        red_out[(b<<7)+(rp<<1)+1]=c2;
    }
}

// ---------------------------------------------------------------------------
extern "C" void kernel_launch(void* const* d_in, const int* in_sizes, int n_in,
                              void* d_out, int out_size, void* d_ws, size_t ws_size,
                              hipStream_t stream)
{
    const float* y        = (const float*)d_in[0];
    const float* atoms_p  = (const float*)d_in[1];
    const float* fatoms_p = (const float*)d_in[2];
    const float* beta_p   = (const float*)d_in[3];
    const float* lmbda_p  = (const float*)d_in[4];
    float* out = (float*)d_out;
    float* w = (float*)d_ws;

    size_t off=0;
    float* cf[3];  cf[0]=w+off; off+=NCOEF; cf[1]=w+off; off+=NCOEF; cf[2]=w+off; off+=NCOEF;
    float* ib[2];  ib[0]=w+off;  off+=NIMG;  ib[1]=w+off;  off+=NIMG;
    float* nib[2]; nib[0]=w+off; off+=NIMG;  nib[1]=w+off; off+=NIMG;
    float* part=w+off;    off+=NPG*NIMG;
    float* red[2]; red[0]=w+off; off+=512; red[1]=w+off; off+=512;
    float* gram=w+off;    off+=6561;
    float* pf=w+off;      off+=6561;
    float* PP=w+off;      off+=6561;
    float* pi=w+off;      off+=512;
    float* af_rn=w+off;   off+=5184;
    float* af_rnT=w+off;  off+=5184;
    float* Mmat=w+off;    off+=4096;
    float* MA=w+off;      off+=4096;
    float* MB=w+off;      off+=4096;
    float* atoms_f=w+off; off+=5184;
    float* atomsT=w+off;  off+=5184;
    float* Xmat=w+off;    off+=4096;
    float* scalars=w+off; off+=32;

    k_prep1<<<dim3(1),dim3(256),0,stream>>>(fatoms_p, beta_p, gram, pf, scalars);
    k_PP<<<dim3(26),dim3(256),0,stream>>>(pf, PP);
    k_impulse<<<dim3(1),dim3(320),0,stream>>>(PP, pi);
    k_dft<<<dim3(256),dim3(64),0,stream>>>(pi, scalars);
    k_atoms1<<<dim3(64),dim3(128),0,stream>>>(atoms_p, gram, af_rn, af_rnT);
    k_M<<<dim3(16),dim3(256),0,stream>>>(af_rn, af_rnT, Mmat);
    k_M2<<<dim3(16),dim3(256),0,stream>>>(Mmat, MA);   // M^2
    k_M2<<<dim3(16),dim3(256),0,stream>>>(MA, MB);     // M^4
    k_M2<<<dim3(16),dim3(256),0,stream>>>(MB, MA);     // M^8
    k_M2<<<dim3(16),dim3(256),0,stream>>>(MA, MB);     // M^16
    k_fin<<<dim3(1),dim3(256),0,stream>>>(Mmat, MB, af_rn, scalars, atoms_f, atomsT, Xmat);

    // 3-buffer rotation: iter k uses (C=cf[ic], N=cf[in]); nc_out -> cf[io];
    // after the iter: c_{k+1} buffer = cf[in] (rotation), n_{k+1} = cf[io].
    int ic=0, in=1, io=2;
    int p=0;
    for (int k=1; k<=20; ++k){
        float mom = (float)(k-1)/(float)(k+2);
        const float* rin = red[(k-1)&1];
        float* rout = red[k&1];
        const float* img_i  = (k==1)? y : ib[p];
        const float* nimg_i = (k==1)? y : nib[p];
        float* nc_t  = (k==20)? (out+NIMG) : cf[io];
        float* nimg_t= (k==20)? out : nib[p^1];
        if (k==1){
            kA<true><<<dim3(128,4),dim3(512),0,stream>>>(cf[ic],cf[in],nimg_i,Xmat,atomsT,
                scalars,lmbda_p,rin, nc_t,mom);
        } else {
            kA<false><<<dim3(128,4),dim3(512),0,stream>>>(cf[ic],cf[in],nimg_i,Xmat,atomsT,
                scalars,lmbda_p,rin, nc_t,mom);
        }
        kB1<<<dim3(8,32,4),dim3(256),0,stream>>>(nc_t, atoms_f, part);
        if (k==1){
            kB2<true><<<dim3(64,4),dim3(512),0,stream>>>(img_i,nimg_i,y,part,pi,scalars,rin,
                ib[p^1],nimg_t,rout,mom);
        } else {
            kB2<false><<<dim3(64,4),dim3(512),0,stream>>>(img_i,nimg_i,y,part,pi,scalars,rin,
                ib[p^1],nimg_t,rout,mom);
        }
        int t=ic; ic=in; in=io; io=t;
        p^=1;
    }
}